// Round 5
// baseline (3816.154 us; speedup 1.0000x reference)
//
#include <hip/hip_runtime.h>
#include <hip/hip_bf16.h>

#define BB 128
#define TT 150
#define TS 149
#define NITEM (TS*BB)
#define GRIDX 1024

typedef __attribute__((ext_vector_type(8))) short bf16x8;
typedef __attribute__((ext_vector_type(4))) float f32x4;

__device__ __forceinline__ float bf(__hip_bfloat16 x) { return __bfloat162float(x); }
__device__ __forceinline__ __hip_bfloat16 tobf(float x) { return __float2bfloat16(x); }
__device__ __forceinline__ float sigm(float x) { return 1.f / (1.f + expf(-x)); }

// bf16 pack/unpack helpers (RNE)
__device__ __forceinline__ unsigned pk2(float a, float b) {
  unsigned ua = __float_as_uint(a), ub = __float_as_uint(b);
  ua += 0x7fffu + ((ua >> 16) & 1u);
  ub += 0x7fffu + ((ub >> 16) & 1u);
  return (ua >> 16) | (ub & 0xffff0000u);
}
__device__ __forceinline__ float blo(unsigned u) { return __uint_as_float(u << 16); }
__device__ __forceinline__ float bhi(unsigned u) { return __uint_as_float(u & 0xffff0000u); }

// ---- 4-column VALU dot helpers; W layout [k4*100 + c] (k-major, conflict-free) ----
__device__ __forceinline__ void dot4c(const uint2* __restrict__ W, int q,
                                      const float* __restrict__ x, float acc[4]) {
  for (int k4 = 0; k4 < 25; k4++) {
    float4 xv = *(const float4*)&x[k4*4];
#pragma unroll
    for (int j = 0; j < 4; j++) {
      uint2 w = W[k4*100 + q + 25*j];
      acc[j] = fmaf(blo(w.x), xv.x, fmaf(bhi(w.x), xv.y,
               fmaf(blo(w.y), xv.z, fmaf(bhi(w.y), xv.w, acc[j]))));
    }
  }
}
__device__ __forceinline__ void dot4c2(const uint2* __restrict__ W, int q,
                                       const float* __restrict__ xa, const float* __restrict__ xb,
                                       float acc[4]) {
  for (int k4 = 0; k4 < 25; k4++) {
    float4 av = *(const float4*)&xa[k4*4];
    float4 bv = *(const float4*)&xb[k4*4];
    float x0 = av.x+bv.x, x1 = av.y+bv.y, x2 = av.z+bv.z, x3 = av.w+bv.w;
#pragma unroll
    for (int j = 0; j < 4; j++) {
      uint2 w = W[k4*100 + q + 25*j];
      acc[j] = fmaf(blo(w.x), x0, fmaf(bhi(w.x), x1,
               fmaf(blo(w.y), x2, fmaf(bhi(w.y), x3, acc[j]))));
    }
  }
}
template<int NR>
__device__ __forceinline__ void dot4cm(const uint2* __restrict__ W, int q,
                                       const float* __restrict__ rows, float inv,
                                       const float* __restrict__ x0p, float acc[4]) {
  for (int k4 = 0; k4 < 25; k4++) {
    float sx=0.f, sy=0.f, sz=0.f, sw=0.f;
#pragma unroll
    for (int r = 0; r < NR; r++) {
      float4 v = *(const float4*)&rows[r*100 + k4*4];
      sx += v.x; sy += v.y; sz += v.z; sw += v.w;
    }
    float4 b = *(const float4*)&x0p[k4*4];
    float x0 = inv*sx+b.x, x1 = inv*sy+b.y, x2 = inv*sz+b.z, x3 = inv*sw+b.w;
#pragma unroll
    for (int j = 0; j < 4; j++) {
      uint2 w = W[k4*100 + q + 25*j];
      acc[j] = fmaf(blo(w.x), x0, fmaf(bhi(w.x), x1,
               fmaf(blo(w.y), x2, fmaf(bhi(w.y), x3, acc[j]))));
    }
  }
}

// S offsets (floats). T1B overlays dead T1IN.
#define T1INQ 0
#define T1INU 400
#define T1BQ  0
#define T1BU  400
#define T0INQ 1400
#define T0INU 1500
#define M2BQ  1600
#define M2BU  2000
#define T1AQ  3000
#define T1AU  3400
#define T0AQ  4400
#define T0AU  4500
#define T0BQ  4600
#define T0BU  4700
#define T0CQ  4800
#define T0CU  4900
#define SSZ   5000

// ---------------------------------------------------------------------------
// P1: per-(t,b) multi-hop aggregate -> emb_hat. t2 stage on MFMA.
// ---------------------------------------------------------------------------
__global__ __launch_bounds__(512, 1) void k_embhat(
    const float* __restrict__ emb_q, const float* __restrict__ emb_q2,
    const float* __restrict__ emb_s, const float* __restrict__ emb_u,
    const float* __restrict__ w1_q, const float* __restrict__ w2_q,
    const float* __restrict__ agg_W, const float* __restrict__ agg_b,
    const float* __restrict__ last_W, const float* __restrict__ last_b,
    const int* __restrict__ user, const int* __restrict__ question, const int* __restrict__ mask,
    const int* __restrict__ q_nb, const int* __restrict__ s_nb,
    const int* __restrict__ u_nb, const int* __restrict__ q_nb2,
    __hip_bfloat16* __restrict__ embhat)
{
  __shared__ __align__(16) char Ab[96*256];    // A-tile [96 rows][128 k] bf16, swizzled
  __shared__ __align__(16) char Wm[112*256];   // W2^T tile [112 c][128 k] bf16, swizzled
  __shared__ __hip_bfloat16 Cb[9000];          // C [90][100] bf16
  __shared__ uint2 W0u[2500], W1u[2500], WLu[2500]; // [k4*100+c] bf16x4 packed
  __shared__ float b0[100], b1[100], b2[100], bl[100];
  __shared__ __align__(16) float S[SSZ];
  __shared__ int n1[4], n2[40], n3[160], m1[10], m2[50], m3[500];
  const int tid = threadIdx.x;
  const int wid = tid >> 6, lane = tid & 63;
  const float4* eq4  = (const float4*)emb_q;
  const float4* eq24 = (const float4*)emb_q2;
  const float4* es4  = (const float4*)emb_s;
  const float4* eu4  = (const float4*)emb_u;

  // stage k-major uint2 weights (W0, W1, WL)
  for (int i = tid; i < 2500; i += 512) {
    int k4 = i / 100, c = i % 100;
    float4 a;
    a = *(const float4*)&agg_W[c*100 + k4*4];          W0u[i] = make_uint2(pk2(a.x,a.y), pk2(a.z,a.w));
    a = *(const float4*)&agg_W[10000 + c*100 + k4*4];  W1u[i] = make_uint2(pk2(a.x,a.y), pk2(a.z,a.w));
    a = *(const float4*)&last_W[c*100 + k4*4];         WLu[i] = make_uint2(pk2(a.x,a.y), pk2(a.z,a.w));
  }
  // stage W2 in MFMA B^T layout [c][k] bf16, swizzled, ZERO-padded (c>=100 or k>=100)
  for (int i = tid; i < 112*32; i += 512) {
    int c = i >> 5, q8 = i & 31;
    float v0=0.f, v1=0.f, v2=0.f, v3=0.f;
    if (c < 100 && q8 < 25) {
      float4 a = *(const float4*)&agg_W[20000 + c*100 + q8*4];
      v0=a.x; v1=a.y; v2=a.z; v3=a.w;
    }
    int ofs = (c*256 + q8*8) ^ ((c&7)<<4);
    *(uint2*)(Wm + ofs) = make_uint2(pk2(v0,v1), pk2(v2,v3));
  }
  // zero A-tile k-pad (k 100..127, all 96 rows) once; gathers only write k<100
  for (int i = tid; i < 96*7; i += 512) {
    int r = i / 7, q8 = 25 + i % 7;
    int ofs = (r*256 + q8*8) ^ ((r&7)<<4);
    *(uint2*)(Ab + ofs) = make_uint2(0u, 0u);
  }
  if (tid < 100) {
    b0[tid] = agg_b[tid]; b1[tid] = agg_b[100+tid];
    b2[tid] = agg_b[200+tid]; bl[tid] = last_b[tid];
  }
  const float w1 = w1_q[0], w2 = w2_q[0];
  __syncthreads();

  for (int item = blockIdx.x; item < NITEM; item += GRIDX) {
    const int t = item / BB, b = item % BB;
    const int qt = question[b*TT + t];
    if (mask[b*TT + t] != 1) {
      if (tid < 50) {
        const float2 q = *(const float2*)&emb_q[qt*100 + tid*2];
        const float2 p = *(const float2*)&emb_q2[qt*100 + tid*2];
        ((unsigned*)embhat)[item*50 + tid] = pk2(w1*q.x + w2*p.x, w1*q.y + w2*p.y);
      }
      continue;
    }
    const int ut = user[b*TT + t];
    // ---- index staging (3 dependent levels) ----
    if (tid < 4) n1[tid] = q_nb[qt*4 + tid];
    else if (tid >= 64 && tid < 74) m1[tid-64] = u_nb[ut*10 + (tid-64)];
    __syncthreads();
    if (tid < 40) n2[tid] = s_nb[n1[tid/10]*10 + tid%10];
    else if (tid >= 64 && tid < 114) { int e = tid-64; m2[e] = q_nb2[m1[e/5]*5 + e%5]; }
    __syncthreads();
    for (int i = tid; i < 660; i += 512) {
      if (i < 160) n3[i] = q_nb[n2[i/4]*4 + i%4];
      else { int e = i-160; m3[e] = u_nb[m2[e/10]*10 + e%10]; }
    }
    __syncthreads();
    // ---- ph1: gathers. A rows 0-39 = Q bufA, 40-89 = U bufA (bf16 swizzled);
    //            T1IN / T0IN stay f32 in S.
    for (int v = tid; v < 2650; v += 512) {
      if (v < 1000) {
        int r = v/25, k4 = v%25;
        float4 v0 = es4[n3[r*4+0]*25+k4], v1 = es4[n3[r*4+1]*25+k4];
        float4 v2 = es4[n3[r*4+2]*25+k4], v3 = es4[n3[r*4+3]*25+k4];
        float4 qv = eq4[n2[r]*25+k4];
        float x0 = 0.25f*(v0.x+v1.x+v2.x+v3.x)+qv.x, x1 = 0.25f*(v0.y+v1.y+v2.y+v3.y)+qv.y;
        float x2 = 0.25f*(v0.z+v1.z+v2.z+v3.z)+qv.z, x3 = 0.25f*(v0.w+v1.w+v2.w+v3.w)+qv.w;
        int ofs = (r*256 + k4*8) ^ ((r&7)<<4);
        *(uint2*)(Ab + ofs) = make_uint2(pk2(x0,x1), pk2(x2,x3));
      } else if (v < 2250) {
        int e = v-1000, r = e/25, k4 = e%25;
        float sx=0.f,sy=0.f,sz=0.f,sw=0.f;
        for (int k = 0; k < 10; k++) {
          float4 vv = eq24[m3[r*10+k]*25+k4]; sx+=vv.x; sy+=vv.y; sz+=vv.z; sw+=vv.w;
        }
        float4 h = eu4[m2[r]*25+k4];
        int row = 40 + r;
        int ofs = (row*256 + k4*8) ^ ((row&7)<<4);
        *(uint2*)(Ab + ofs) = make_uint2(pk2(0.1f*sx+h.x, 0.1f*sy+h.y), pk2(0.1f*sz+h.z, 0.1f*sw+h.w));
      } else if (v < 2350) {
        int e = v-2250, a = e/25, k4 = e%25;
        float sx=0.f,sy=0.f,sz=0.f,sw=0.f;
        for (int j = 0; j < 10; j++) {
          float4 vv = eq4[n2[a*10+j]*25+k4]; sx+=vv.x; sy+=vv.y; sz+=vv.z; sw+=vv.w;
        }
        float4 h = es4[n1[a]*25+k4];
        *(float4*)&S[T1INQ + a*100 + k4*4] = make_float4(0.1f*sx+h.x, 0.1f*sy+h.y, 0.1f*sz+h.z, 0.1f*sw+h.w);
      } else if (v < 2600) {
        int e = v-2350, a = e/25, k4 = e%25;
        float sx=0.f,sy=0.f,sz=0.f,sw=0.f;
        for (int p = 0; p < 5; p++) {
          float4 vv = eu4[m2[a*5+p]*25+k4]; sx+=vv.x; sy+=vv.y; sz+=vv.z; sw+=vv.w;
        }
        float4 h = eq24[m1[a]*25+k4];
        *(float4*)&S[T1INU + a*100 + k4*4] = make_float4(0.2f*sx+h.x, 0.2f*sy+h.y, 0.2f*sz+h.z, 0.2f*sw+h.w);
      } else if (v < 2625) {
        int k4 = v-2600;
        float4 v0 = es4[n1[0]*25+k4], v1 = es4[n1[1]*25+k4];
        float4 v2 = es4[n1[2]*25+k4], v3 = es4[n1[3]*25+k4];
        float4 qv = eq4[qt*25+k4];
        *(float4*)&S[T0INQ + k4*4] = make_float4(
          0.25f*(v0.x+v1.x+v2.x+v3.x)+qv.x, 0.25f*(v0.y+v1.y+v2.y+v3.y)+qv.y,
          0.25f*(v0.z+v1.z+v2.z+v3.z)+qv.z, 0.25f*(v0.w+v1.w+v2.w+v3.w)+qv.w);
      } else {
        int k4 = v-2625;
        float sx=0.f,sy=0.f,sz=0.f,sw=0.f;
        for (int mm = 0; mm < 10; mm++) {
          float4 vv = eq24[m1[mm]*25+k4]; sx+=vv.x; sy+=vv.y; sz+=vv.z; sw+=vv.w;
        }
        float4 h = eu4[ut*25+k4];
        *(float4*)&S[T0INU + k4*4] = make_float4(0.1f*sx+h.x, 0.1f*sy+h.y, 0.1f*sz+h.z, 0.1f*sw+h.w);
      }
    }
    __syncthreads();
    // ---- ph2a: MFMA t2 GEMM: C[90][100] = A[90][128] * W2^T[128][100] ----
    {
      const int l15 = lane & 15, lg = lane >> 4;
      for (int tp = wid; tp < 42; tp += 8) {
        int mt = tp / 7, nt = tp % 7;
        int arow = mt*16 + l15;
        int brow = nt*16 + l15;
        int koff = lg*16;
        f32x4 acc = {0.f, 0.f, 0.f, 0.f};
#pragma unroll
        for (int kc = 0; kc < 4; kc++) {
          int aofs = (arow*256 + kc*64 + koff) ^ ((arow&7)<<4);
          int bofs = (brow*256 + kc*64 + koff) ^ ((brow&7)<<4);
          bf16x8 av = *(const bf16x8*)(Ab + aofs);
          bf16x8 bv = *(const bf16x8*)(Wm + bofs);
          acc = __builtin_amdgcn_mfma_f32_16x16x32_bf16(av, bv, acc, 0, 0, 0);
        }
        int col = nt*16 + l15;
        int r0 = mt*16 + lg*4;
        if (col < 100) {
#pragma unroll
          for (int r = 0; r < 4; r++)
            if (r0 + r < 90) Cb[(r0+r)*100 + col] = tobf(acc[r]);
        }
      }
    }
    __syncthreads();
    // ---- ph2b: combine (relu+mean of C) + t1a + t0a ----
    for (int u = tid; u < 1800; u += 512) {
      if (u < 400) {
        int a = u/100, c = u%100; float m = 0.f;
#pragma unroll
        for (int s = 0; s < 10; s++) m += fmaxf(b2[c] + bf(Cb[(a*10+s)*100 + c]), 0.f);
        S[M2BQ + a*100 + c] = 0.1f*m;
      } else if (u < 1400) {
        int e = u-400, a = e/100, c = e%100; float m = 0.f;
#pragma unroll
        for (int p = 0; p < 5; p++) m += fmaxf(b2[c] + bf(Cb[(40 + a*5+p)*100 + c]), 0.f);
        S[M2BU + a*100 + c] = 0.2f*m;
      } else if (u < 1500) {
        int e = u-1400, q = e%25, a = e/25;
        float acc[4] = {0.f,0.f,0.f,0.f};
        dot4c(W1u, q, &S[T1INQ + a*100], acc);
#pragma unroll
        for (int j = 0; j < 4; j++) { int c = q+25*j; S[T1AQ + a*100 + c] = fmaxf(b1[c]+acc[j], 0.f); }
      } else if (u < 1750) {
        int e = u-1500, q = e%25, a = e/25;
        float acc[4] = {0.f,0.f,0.f,0.f};
        dot4c(W1u, q, &S[T1INU + a*100], acc);
#pragma unroll
        for (int j = 0; j < 4; j++) { int c = q+25*j; S[T1AU + a*100 + c] = fmaxf(b1[c]+acc[j], 0.f); }
      } else if (u < 1775) {
        int q = u-1750;
        float acc[4] = {0.f,0.f,0.f,0.f};
        dot4c(W0u, q, &S[T0INQ], acc);
#pragma unroll
        for (int j = 0; j < 4; j++) { int c = q+25*j; S[T0AQ + c] = fmaxf(b0[c]+acc[j], 0.f); }
      } else {
        int q = u-1775;
        float acc[4] = {0.f,0.f,0.f,0.f};
        dot4c(W0u, q, &S[T0INU], acc);
#pragma unroll
        for (int j = 0; j < 4; j++) { int c = q+25*j; S[T0AU + c] = fmaxf(b0[c]+acc[j], 0.f); }
      }
    }
    __syncthreads();
    // ---- ph3: t1b (overlays T1IN) + t0b ----
    if (tid < 400) {
      if (tid < 100) {
        int q = tid%25, a = tid/25;
        float acc[4] = {0.f,0.f,0.f,0.f};
        dot4c2(W1u, q, &S[M2BQ + a*100], &S[T1AQ + a*100], acc);
#pragma unroll
        for (int j = 0; j < 4; j++) { int c = q+25*j; S[T1BQ + a*100 + c] = fmaxf(b1[c]+acc[j], 0.f); }
      } else if (tid < 350) {
        int e = tid-100, q = e%25, a = e/25;
        float acc[4] = {0.f,0.f,0.f,0.f};
        dot4c2(W1u, q, &S[M2BU + a*100], &S[T1AU + a*100], acc);
#pragma unroll
        for (int j = 0; j < 4; j++) { int c = q+25*j; S[T1BU + a*100 + c] = fmaxf(b1[c]+acc[j], 0.f); }
      } else if (tid < 375) {
        int q = tid-350;
        float acc[4] = {0.f,0.f,0.f,0.f};
        dot4cm<4>(W0u, q, &S[T1AQ], 0.25f, &S[T0AQ], acc);
#pragma unroll
        for (int j = 0; j < 4; j++) { int c = q+25*j; S[T0BQ + c] = fmaxf(b0[c]+acc[j], 0.f); }
      } else {
        int q = tid-375;
        float acc[4] = {0.f,0.f,0.f,0.f};
        dot4cm<10>(W0u, q, &S[T1AU], 0.1f, &S[T0AU], acc);
#pragma unroll
        for (int j = 0; j < 4; j++) { int c = q+25*j; S[T0BU + c] = fmaxf(b0[c]+acc[j], 0.f); }
      }
    }
    __syncthreads();
    // ---- ph4: t0c ----
    if (tid < 50) {
      float acc[4] = {0.f,0.f,0.f,0.f};
      if (tid < 25) {
        int q = tid;
        dot4cm<4>(W0u, q, &S[T1BQ], 0.25f, &S[T0BQ], acc);
#pragma unroll
        for (int j = 0; j < 4; j++) { int c = q+25*j; S[T0CQ + c] = fmaxf(b0[c]+acc[j], 0.f); }
      } else {
        int q = tid-25;
        dot4cm<10>(W0u, q, &S[T1BU], 0.1f, &S[T0BU], acc);
#pragma unroll
        for (int j = 0; j < 4; j++) { int c = q+25*j; S[T0CU + c] = fmaxf(b0[c]+acc[j], 0.f); }
      }
    }
    __syncthreads();
    // ---- ph5: final linear + combine ----
    if (tid < 25) {
      int q = tid;
      float aq[4] = {0.f,0.f,0.f,0.f}, au[4] = {0.f,0.f,0.f,0.f};
      dot4c(WLu, q, &S[T0CQ], aq);
      dot4c(WLu, q, &S[T0CU], au);
#pragma unroll
      for (int j = 0; j < 4; j++) {
        int c = q+25*j;
        float dq = fmaxf(bl[c]+aq[j], 0.f), du = fmaxf(bl[c]+au[j], 0.f);
        embhat[item*100 + c] = tobf(w1*dq + w2*du);
      }
    }
    __syncthreads();
  }
}

// ---------------------------------------------------------------------------
// P2a: x_in = relu(lin([emb_hat, emb_r[r_t]]))
// ---------------------------------------------------------------------------
__global__ __launch_bounds__(256, 1) void k_xin(
    const float* __restrict__ emb_r, const float* __restrict__ lin_W,
    const float* __restrict__ lin_b, const int* __restrict__ response,
    const __hip_bfloat16* __restrict__ embhat, __hip_bfloat16* __restrict__ xin)
{
  __shared__ __hip_bfloat16 WT[40000];
  __shared__ float xcat[200];
  __shared__ float lb[200];
  const int tid = threadIdx.x;
  for (int i = tid; i < 40000; i += 256) { int j = i/200, k = i%200; WT[k*200+j] = tobf(lin_W[i]); }
  if (tid < 200) lb[tid] = lin_b[tid];
  __syncthreads();
  for (int item = blockIdx.x; item < NITEM; item += gridDim.x) {
    const int t = item / BB, b = item % BB;
    if (tid < 100) xcat[tid] = bf(embhat[item*100 + tid]);
    else if (tid < 200) { int rt = response[b*TT + t]; xcat[tid] = emb_r[rt*100 + tid - 100]; }
    __syncthreads();
    if (tid < 200) {
      float acc = lb[tid];
      for (int k = 0; k < 200; k++) acc += bf(WT[k*200+tid]) * xcat[k];
      xin[item*200 + tid] = tobf(fmaxf(acc, 0.f));
    }
    __syncthreads();
  }
}

// ---------------------------------------------------------------------------
// P2b: xg = x_in @ Wih.T + bih + bhh   (blockIdx.y selects output half)
// ---------------------------------------------------------------------------
__global__ __launch_bounds__(256, 1) void k_xg(
    const float* __restrict__ Wih, const float* __restrict__ bih,
    const float* __restrict__ bhh,
    const __hip_bfloat16* __restrict__ xin, __hip_bfloat16* __restrict__ xg)
{
  __shared__ __hip_bfloat16 WT[40000];
  __shared__ float xv[200];
  __shared__ float bsum[200];
  const int tid = threadIdx.x;
  const int H = blockIdx.y;
  for (int i = tid; i < 40000; i += 256) { int jj = i/200, k = i%200; WT[k*200+jj] = tobf(Wih[H*40000 + i]); }
  if (tid < 200) bsum[tid] = bih[H*200+tid] + bhh[H*200+tid];
  __syncthreads();
  for (int item = blockIdx.x; item < NITEM; item += gridDim.x) {
    if (tid < 200) xv[tid] = bf(xin[item*200 + tid]);
    __syncthreads();
    if (tid < 200) {
      float acc = bsum[tid];
      for (int k = 0; k < 200; k++) acc += bf(WT[k*200+tid]) * xv[k];
      xg[(long)item*400 + H*200 + tid] = tobf(acc);
    }
    __syncthreads();
  }
}

// ---------------------------------------------------------------------------
// P3: per-(b,t) top-10 of dot(eq[question[b,t+1]], eq[question[b,j]]), j<t
// ---------------------------------------------------------------------------
__global__ __launch_bounds__(256, 2) void k_topk(
    const float* __restrict__ emb_q, const int* __restrict__ question,
    int* __restrict__ topidx)
{
  __shared__ float Qb[150*101];
  __shared__ int qid[150];
  __shared__ float tval[1490];
  __shared__ int tidxs[1490];
  const int b = blockIdx.x, tid = threadIdx.x;
  if (tid < 150) qid[tid] = question[b*TT + tid];
  __syncthreads();
  for (int i = tid; i < 15000; i += 256) { int r = i/100, c = i%100; Qb[r*101+c] = emb_q[qid[r]*100+c]; }
  __syncthreads();
  if (tid < TS) {
    const int t = tid;
    float* v = &tval[t*10]; int* ix = &tidxs[t*10];
    for (int p = 0; p < 10; p++) { v[p] = -3.0e38f; ix[p] = 0; }
    const float* qrow = &Qb[(t+1)*101];
    for (int j = 0; j < t; j++) {
      const float* r = &Qb[j*101];
      float s = 0.f;
      for (int k = 0; k < 100; k++) s += qrow[k] * r[k];
      if (s > v[9]) {
        int p = 9;
        while (p > 0 && s > v[p-1]) { v[p] = v[p-1]; ix[p] = ix[p-1]; p--; }
        v[p] = s; ix[p] = j;
      }
    }
    for (int p = 0; p < 10; p++) topidx[(t*BB + b)*10 + p] = ix[p];
  }
}

// ---------------------------------------------------------------------------
// P4: the sequential scan — one block per batch element, everything in LDS.
// ---------------------------------------------------------------------------
__global__ __launch_bounds__(512, 1) void k_scan(
    const float* __restrict__ emb_q, const float* __restrict__ emb_s,
    const float* __restrict__ Whh,
    const float* __restrict__ qW, const float* __restrict__ qb,
    const float* __restrict__ kW, const float* __restrict__ kb,
    const float* __restrict__ wW, const float* __restrict__ wb,
    const float* __restrict__ h0, const float* __restrict__ c0,
    const int* __restrict__ question, const int* __restrict__ qs_skill,
    const __hip_bfloat16* __restrict__ xg, const int* __restrict__ topidx,
    float* __restrict__ out)
{
  __shared__ __hip_bfloat16 WhhT[40000];   // [k][j]
  __shared__ float hist[15000];            // [150][100]; row 0 stays zero forever
  __shared__ float h_l[100], c_l[100], gates[400], partial[100];
  __shared__ float qs_l[500], kv[100], qv[100], skv[150], wvec[200];
  __shared__ float gmat[55], sq_l[5];
  __shared__ int selidx[11];
  __shared__ float scal[4]; // 0:ck 1:cq 2:wb0 3:sk(current h)
  const int b = blockIdx.x, tid = threadIdx.x;
  for (int i = tid; i < 40000; i += 512) { int j = i/100, k = i%100; WhhT[k*400+j] = tobf(Whh[i]); }
  for (int i = tid; i < 15000; i += 512) hist[i] = 0.f;
  if (tid < 200) wvec[tid] = wW[tid];
  if (tid < 150) skv[tid] = 0.f;
  if (tid >= 256 && tid < 356) { h_l[tid-256] = h0[b*100+tid-256]; c_l[tid-256] = c0[b*100+tid-256]; }
  __syncthreads();
  if (tid < 100) {
    float a1 = 0.f, a2 = 0.f;
    for (int c = 0; c < 100; c++) { a1 += kW[c*100+tid] * wvec[100+c]; a2 += qW[c*100+tid] * wvec[c]; }
    kv[tid] = a1; qv[tid] = a2;
  }
  if (tid == 256) {
    float ck = 0.f, cq = 0.f;
    for (int c = 0; c < 100; c++) { ck += kb[c] * wvec[100+c]; cq += qb[c] * wvec[c]; }
    scal[0] = ck; scal[1] = cq; scal[2] = wb[0]; scal[3] = 0.f;
    skv[0] = ck;
    out[b*TT] = 0.5f;
  }
  __syncthreads();
  for (int t = 0; t < TS; t++) {
    if (tid < 400) {
      float acc = bf(xg[((long)t*BB + b)*400 + tid]);
      for (int k = 0; k < 100; k++) acc += bf(WhhT[k*400+tid]) * h_l[k];
      gates[tid] = acc;
    }
    __syncthreads();
    if (tid < 100) {
      float cc = sigm(gates[100+tid])*c_l[tid] + sigm(gates[tid])*tanhf(gates[200+tid]);
      c_l[tid] = cc;
      float hn = sigm(gates[300+tid])*tanhf(cc);
      h_l[tid] = hn;
      if (t > 0) hist[t*100+tid] = hn;
      partial[tid] = hn * kv[tid];
    }
    __syncthreads();
    if (tid < 64) {
      float v = partial[tid] + ((tid < 36) ? partial[tid+64] : 0.f);
#pragma unroll
      for (int o = 32; o; o >>= 1) v += __shfl_xor(v, o);
      if (tid == 0) { float s = v + scal[0]; scal[3] = s; if (t > 0) skv[t] = s; }
    } else {
      const int qn = question[b*TT + t + 1];
      for (int e = tid - 64; e < 500; e += 448) {
        int q = e / 100, c = e % 100;
        qs_l[e] = (q == 0) ? emb_q[qn*100 + c] : emb_s[qs_skill[qn*4 + q - 1]*100 + c];
      }
      if (tid < 75) {
        int p = tid - 64;
        if (p == 0) selidx[0] = -2;
        else {
          int pp = p - 1;
          int cnt = t < 10 ? t : 10;
          selidx[p] = (pp < cnt) ? topidx[((long)t*BB + b)*10 + pp] : -1;
        }
      }
    }
    __syncthreads();
    {
      int u = tid >> 2, l4 = tid & 3;
      if (u < 60) {
        const float* row;
        int q;
        const bool isG = (u < 55);
        if (isG) {
          q = u / 11;
          int s = u % 11;
          int j = (s == 0) ? 0 : selidx[s];
          if (j < 0) j = 0;
          row = (s == 0) ? h_l : &hist[j*100];
        } else { q = u - 55; row = qv; }
        float part = 0.f;
        for (int k = l4*25; k < l4*25+25; k++) part += qs_l[q*100+k] * row[k];
        part += __shfl_xor(part, 1);
        part += __shfl_xor(part, 2);
        if (l4 == 0) { if (isG) gmat[u] = part; else sq_l[q] = part + scal[1]; }
      }
    }
    __syncthreads();
    if (tid < 64) {
      const bool has = (tid < 55);
      int q = has ? tid/11 : 0, s = has ? tid%11 : 0;
      int j = (s == 0) ? 0 : selidx[s];
      bool valid = has && ((s == 0) || (j >= 0));
      if (j < 0) j = 0;
      float sk = (s == 0) ? scal[3] : skv[j];
      float sc = valid ? (sq_l[q] + sk + scal[2]) : -1e9f;
      float gv = has ? gmat[tid] : 0.f;
      float m = sc;
#pragma unroll
      for (int o = 32; o; o >>= 1) m = fmaxf(m, __shfl_xor(m, o));
      float ex = has ? expf(sc - m) : 0.f;
      float num = ex * gv, den = ex;
#pragma unroll
      for (int o = 32; o; o >>= 1) { num += __shfl_xor(num, o); den += __shfl_xor(den, o); }
      if (tid == 0) out[b*TT + t + 1] = sigm(num/den);
    }
    __syncthreads();
  }
}

extern "C" void kernel_launch(void* const* d_in, const int* in_sizes, int n_in,
                              void* d_out, int out_size, void* d_ws, size_t ws_size,
                              hipStream_t stream) {
  const float* emb_q  = (const float*)d_in[0];
  const float* emb_q2 = (const float*)d_in[1];
  const float* emb_s  = (const float*)d_in[2];
  const float* emb_u  = (const float*)d_in[3];
  const float* emb_r  = (const float*)d_in[4];
  const float* w1_q   = (const float*)d_in[5];
  const float* w2_q   = (const float*)d_in[6];
  const float* lin_W  = (const float*)d_in[7];
  const float* lin_b  = (const float*)d_in[8];
  const float* Wih    = (const float*)d_in[9];
  const float* Whh    = (const float*)d_in[10];
  const float* bih    = (const float*)d_in[11];
  const float* bhh    = (const float*)d_in[12];
  const float* agg_W  = (const float*)d_in[13];
  const float* agg_b  = (const float*)d_in[14];
  const float* last_W = (const float*)d_in[15];
  const float* last_b = (const float*)d_in[16];
  const float* qW     = (const float*)d_in[17];
  const float* qb     = (const float*)d_in[18];
  const float* kW     = (const float*)d_in[19];
  const float* kb     = (const float*)d_in[20];
  const float* wW     = (const float*)d_in[21];
  const float* wb     = (const float*)d_in[22];
  const float* h0     = (const float*)d_in[23];
  const float* c0     = (const float*)d_in[24];
  const int* user      = (const int*)d_in[25];
  const int* question  = (const int*)d_in[26];
  const int* response  = (const int*)d_in[27];
  const int* mask      = (const int*)d_in[28];
  const int* q_nb      = (const int*)d_in[29];
  const int* s_nb      = (const int*)d_in[30];
  const int* u_nb      = (const int*)d_in[31];
  const int* q_nb2     = (const int*)d_in[32];
  const int* qs_skill  = (const int*)d_in[33];

  __hip_bfloat16* embhat = (__hip_bfloat16*)d_ws;              // NITEM*100
  __hip_bfloat16* xin    = embhat + (size_t)NITEM*100;         // NITEM*200
  __hip_bfloat16* xg     = xin    + (size_t)NITEM*200;         // NITEM*400
  int*            topidx = (int*)(xg + (size_t)NITEM*400);     // NITEM*10

  k_embhat<<<GRIDX, 512, 0, stream>>>(emb_q, emb_q2, emb_s, emb_u, w1_q, w2_q,
                                      agg_W, agg_b, last_W, last_b,
                                      user, question, mask, q_nb, s_nb, u_nb, q_nb2,
                                      embhat);
  k_xin<<<256, 256, 0, stream>>>(emb_r, lin_W, lin_b, response, embhat, xin);
  k_xg<<<dim3(256, 2), 256, 0, stream>>>(Wih, bih, bhh, xin, xg);
  k_topk<<<128, 256, 0, stream>>>(emb_q, question, topidx);
  k_scan<<<128, 512, 0, stream>>>(emb_q, emb_s, Whh, qW, qb, kW, kb, wW, wb,
                                  h0, c0, question, qs_skill, xg, topidx,
                                  (float*)d_out);
}

// Round 6
// 2079.517 us; speedup vs baseline: 1.8351x; 1.8351x over previous
//
#include <hip/hip_runtime.h>
#include <hip/hip_bf16.h>

#define BB 128
#define TT 150
#define TS 149
#define NITEM (TS*BB)

typedef __attribute__((ext_vector_type(8))) short bf16x8;
typedef __attribute__((ext_vector_type(4))) float f32x4;

__device__ __forceinline__ float bf(__hip_bfloat16 x) { return __bfloat162float(x); }
__device__ __forceinline__ __hip_bfloat16 tobf(float x) { return __float2bfloat16(x); }
__device__ __forceinline__ float sigm(float x) { return 1.f / (1.f + expf(-x)); }

// bf16 pack/unpack (RNE)
__device__ __forceinline__ unsigned pk2(float a, float b) {
  unsigned ua = __float_as_uint(a), ub = __float_as_uint(b);
  ua += 0x7fffu + ((ua >> 16) & 1u);
  ub += 0x7fffu + ((ub >> 16) & 1u);
  return (ua >> 16) | (ub & 0xffff0000u);
}
__device__ __forceinline__ float blo(unsigned u) { return __uint_as_float(u << 16); }
__device__ __forceinline__ float bhi(unsigned u) { return __uint_as_float(u & 0xffff0000u); }
__device__ __forceinline__ float4 up4(uint2 u) {
  return make_float4(blo(u.x), bhi(u.x), blo(u.y), bhi(u.y));
}

// 4-column dot; W layout [k4*100 + c] uint2 (4 bf16) — works on global (ws) pointers
__device__ __forceinline__ void dot4c(const uint2* __restrict__ W, int q,
                                      const float* __restrict__ x, float acc[4]) {
  for (int k4 = 0; k4 < 25; k4++) {
    float4 xv = *(const float4*)&x[k4*4];
#pragma unroll
    for (int j = 0; j < 4; j++) {
      uint2 w = W[k4*100 + q + 25*j];
      acc[j] = fmaf(blo(w.x), xv.x, fmaf(bhi(w.x), xv.y,
               fmaf(blo(w.y), xv.z, fmaf(bhi(w.y), xv.w, acc[j]))));
    }
  }
}

// ---------------------------------------------------------------------------
// P0: one-time weight/table conversion into ws
//   Wb[4][128][128] bf16 (MFMA-B layout, zero-padded), W0g/WLg k-major uint2,
//   eq2b/esb bf16-packed embedding tables.
// ---------------------------------------------------------------------------
#define PREP_N (65536 + 5000 + 1250000 + 50000)
__global__ __launch_bounds__(256, 4) void k_prep(
    const float* __restrict__ agg_W, const float* __restrict__ last_W,
    const float* __restrict__ emb_q2, const float* __restrict__ emb_s,
    __hip_bfloat16* __restrict__ Wb, uint2* __restrict__ W0g, uint2* __restrict__ WLg,
    uint2* __restrict__ eq2b, uint2* __restrict__ esb)
{
  for (int v = blockIdx.x*256 + threadIdx.x; v < PREP_N; v += gridDim.x*256) {
    if (v < 65536) {
      int m = v >> 14, r = v & 16383, c = r >> 7, k = r & 127;
      const float* src = (m==0) ? agg_W+20000 : (m==1) ? agg_W+10000 : (m==2) ? agg_W : last_W;
      Wb[v] = tobf((c < 100 && k < 100) ? src[c*100+k] : 0.f);
    } else if (v < 70536) {
      int j = v - 65536; int mtx = j / 2500; j %= 2500;
      int k4 = j / 100, c = j % 100;
      const float* src = mtx ? last_W : agg_W;
      float4 a = *(const float4*)&src[c*100 + k4*4];
      (mtx ? WLg : W0g)[j] = make_uint2(pk2(a.x,a.y), pk2(a.z,a.w));
    } else if (v < 1320536) {
      int j = v - 70536;
      float4 a = *(const float4*)&emb_q2[j*4];
      eq2b[j] = make_uint2(pk2(a.x,a.y), pk2(a.z,a.w));
    } else {
      int j = v - 1320536;
      float4 a = *(const float4*)&emb_s[j*4];
      esb[j] = make_uint2(pk2(a.x,a.y), pk2(a.z,a.w));
    }
  }
}

// ---------------------------------------------------------------------------
// P1: multi-hop aggregate, one item per block. 6 barriers/heavy item.
// A-tile rows: 0-39 bufQ | 40-89 bufU | 96-99 t1aQ | 100-109 t1aU | 112 t0aQ | 113 t0aU
// ---------------------------------------------------------------------------
__global__ __launch_bounds__(512, 4) void k_embhat(
    const float* __restrict__ emb_q, const float* __restrict__ emb_q2,
    const float* __restrict__ emb_u,
    const float* __restrict__ w1_q, const float* __restrict__ w2_q,
    const float* __restrict__ agg_b, const float* __restrict__ last_b,
    const int* __restrict__ user, const int* __restrict__ question, const int* __restrict__ mask,
    const int* __restrict__ q_nb, const int* __restrict__ s_nb,
    const int* __restrict__ u_nb, const int* __restrict__ q_nb2,
    const __hip_bfloat16* __restrict__ Wb, const uint2* __restrict__ W0g,
    const uint2* __restrict__ WLg, const uint2* __restrict__ eq2b,
    const uint2* __restrict__ esb,
    __hip_bfloat16* __restrict__ embhat)
{
  __shared__ __align__(16) char Ab[128*256];        // [128 rows][128 k] bf16 swizzled
  __shared__ __hip_bfloat16 Cb[128*100];            // C rows bf16
  __shared__ __align__(16) float S[400];            // t0c-in Q/U, t0c Q/U
  const int tid = threadIdx.x, wid = tid >> 6, lane = tid & 63;
  const int l15 = lane & 15, lg = lane >> 4;
  const int item = blockIdx.x;
  const int t = item / BB, b = item % BB;
  const int qt = question[b*TT + t];
  const float w1 = w1_q[0], w2 = w2_q[0];

  if (mask[b*TT + t] != 1) {
    if (tid < 50) {
      const float2 q = *(const float2*)&emb_q[qt*100 + tid*2];
      const float2 p = *(const float2*)&emb_q2[qt*100 + tid*2];
      ((unsigned*)embhat)[item*50 + tid] = pk2(w1*q.x + w2*p.x, w1*q.y + w2*p.y);
    }
    return;
  }
  const int ut = user[b*TT + t];
  const float4* eq4 = (const float4*)emb_q;
  const float4* eu4 = (const float4*)emb_u;

  // ---- P0: zero k-pad (896) + gathers (2650), barrier-free index chains ----
  for (int v = tid; v < 3546; v += 512) {
    if (v < 896) {
      int row = v / 7, k4 = 25 + v % 7;
      int ofs = (row*256 + k4*8) ^ ((row&7)<<4);
      *(uint2*)(Ab + ofs) = make_uint2(0u, 0u);
      continue;
    }
    int g = v - 896;
    float x0, x1, x2, x3; int row, k4;
    if (g < 1000) {                         // bufQ rows 0-39
      int r = g / 25; k4 = g % 25;
      int n1a = q_nb[qt*4 + r/10];
      int n2r = s_nb[n1a*10 + r%10];
      float sx=0.f, sy=0.f, sz=0.f, sw=0.f;
#pragma unroll
      for (int i = 0; i < 4; i++) {
        float4 e = up4(esb[q_nb[n2r*4+i]*25 + k4]);
        sx += e.x; sy += e.y; sz += e.z; sw += e.w;
      }
      float4 qv = eq4[n2r*25 + k4];
      x0 = 0.25f*sx+qv.x; x1 = 0.25f*sy+qv.y; x2 = 0.25f*sz+qv.z; x3 = 0.25f*sw+qv.w;
      row = r;
    } else if (g < 2250) {                  // bufU rows 40-89
      int e0 = g - 1000; int r = e0 / 25; k4 = e0 % 25;
      int m1a = u_nb[ut*10 + r/5];
      int m2r = q_nb2[m1a*5 + r%5];
      float sx=0.f, sy=0.f, sz=0.f, sw=0.f;
      for (int k = 0; k < 10; k++) {
        float4 e = up4(eq2b[u_nb[m2r*10+k]*25 + k4]);
        sx += e.x; sy += e.y; sz += e.z; sw += e.w;
      }
      float4 uv = eu4[m2r*25 + k4];
      x0 = 0.1f*sx+uv.x; x1 = 0.1f*sy+uv.y; x2 = 0.1f*sz+uv.z; x3 = 0.1f*sw+uv.w;
      row = 40 + r;
    } else if (g < 2350) {                  // t1aQ-in rows 96-99
      int e0 = g - 2250; int a = e0 / 25; k4 = e0 % 25;
      int n1a = q_nb[qt*4 + a];
      float sx=0.f, sy=0.f, sz=0.f, sw=0.f;
      for (int j = 0; j < 10; j++) {
        float4 e = eq4[s_nb[n1a*10+j]*25 + k4];
        sx += e.x; sy += e.y; sz += e.z; sw += e.w;
      }
      float4 hv = up4(esb[n1a*25 + k4]);
      x0 = 0.1f*sx+hv.x; x1 = 0.1f*sy+hv.y; x2 = 0.1f*sz+hv.z; x3 = 0.1f*sw+hv.w;
      row = 96 + a;
    } else if (g < 2600) {                  // t1aU-in rows 100-109
      int e0 = g - 2350; int a = e0 / 25; k4 = e0 % 25;
      int m1a = u_nb[ut*10 + a];
      float sx=0.f, sy=0.f, sz=0.f, sw=0.f;
#pragma unroll
      for (int p = 0; p < 5; p++) {
        float4 e = eu4[q_nb2[m1a*5+p]*25 + k4];
        sx += e.x; sy += e.y; sz += e.z; sw += e.w;
      }
      float4 hv = up4(eq2b[m1a*25 + k4]);
      x0 = 0.2f*sx+hv.x; x1 = 0.2f*sy+hv.y; x2 = 0.2f*sz+hv.z; x3 = 0.2f*sw+hv.w;
      row = 100 + a;
    } else if (g < 2625) {                  // t0aQ-in row 112
      k4 = g - 2600;
      float sx=0.f, sy=0.f, sz=0.f, sw=0.f;
#pragma unroll
      for (int i = 0; i < 4; i++) {
        float4 e = up4(esb[q_nb[qt*4+i]*25 + k4]);
        sx += e.x; sy += e.y; sz += e.z; sw += e.w;
      }
      float4 qv = eq4[qt*25 + k4];
      x0 = 0.25f*sx+qv.x; x1 = 0.25f*sy+qv.y; x2 = 0.25f*sz+qv.z; x3 = 0.25f*sw+qv.w;
      row = 112;
    } else {                                // t0aU-in row 113
      k4 = g - 2625;
      float sx=0.f, sy=0.f, sz=0.f, sw=0.f;
      for (int x = 0; x < 10; x++) {
        float4 e = up4(eq2b[u_nb[ut*10+x]*25 + k4]);
        sx += e.x; sy += e.y; sz += e.z; sw += e.w;
      }
      float4 uv = eu4[ut*25 + k4];
      x0 = 0.1f*sx+uv.x; x1 = 0.1f*sy+uv.y; x2 = 0.1f*sz+uv.z; x3 = 0.1f*sw+uv.w;
      row = 113;
    }
    int ofs = (row*256 + k4*8) ^ ((row&7)<<4);
    *(uint2*)(Ab + ofs) = make_uint2(pk2(x0,x1), pk2(x2,x3));
  }
  __syncthreads();
  // ---- P1: L1 MFMA — mt 0-5: W2, mt 6: W1, mt 7: W0 ----
  for (int tp = wid; tp < 56; tp += 8) {
    int mt = tp / 7, nt = tp % 7;
    const __hip_bfloat16* wm = Wb + ((mt < 6) ? 0 : (mt == 6) ? 16384 : 32768);
    int arow = mt*16 + l15;
    f32x4 acc = {0.f,0.f,0.f,0.f};
#pragma unroll
    for (int kc = 0; kc < 4; kc++) {
      bf16x8 av = *(const bf16x8*)(Ab + ((arow*256 + kc*64 + lg*16) ^ ((arow&7)<<4)));
      bf16x8 bv = *(const bf16x8*)(wm + (nt*16 + l15)*128 + kc*32 + lg*8);
      acc = __builtin_amdgcn_mfma_f32_16x16x32_bf16(av, bv, acc, 0, 0, 0);
    }
    int col = nt*16 + l15, r0 = mt*16 + lg*4;
    if (col < 100) {
#pragma unroll
      for (int r = 0; r < 4; r++) Cb[(r0+r)*100 + col] = tobf(acc[r]);
    }
  }
  __syncthreads();
  // ---- P2: reduce + build L2 inputs (A rows 0-13 t1b-in, 16-17 t0b-in) ----
  for (int v = tid; v < 400; v += 512) {
    int k4 = (v < 350) ? v % 25 : (v - 350) % 25;
    float4 b2q = *(const float4*)&agg_b[200 + k4*4];
    float4 b1q = *(const float4*)&agg_b[100 + k4*4];
    float4 b0q = *(const float4*)&agg_b[k4*4];
    float x0, x1, x2, x3; int row;
#define RELU4(rr, bq, r0v,r1v,r2v,r3v) { \
    r0v = fmaxf(bf(Cb[(rr)*100 + k4*4+0]) + bq.x, 0.f); \
    r1v = fmaxf(bf(Cb[(rr)*100 + k4*4+1]) + bq.y, 0.f); \
    r2v = fmaxf(bf(Cb[(rr)*100 + k4*4+2]) + bq.z, 0.f); \
    r3v = fmaxf(bf(Cb[(rr)*100 + k4*4+3]) + bq.w, 0.f); }
    if (v < 350) {
      int a = v / 25;
      float s0=0.f,s1=0.f,s2=0.f,s3=0.f, r0,r1,r2,r3;
      float inv;
      if (a < 4) {
        for (int s = 0; s < 10; s++) { RELU4(a*10+s, b2q, r0,r1,r2,r3); s0+=r0;s1+=r1;s2+=r2;s3+=r3; }
        inv = 0.1f; RELU4(96+a, b1q, r0,r1,r2,r3);
      } else {
        int au = a - 4;
        for (int p = 0; p < 5; p++) { RELU4(40+au*5+p, b2q, r0,r1,r2,r3); s0+=r0;s1+=r1;s2+=r2;s3+=r3; }
        inv = 0.2f; RELU4(100+au, b1q, r0,r1,r2,r3);
      }
      x0 = inv*s0+r0; x1 = inv*s1+r1; x2 = inv*s2+r2; x3 = inv*s3+r3;
      row = a;
    } else {
      float s0=0.f,s1=0.f,s2=0.f,s3=0.f, r0,r1,r2,r3;
      if (v < 375) {
        for (int a = 0; a < 4; a++) { RELU4(96+a, b1q, r0,r1,r2,r3); s0+=r0;s1+=r1;s2+=r2;s3+=r3; }
        RELU4(112, b0q, r0,r1,r2,r3);
        x0 = 0.25f*s0+r0; x1 = 0.25f*s1+r1; x2 = 0.25f*s2+r2; x3 = 0.25f*s3+r3;
        row = 16;
      } else {
        for (int a = 0; a < 10; a++) { RELU4(100+a, b1q, r0,r1,r2,r3); s0+=r0;s1+=r1;s2+=r2;s3+=r3; }
        RELU4(113, b0q, r0,r1,r2,r3);
        x0 = 0.1f*s0+r0; x1 = 0.1f*s1+r1; x2 = 0.1f*s2+r2; x3 = 0.1f*s3+r3;
        row = 17;
      }
    }
    int ofs = (row*256 + k4*8) ^ ((row&7)<<4);
    *(uint2*)(Ab + ofs) = make_uint2(pk2(x0,x1), pk2(x2,x3));
  }
  __syncthreads();
  // ---- P3: L2 MFMA — mt0 (rows 0-13, W1), mt1 (rows 16-17, W0) ----
  for (int tp = wid; tp < 14; tp += 8) {
    int mt = tp / 7, nt = tp % 7;
    const __hip_bfloat16* wm = Wb + (mt ? 32768 : 16384);
    int arow = mt*16 + l15;
    f32x4 acc = {0.f,0.f,0.f,0.f};
#pragma unroll
    for (int kc = 0; kc < 4; kc++) {
      bf16x8 av = *(const bf16x8*)(Ab + ((arow*256 + kc*64 + lg*16) ^ ((arow&7)<<4)));
      bf16x8 bv = *(const bf16x8*)(wm + (nt*16 + l15)*128 + kc*32 + lg*8);
      acc = __builtin_amdgcn_mfma_f32_16x16x32_bf16(av, bv, acc, 0, 0, 0);
    }
    int col = nt*16 + l15, r0 = mt*16 + lg*4;
    if (col < 100) {
#pragma unroll
      for (int r = 0; r < 4; r++) Cb[(r0+r)*100 + col] = tobf(acc[r]);
    }
  }
  __syncthreads();
  // ---- P4: build t0c inputs into S[0..199] ----
  if (tid < 50) {
    int side = tid / 25, k4 = tid % 25;
    float4 b1q = *(const float4*)&agg_b[100 + k4*4];
    float4 b0q = *(const float4*)&agg_b[k4*4];
    float s0=0.f,s1=0.f,s2=0.f,s3=0.f, r0,r1,r2,r3;
    float inv;
    if (side == 0) {
      for (int a = 0; a < 4; a++) { RELU4(a, b1q, r0,r1,r2,r3); s0+=r0;s1+=r1;s2+=r2;s3+=r3; }
      inv = 0.25f; RELU4(16, b0q, r0,r1,r2,r3);
    } else {
      for (int a = 4; a < 14; a++) { RELU4(a, b1q, r0,r1,r2,r3); s0+=r0;s1+=r1;s2+=r2;s3+=r3; }
      inv = 0.1f; RELU4(17, b0q, r0,r1,r2,r3);
    }
    *(float4*)&S[side*100 + k4*4] = make_float4(inv*s0+r0, inv*s1+r1, inv*s2+r2, inv*s3+r3);
  }
  __syncthreads();
  // ---- P5: t0c = relu(W0 · in + b0) ----
  if (tid < 50) {
    int side = tid / 25, q = tid % 25;
    float acc[4] = {0.f,0.f,0.f,0.f};
    dot4c(W0g, q, &S[side*100], acc);
#pragma unroll
    for (int j = 0; j < 4; j++) {
      int c = q + 25*j;
      S[200 + side*100 + c] = fmaxf(agg_b[c] + acc[j], 0.f);
    }
  }
  __syncthreads();
  // ---- P6: last linear + combine ----
  if (tid < 25) {
    int q = tid;
    float aq[4] = {0.f,0.f,0.f,0.f}, au[4] = {0.f,0.f,0.f,0.f};
    dot4c(WLg, q, &S[200], aq);
    dot4c(WLg, q, &S[300], au);
#pragma unroll
    for (int j = 0; j < 4; j++) {
      int c = q + 25*j;
      float dq = fmaxf(last_b[c] + aq[j], 0.f);
      float du = fmaxf(last_b[c] + au[j], 0.f);
      embhat[item*100 + c] = tobf(w1*dq + w2*du);
    }
  }
#undef RELU4
}

// ---------------------------------------------------------------------------
// P2a: x_in = relu(lin([emb_hat, emb_r[r_t]]))
// ---------------------------------------------------------------------------
__global__ __launch_bounds__(256, 1) void k_xin(
    const float* __restrict__ emb_r, const float* __restrict__ lin_W,
    const float* __restrict__ lin_b, const int* __restrict__ response,
    const __hip_bfloat16* __restrict__ embhat, __hip_bfloat16* __restrict__ xin)
{
  __shared__ __hip_bfloat16 WT[40000];
  __shared__ float xcat[200];
  __shared__ float lb[200];
  const int tid = threadIdx.x;
  for (int i = tid; i < 40000; i += 256) { int j = i/200, k = i%200; WT[k*200+j] = tobf(lin_W[i]); }
  if (tid < 200) lb[tid] = lin_b[tid];
  __syncthreads();
  for (int item = blockIdx.x; item < NITEM; item += gridDim.x) {
    const int t = item / BB, b = item % BB;
    if (tid < 100) xcat[tid] = bf(embhat[item*100 + tid]);
    else if (tid < 200) { int rt = response[b*TT + t]; xcat[tid] = emb_r[rt*100 + tid - 100]; }
    __syncthreads();
    if (tid < 200) {
      float acc = lb[tid];
      for (int k = 0; k < 200; k++) acc += bf(WT[k*200+tid]) * xcat[k];
      xin[item*200 + tid] = tobf(fmaxf(acc, 0.f));
    }
    __syncthreads();
  }
}

// ---------------------------------------------------------------------------
// P2b: xg = x_in @ Wih.T + bih + bhh   (blockIdx.y selects output half)
// ---------------------------------------------------------------------------
__global__ __launch_bounds__(256, 1) void k_xg(
    const float* __restrict__ Wih, const float* __restrict__ bih,
    const float* __restrict__ bhh,
    const __hip_bfloat16* __restrict__ xin, __hip_bfloat16* __restrict__ xg)
{
  __shared__ __hip_bfloat16 WT[40000];
  __shared__ float xv[200];
  __shared__ float bsum[200];
  const int tid = threadIdx.x;
  const int H = blockIdx.y;
  for (int i = tid; i < 40000; i += 256) { int jj = i/200, k = i%200; WT[k*200+jj] = tobf(Wih[H*40000 + i]); }
  if (tid < 200) bsum[tid] = bih[H*200+tid] + bhh[H*200+tid];
  __syncthreads();
  for (int item = blockIdx.x; item < NITEM; item += gridDim.x) {
    if (tid < 200) xv[tid] = bf(xin[item*200 + tid]);
    __syncthreads();
    if (tid < 200) {
      float acc = bsum[tid];
      for (int k = 0; k < 200; k++) acc += bf(WT[k*200+tid]) * xv[k];
      xg[(long)item*400 + H*200 + tid] = tobf(acc);
    }
    __syncthreads();
  }
}

// ---------------------------------------------------------------------------
// P3: per-(b,t) top-10 of dot(eq[question[b,t+1]], eq[question[b,j]]), j<t
// ---------------------------------------------------------------------------
__global__ __launch_bounds__(256, 2) void k_topk(
    const float* __restrict__ emb_q, const int* __restrict__ question,
    int* __restrict__ topidx)
{
  __shared__ float Qb[150*101];
  __shared__ int qid[150];
  __shared__ float tval[1490];
  __shared__ int tidxs[1490];
  const int b = blockIdx.x, tid = threadIdx.x;
  if (tid < 150) qid[tid] = question[b*TT + tid];
  __syncthreads();
  for (int i = tid; i < 15000; i += 256) { int r = i/100, c = i%100; Qb[r*101+c] = emb_q[qid[r]*100+c]; }
  __syncthreads();
  if (tid < TS) {
    const int t = tid;
    float* v = &tval[t*10]; int* ix = &tidxs[t*10];
    for (int p = 0; p < 10; p++) { v[p] = -3.0e38f; ix[p] = 0; }
    const float* qrow = &Qb[(t+1)*101];
    for (int j = 0; j < t; j++) {
      const float* r = &Qb[j*101];
      float s = 0.f;
      for (int k = 0; k < 100; k++) s += qrow[k] * r[k];
      if (s > v[9]) {
        int p = 9;
        while (p > 0 && s > v[p-1]) { v[p] = v[p-1]; ix[p] = ix[p-1]; p--; }
        v[p] = s; ix[p] = j;
      }
    }
    for (int p = 0; p < 10; p++) topidx[(t*BB + b)*10 + p] = ix[p];
  }
}

// ---------------------------------------------------------------------------
// P4: the sequential scan — one block per batch element, everything in LDS.
// ---------------------------------------------------------------------------
__global__ __launch_bounds__(512, 1) void k_scan(
    const float* __restrict__ emb_q, const float* __restrict__ emb_s,
    const float* __restrict__ Whh,
    const float* __restrict__ qW, const float* __restrict__ qb,
    const float* __restrict__ kW, const float* __restrict__ kb,
    const float* __restrict__ wW, const float* __restrict__ wb,
    const float* __restrict__ h0, const float* __restrict__ c0,
    const int* __restrict__ question, const int* __restrict__ qs_skill,
    const __hip_bfloat16* __restrict__ xg, const int* __restrict__ topidx,
    float* __restrict__ out)
{
  __shared__ __hip_bfloat16 WhhT[40000];   // [k][j]
  __shared__ float hist[15000];            // [150][100]; row 0 stays zero forever
  __shared__ float h_l[100], c_l[100], gates[400], partial[100];
  __shared__ float qs_l[500], kv[100], qv[100], skv[150], wvec[200];
  __shared__ float gmat[55], sq_l[5];
  __shared__ int selidx[11];
  __shared__ float scal[4]; // 0:ck 1:cq 2:wb0 3:sk(current h)
  const int b = blockIdx.x, tid = threadIdx.x;
  for (int i = tid; i < 40000; i += 512) { int j = i/100, k = i%100; WhhT[k*400+j] = tobf(Whh[i]); }
  for (int i = tid; i < 15000; i += 512) hist[i] = 0.f;
  if (tid < 200) wvec[tid] = wW[tid];
  if (tid < 150) skv[tid] = 0.f;
  if (tid >= 256 && tid < 356) { h_l[tid-256] = h0[b*100+tid-256]; c_l[tid-256] = c0[b*100+tid-256]; }
  __syncthreads();
  if (tid < 100) {
    float a1 = 0.f, a2 = 0.f;
    for (int c = 0; c < 100; c++) { a1 += kW[c*100+tid] * wvec[100+c]; a2 += qW[c*100+tid] * wvec[c]; }
    kv[tid] = a1; qv[tid] = a2;
  }
  if (tid == 256) {
    float ck = 0.f, cq = 0.f;
    for (int c = 0; c < 100; c++) { ck += kb[c] * wvec[100+c]; cq += qb[c] * wvec[c]; }
    scal[0] = ck; scal[1] = cq; scal[2] = wb[0]; scal[3] = 0.f;
    skv[0] = ck;
    out[b*TT] = 0.5f;
  }
  __syncthreads();
  for (int t = 0; t < TS; t++) {
    if (tid < 400) {
      float acc = bf(xg[((long)t*BB + b)*400 + tid]);
      for (int k = 0; k < 100; k++) acc += bf(WhhT[k*400+tid]) * h_l[k];
      gates[tid] = acc;
    }
    __syncthreads();
    if (tid < 100) {
      float cc = sigm(gates[100+tid])*c_l[tid] + sigm(gates[tid])*tanhf(gates[200+tid]);
      c_l[tid] = cc;
      float hn = sigm(gates[300+tid])*tanhf(cc);
      h_l[tid] = hn;
      if (t > 0) hist[t*100+tid] = hn;
      partial[tid] = hn * kv[tid];
    }
    __syncthreads();
    if (tid < 64) {
      float v = partial[tid] + ((tid < 36) ? partial[tid+64] : 0.f);
#pragma unroll
      for (int o = 32; o; o >>= 1) v += __shfl_xor(v, o);
      if (tid == 0) { float s = v + scal[0]; scal[3] = s; if (t > 0) skv[t] = s; }
    } else {
      const int qn = question[b*TT + t + 1];
      for (int e = tid - 64; e < 500; e += 448) {
        int q = e / 100, c = e % 100;
        qs_l[e] = (q == 0) ? emb_q[qn*100 + c] : emb_s[qs_skill[qn*4 + q - 1]*100 + c];
      }
      if (tid < 75) {
        int p = tid - 64;
        if (p == 0) selidx[0] = -2;
        else {
          int pp = p - 1;
          int cnt = t < 10 ? t : 10;
          selidx[p] = (pp < cnt) ? topidx[((long)t*BB + b)*10 + pp] : -1;
        }
      }
    }
    __syncthreads();
    {
      int u = tid >> 2, l4 = tid & 3;
      if (u < 60) {
        const float* row;
        int q;
        const bool isG = (u < 55);
        if (isG) {
          q = u / 11;
          int s = u % 11;
          int j = (s == 0) ? 0 : selidx[s];
          if (j < 0) j = 0;
          row = (s == 0) ? h_l : &hist[j*100];
        } else { q = u - 55; row = qv; }
        float part = 0.f;
        for (int k = l4*25; k < l4*25+25; k++) part += qs_l[q*100+k] * row[k];
        part += __shfl_xor(part, 1);
        part += __shfl_xor(part, 2);
        if (l4 == 0) { if (isG) gmat[u] = part; else sq_l[q] = part + scal[1]; }
      }
    }
    __syncthreads();
    if (tid < 64) {
      const bool has = (tid < 55);
      int q = has ? tid/11 : 0, s = has ? tid%11 : 0;
      int j = (s == 0) ? 0 : selidx[s];
      bool valid = has && ((s == 0) || (j >= 0));
      if (j < 0) j = 0;
      float sk = (s == 0) ? scal[3] : skv[j];
      float sc = valid ? (sq_l[q] + sk + scal[2]) : -1e9f;
      float gv = has ? gmat[tid] : 0.f;
      float m = sc;
#pragma unroll
      for (int o = 32; o; o >>= 1) m = fmaxf(m, __shfl_xor(m, o));
      float ex = has ? expf(sc - m) : 0.f;
      float num = ex * gv, den = ex;
#pragma unroll
      for (int o = 32; o; o >>= 1) { num += __shfl_xor(num, o); den += __shfl_xor(den, o); }
      if (tid == 0) out[b*TT + t + 1] = sigm(num/den);
    }
    __syncthreads();
  }
}

extern "C" void kernel_launch(void* const* d_in, const int* in_sizes, int n_in,
                              void* d_out, int out_size, void* d_ws, size_t ws_size,
                              hipStream_t stream) {
  const float* emb_q  = (const float*)d_in[0];
  const float* emb_q2 = (const float*)d_in[1];
  const float* emb_s  = (const float*)d_in[2];
  const float* emb_u  = (const float*)d_in[3];
  const float* emb_r  = (const float*)d_in[4];
  const float* w1_q   = (const float*)d_in[5];
  const float* w2_q   = (const float*)d_in[6];
  const float* lin_W  = (const float*)d_in[7];
  const float* lin_b  = (const float*)d_in[8];
  const float* Wih    = (const float*)d_in[9];
  const float* Whh    = (const float*)d_in[10];
  const float* bih    = (const float*)d_in[11];
  const float* bhh    = (const float*)d_in[12];
  const float* agg_W  = (const float*)d_in[13];
  const float* agg_b  = (const float*)d_in[14];
  const float* last_W = (const float*)d_in[15];
  const float* last_b = (const float*)d_in[16];
  const float* qW     = (const float*)d_in[17];
  const float* qb     = (const float*)d_in[18];
  const float* kW     = (const float*)d_in[19];
  const float* kb     = (const float*)d_in[20];
  const float* wW     = (const float*)d_in[21];
  const float* wb     = (const float*)d_in[22];
  const float* h0     = (const float*)d_in[23];
  const float* c0     = (const float*)d_in[24];
  const int* user      = (const int*)d_in[25];
  const int* question  = (const int*)d_in[26];
  const int* response  = (const int*)d_in[27];
  const int* mask      = (const int*)d_in[28];
  const int* q_nb      = (const int*)d_in[29];
  const int* s_nb      = (const int*)d_in[30];
  const int* u_nb      = (const int*)d_in[31];
  const int* q_nb2     = (const int*)d_in[32];
  const int* qs_skill  = (const int*)d_in[33];

  char* ws = (char*)d_ws;
  __hip_bfloat16* embhat = (__hip_bfloat16*)(ws + 0);          // 3,814,400 B
  __hip_bfloat16* xin    = (__hip_bfloat16*)(ws + 3814400);    // 7,628,800 B
  __hip_bfloat16* xg     = (__hip_bfloat16*)(ws + 11443200);   // 15,257,600 B
  int*            topidx = (int*)(ws + 26700800);              // 762,880 B
  __hip_bfloat16* Wb     = (__hip_bfloat16*)(ws + 27463680);   // 131,072 B
  uint2*          W0g    = (uint2*)(ws + 27594752);            // 20,000 B
  uint2*          WLg    = (uint2*)(ws + 27614752);            // 20,000 B
  uint2*          eq2b   = (uint2*)(ws + 27634752);            // 10,000,000 B
  uint2*          esb    = (uint2*)(ws + 37634752);            // 400,000 B -> 38,034,752 total

  k_prep<<<2048, 256, 0, stream>>>(agg_W, last_W, emb_q2, emb_s, Wb, W0g, WLg, eq2b, esb);
  k_embhat<<<NITEM, 512, 0, stream>>>(emb_q, emb_q2, emb_u, w1_q, w2_q,
                                      agg_b, last_b,
                                      user, question, mask, q_nb, s_nb, u_nb, q_nb2,
                                      Wb, W0g, WLg, eq2b, esb, embhat);
  k_xin<<<256, 256, 0, stream>>>(emb_r, lin_W, lin_b, response, embhat, xin);
  k_xg<<<dim3(256, 2), 256, 0, stream>>>(Wih, bih, bhh, xin, xg);
  k_topk<<<128, 256, 0, stream>>>(emb_q, question, topidx);
  k_scan<<<128, 512, 0, stream>>>(emb_q, emb_s, Whh, qW, qb, kW, kb, wW, wb,
                                  h0, c0, question, qs_skill, xg, topidx,
                                  (float*)d_out);
}

// Round 7
// 1569.928 us; speedup vs baseline: 2.4308x; 1.3246x over previous
//
#include <hip/hip_runtime.h>
#include <hip/hip_bf16.h>

#define BB 128
#define TT 150
#define TS 149
#define NITEM (TS*BB)

typedef __attribute__((ext_vector_type(8))) short bf16x8;
typedef __attribute__((ext_vector_type(4))) float f32x4;

__device__ __forceinline__ float bf(__hip_bfloat16 x) { return __bfloat162float(x); }
__device__ __forceinline__ __hip_bfloat16 tobf(float x) { return __float2bfloat16(x); }
__device__ __forceinline__ float sigm(float x) { return 1.f / (1.f + expf(-x)); }

__device__ __forceinline__ unsigned pk2(float a, float b) {
  unsigned ua = __float_as_uint(a), ub = __float_as_uint(b);
  ua += 0x7fffu + ((ua >> 16) & 1u);
  ub += 0x7fffu + ((ub >> 16) & 1u);
  return (ua >> 16) | (ub & 0xffff0000u);
}
__device__ __forceinline__ float blo(unsigned u) { return __uint_as_float(u << 16); }
__device__ __forceinline__ float bhi(unsigned u) { return __uint_as_float(u & 0xffff0000u); }
__device__ __forceinline__ float4 up4(uint2 u) {
  return make_float4(blo(u.x), bhi(u.x), blo(u.y), bhi(u.y));
}

// 4-column dot; W layout [k4*100 + c] uint2 (4 bf16), W in global/L2
__device__ __forceinline__ void dot4c(const uint2* __restrict__ W, int q,
                                      const float* __restrict__ x, float acc[4]) {
  for (int k4 = 0; k4 < 25; k4++) {
    float4 xv = *(const float4*)&x[k4*4];
#pragma unroll
    for (int j = 0; j < 4; j++) {
      uint2 w = W[k4*100 + q + 25*j];
      acc[j] = fmaf(blo(w.x), xv.x, fmaf(bhi(w.x), xv.y,
               fmaf(blo(w.y), xv.z, fmaf(bhi(w.y), xv.w, acc[j]))));
    }
  }
}

// ---------------------------------------------------------------------------
// P0: one-time weight/table conversion into ws
// ---------------------------------------------------------------------------
#define PREP_N (65536 + 5000 + 1250000 + 50000 + 46592 + 89600)
__global__ __launch_bounds__(256, 4) void k_prep(
    const float* __restrict__ agg_W, const float* __restrict__ last_W,
    const float* __restrict__ emb_q2, const float* __restrict__ emb_s,
    const float* __restrict__ lin_W, const float* __restrict__ Wih,
    __hip_bfloat16* __restrict__ Wb, uint2* __restrict__ W0g, uint2* __restrict__ WLg,
    uint2* __restrict__ eq2b, uint2* __restrict__ esb,
    __hip_bfloat16* __restrict__ linB, __hip_bfloat16* __restrict__ wihB)
{
  for (int v = blockIdx.x*256 + threadIdx.x; v < PREP_N; v += gridDim.x*256) {
    if (v < 65536) {
      int m = v >> 14, r = v & 16383, c = r >> 7, k = r & 127;
      const float* src = (m==0) ? agg_W+20000 : (m==1) ? agg_W+10000 : (m==2) ? agg_W : last_W;
      Wb[v] = tobf((c < 100 && k < 100) ? src[c*100+k] : 0.f);
    } else if (v < 70536) {
      int j = v - 65536; int mtx = j / 2500; j %= 2500;
      int k4 = j / 100, c = j % 100;
      const float* src = mtx ? last_W : agg_W;
      float4 a = *(const float4*)&src[c*100 + k4*4];
      (mtx ? WLg : W0g)[j] = make_uint2(pk2(a.x,a.y), pk2(a.z,a.w));
    } else if (v < 1320536) {
      int j = v - 70536;
      float4 a = *(const float4*)&emb_q2[j*4];
      eq2b[j] = make_uint2(pk2(a.x,a.y), pk2(a.z,a.w));
    } else if (v < 1370536) {
      int j = v - 1320536;
      float4 a = *(const float4*)&emb_s[j*4];
      esb[j] = make_uint2(pk2(a.x,a.y), pk2(a.z,a.w));
    } else if (v < 1417128) {
      int j = v - 1370536;                   // linB [208][224]
      int c = j / 224, k = j % 224;
      linB[j] = tobf((c < 200 && k < 200) ? lin_W[c*200+k] : 0.f);
    } else {
      int j = v - 1417128;                   // wihB [400][224]
      int c = j / 224, k = j % 224;
      wihB[j] = tobf((k < 200) ? Wih[c*200+k] : 0.f);
    }
  }
}

// ---------------------------------------------------------------------------
// P1: multi-hop aggregate, one item per block. 51KB LDS -> 3 blocks/CU.
// ---------------------------------------------------------------------------
__global__ __launch_bounds__(512, 6) void k_embhat(
    const float* __restrict__ emb_q, const float* __restrict__ emb_q2,
    const float* __restrict__ emb_u,
    const float* __restrict__ w1_q, const float* __restrict__ w2_q,
    const float* __restrict__ agg_b, const float* __restrict__ last_b,
    const int* __restrict__ user, const int* __restrict__ question, const int* __restrict__ mask,
    const int* __restrict__ q_nb, const int* __restrict__ s_nb,
    const int* __restrict__ u_nb, const int* __restrict__ q_nb2,
    const __hip_bfloat16* __restrict__ Wb, const uint2* __restrict__ W0g,
    const uint2* __restrict__ WLg, const uint2* __restrict__ eq2b,
    const uint2* __restrict__ esb,
    __hip_bfloat16* __restrict__ embhat)
{
  __shared__ __align__(16) char Ab[114*256];        // [114 rows][128 k] bf16 swizzled
  __shared__ __hip_bfloat16 Cb[114*100];            // C rows bf16
  float* S = (float*)Ab;                            // overlays Ab after P3 (dead)
  const int tid = threadIdx.x, wid = tid >> 6, lane = tid & 63;
  const int l15 = lane & 15, lg = lane >> 4;
  const int item = blockIdx.x;
  const int t = item / BB, b = item % BB;
  const int qt = question[b*TT + t];
  const float w1 = w1_q[0], w2 = w2_q[0];

  if (mask[b*TT + t] != 1) {
    if (tid < 50) {
      const float2 q = *(const float2*)&emb_q[qt*100 + tid*2];
      const float2 p = *(const float2*)&emb_q2[qt*100 + tid*2];
      ((unsigned*)embhat)[item*50 + tid] = pk2(w1*q.x + w2*p.x, w1*q.y + w2*p.y);
    }
    return;
  }
  const int ut = user[b*TT + t];
  const float4* eq4 = (const float4*)emb_q;
  const float4* eu4 = (const float4*)emb_u;

  // ---- P0: zero k-pad (798) + gathers (2650), barrier-free index chains ----
  for (int v = tid; v < 3448; v += 512) {
    if (v < 798) {
      int row = v / 7, k4 = 25 + v % 7;
      int ofs = (row*256 + k4*8) ^ ((row&7)<<4);
      *(uint2*)(Ab + ofs) = make_uint2(0u, 0u);
      continue;
    }
    int g = v - 798;
    float x0, x1, x2, x3; int row, k4;
    if (g < 1000) {                         // bufQ rows 0-39
      int r = g / 25; k4 = g % 25;
      int n1a = q_nb[qt*4 + r/10];
      int n2r = s_nb[n1a*10 + r%10];
      float sx=0.f, sy=0.f, sz=0.f, sw=0.f;
#pragma unroll
      for (int i = 0; i < 4; i++) {
        float4 e = up4(esb[q_nb[n2r*4+i]*25 + k4]);
        sx += e.x; sy += e.y; sz += e.z; sw += e.w;
      }
      float4 qv = eq4[n2r*25 + k4];
      x0 = 0.25f*sx+qv.x; x1 = 0.25f*sy+qv.y; x2 = 0.25f*sz+qv.z; x3 = 0.25f*sw+qv.w;
      row = r;
    } else if (g < 2250) {                  // bufU rows 40-89
      int e0 = g - 1000; int r = e0 / 25; k4 = e0 % 25;
      int m1a = u_nb[ut*10 + r/5];
      int m2r = q_nb2[m1a*5 + r%5];
      float sx=0.f, sy=0.f, sz=0.f, sw=0.f;
      for (int k = 0; k < 10; k++) {
        float4 e = up4(eq2b[u_nb[m2r*10+k]*25 + k4]);
        sx += e.x; sy += e.y; sz += e.z; sw += e.w;
      }
      float4 uv = eu4[m2r*25 + k4];
      x0 = 0.1f*sx+uv.x; x1 = 0.1f*sy+uv.y; x2 = 0.1f*sz+uv.z; x3 = 0.1f*sw+uv.w;
      row = 40 + r;
    } else if (g < 2350) {                  // t1aQ-in rows 96-99
      int e0 = g - 2250; int a = e0 / 25; k4 = e0 % 25;
      int n1a = q_nb[qt*4 + a];
      float sx=0.f, sy=0.f, sz=0.f, sw=0.f;
      for (int j = 0; j < 10; j++) {
        float4 e = eq4[s_nb[n1a*10+j]*25 + k4];
        sx += e.x; sy += e.y; sz += e.z; sw += e.w;
      }
      float4 hv = up4(esb[n1a*25 + k4]);
      x0 = 0.1f*sx+hv.x; x1 = 0.1f*sy+hv.y; x2 = 0.1f*sz+hv.z; x3 = 0.1f*sw+hv.w;
      row = 96 + a;
    } else if (g < 2600) {                  // t1aU-in rows 100-109
      int e0 = g - 2350; int a = e0 / 25; k4 = e0 % 25;
      int m1a = u_nb[ut*10 + a];
      float sx=0.f, sy=0.f, sz=0.f, sw=0.f;
#pragma unroll
      for (int p = 0; p < 5; p++) {
        float4 e = eu4[q_nb2[m1a*5+p]*25 + k4];
        sx += e.x; sy += e.y; sz += e.z; sw += e.w;
      }
      float4 hv = up4(eq2b[m1a*25 + k4]);
      x0 = 0.2f*sx+hv.x; x1 = 0.2f*sy+hv.y; x2 = 0.2f*sz+hv.z; x3 = 0.2f*sw+hv.w;
      row = 100 + a;
    } else if (g < 2625) {                  // t0aQ-in row 112
      k4 = g - 2600;
      float sx=0.f, sy=0.f, sz=0.f, sw=0.f;
#pragma unroll
      for (int i = 0; i < 4; i++) {
        float4 e = up4(esb[q_nb[qt*4+i]*25 + k4]);
        sx += e.x; sy += e.y; sz += e.z; sw += e.w;
      }
      float4 qv = eq4[qt*25 + k4];
      x0 = 0.25f*sx+qv.x; x1 = 0.25f*sy+qv.y; x2 = 0.25f*sz+qv.z; x3 = 0.25f*sw+qv.w;
      row = 112;
    } else {                                // t0aU-in row 113
      k4 = g - 2625;
      float sx=0.f, sy=0.f, sz=0.f, sw=0.f;
      for (int x = 0; x < 10; x++) {
        float4 e = up4(eq2b[u_nb[ut*10+x]*25 + k4]);
        sx += e.x; sy += e.y; sz += e.z; sw += e.w;
      }
      float4 uv = eu4[ut*25 + k4];
      x0 = 0.1f*sx+uv.x; x1 = 0.1f*sy+uv.y; x2 = 0.1f*sz+uv.z; x3 = 0.1f*sw+uv.w;
      row = 113;
    }
    int ofs = (row*256 + k4*8) ^ ((row&7)<<4);
    *(uint2*)(Ab + ofs) = make_uint2(pk2(x0,x1), pk2(x2,x3));
  }
  __syncthreads();
  // ---- P1: L1 MFMA — mt 0-5: W2, mt 6: W1, mt 7: W0 (A-rows clamped <=113) ----
  for (int tp = wid; tp < 56; tp += 8) {
    int mt = tp / 7, nt = tp % 7;
    const __hip_bfloat16* wm = Wb + ((mt < 6) ? 0 : (mt == 6) ? 16384 : 32768);
    int arow = mt*16 + l15; if (arow > 113) arow = 113;
    f32x4 acc = {0.f,0.f,0.f,0.f};
#pragma unroll
    for (int kc = 0; kc < 4; kc++) {
      bf16x8 av = *(const bf16x8*)(Ab + ((arow*256 + kc*64 + lg*16) ^ ((arow&7)<<4)));
      bf16x8 bv = *(const bf16x8*)(wm + (nt*16 + l15)*128 + kc*32 + lg*8);
      acc = __builtin_amdgcn_mfma_f32_16x16x32_bf16(av, bv, acc, 0, 0, 0);
    }
    int col = nt*16 + l15, r0 = mt*16 + lg*4;
    if (col < 100) {
#pragma unroll
      for (int r = 0; r < 4; r++)
        if (r0 + r < 114) Cb[(r0+r)*100 + col] = tobf(acc[r]);
    }
  }
  __syncthreads();
  // ---- P2: reduce + build L2 inputs (A rows 0-13 t1b-in, 16-17 t0b-in) ----
  for (int v = tid; v < 400; v += 512) {
    int k4 = (v < 350) ? v % 25 : (v - 350) % 25;
    float4 b2q = *(const float4*)&agg_b[200 + k4*4];
    float4 b1q = *(const float4*)&agg_b[100 + k4*4];
    float4 b0q = *(const float4*)&agg_b[k4*4];
    float x0, x1, x2, x3; int row;
#define RELU4(rr, bq, r0v,r1v,r2v,r3v) { \
    r0v = fmaxf(bf(Cb[(rr)*100 + k4*4+0]) + bq.x, 0.f); \
    r1v = fmaxf(bf(Cb[(rr)*100 + k4*4+1]) + bq.y, 0.f); \
    r2v = fmaxf(bf(Cb[(rr)*100 + k4*4+2]) + bq.z, 0.f); \
    r3v = fmaxf(bf(Cb[(rr)*100 + k4*4+3]) + bq.w, 0.f); }
    if (v < 350) {
      int a = v / 25;
      float s0=0.f,s1=0.f,s2=0.f,s3=0.f, r0,r1,r2,r3;
      float inv;
      if (a < 4) {
        for (int s = 0; s < 10; s++) { RELU4(a*10+s, b2q, r0,r1,r2,r3); s0+=r0;s1+=r1;s2+=r2;s3+=r3; }
        inv = 0.1f; RELU4(96+a, b1q, r0,r1,r2,r3);
      } else {
        int au = a - 4;
        for (int p = 0; p < 5; p++) { RELU4(40+au*5+p, b2q, r0,r1,r2,r3); s0+=r0;s1+=r1;s2+=r2;s3+=r3; }
        inv = 0.2f; RELU4(100+au, b1q, r0,r1,r2,r3);
      }
      x0 = inv*s0+r0; x1 = inv*s1+r1; x2 = inv*s2+r2; x3 = inv*s3+r3;
      row = a;
    } else {
      float s0=0.f,s1=0.f,s2=0.f,s3=0.f, r0,r1,r2,r3;
      if (v < 375) {
        for (int a = 0; a < 4; a++) { RELU4(96+a, b1q, r0,r1,r2,r3); s0+=r0;s1+=r1;s2+=r2;s3+=r3; }
        RELU4(112, b0q, r0,r1,r2,r3);
        x0 = 0.25f*s0+r0; x1 = 0.25f*s1+r1; x2 = 0.25f*s2+r2; x3 = 0.25f*s3+r3;
        row = 16;
      } else {
        for (int a = 0; a < 10; a++) { RELU4(100+a, b1q, r0,r1,r2,r3); s0+=r0;s1+=r1;s2+=r2;s3+=r3; }
        RELU4(113, b0q, r0,r1,r2,r3);
        x0 = 0.1f*s0+r0; x1 = 0.1f*s1+r1; x2 = 0.1f*s2+r2; x3 = 0.1f*s3+r3;
        row = 17;
      }
    }
    int ofs = (row*256 + k4*8) ^ ((row&7)<<4);
    *(uint2*)(Ab + ofs) = make_uint2(pk2(x0,x1), pk2(x2,x3));
  }
  __syncthreads();
  // ---- P3: L2 MFMA — mt0 (rows 0-15, W1), mt1 (rows 16-31, W0) ----
  for (int tp = wid; tp < 14; tp += 8) {
    int mt = tp / 7, nt = tp % 7;
    const __hip_bfloat16* wm = Wb + (mt ? 32768 : 16384);
    int arow = mt*16 + l15;
    f32x4 acc = {0.f,0.f,0.f,0.f};
#pragma unroll
    for (int kc = 0; kc < 4; kc++) {
      bf16x8 av = *(const bf16x8*)(Ab + ((arow*256 + kc*64 + lg*16) ^ ((arow&7)<<4)));
      bf16x8 bv = *(const bf16x8*)(wm + (nt*16 + l15)*128 + kc*32 + lg*8);
      acc = __builtin_amdgcn_mfma_f32_16x16x32_bf16(av, bv, acc, 0, 0, 0);
    }
    int col = nt*16 + l15, r0 = mt*16 + lg*4;
    if (col < 100) {
#pragma unroll
      for (int r = 0; r < 4; r++)
        if (r0 + r < 114) Cb[(r0+r)*100 + col] = tobf(acc[r]);
    }
  }
  __syncthreads();
  // ---- P4: build t0c inputs into S[0..199] (S overlays dead Ab) ----
  if (tid < 50) {
    int side = tid / 25, k4 = tid % 25;
    float4 b1q = *(const float4*)&agg_b[100 + k4*4];
    float4 b0q = *(const float4*)&agg_b[k4*4];
    float s0=0.f,s1=0.f,s2=0.f,s3=0.f, r0,r1,r2,r3;
    float inv;
    if (side == 0) {
      for (int a = 0; a < 4; a++) { RELU4(a, b1q, r0,r1,r2,r3); s0+=r0;s1+=r1;s2+=r2;s3+=r3; }
      inv = 0.25f; RELU4(16, b0q, r0,r1,r2,r3);
    } else {
      for (int a = 4; a < 14; a++) { RELU4(a, b1q, r0,r1,r2,r3); s0+=r0;s1+=r1;s2+=r2;s3+=r3; }
      inv = 0.1f; RELU4(17, b0q, r0,r1,r2,r3);
    }
    *(float4*)&S[side*100 + k4*4] = make_float4(inv*s0+r0, inv*s1+r1, inv*s2+r2, inv*s3+r3);
  }
  __syncthreads();
  // ---- P5: t0c = relu(W0 · in + b0) ----
  if (tid < 50) {
    int side = tid / 25, q = tid % 25;
    float acc[4] = {0.f,0.f,0.f,0.f};
    dot4c(W0g, q, &S[side*100], acc);
#pragma unroll
    for (int j = 0; j < 4; j++) {
      int c = q + 25*j;
      S[200 + side*100 + c] = fmaxf(agg_b[c] + acc[j], 0.f);
    }
  }
  __syncthreads();
  // ---- P6: last linear + combine ----
  if (tid < 25) {
    int q = tid;
    float aq[4] = {0.f,0.f,0.f,0.f}, au[4] = {0.f,0.f,0.f,0.f};
    dot4c(WLg, q, &S[200], aq);
    dot4c(WLg, q, &S[300], au);
#pragma unroll
    for (int j = 0; j < 4; j++) {
      int c = q + 25*j;
      float dq = fmaxf(last_b[c] + aq[j], 0.f);
      float du = fmaxf(last_b[c] + au[j], 0.f);
      embhat[item*100 + c] = tobf(w1*dq + w2*du);
    }
  }
#undef RELU4
}

// ---------------------------------------------------------------------------
// P2: fused xin+xg GEMM chain via MFMA. block = timestep t, row = batch b.
//   X[128][224] = [embhat | emb_r | 0]  ->  Y = relu(X@linW^T+lb)  ->  xg
// ---------------------------------------------------------------------------
__global__ __launch_bounds__(512, 1) void k_lin(
    const float* __restrict__ emb_r, const float* __restrict__ lin_b,
    const float* __restrict__ bih, const float* __restrict__ bhh,
    const int* __restrict__ response,
    const __hip_bfloat16* __restrict__ embhat,
    const __hip_bfloat16* __restrict__ linB, const __hip_bfloat16* __restrict__ wihB,
    __hip_bfloat16* __restrict__ xg)
{
  __shared__ __align__(16) char Xt[128*512];   // [128][224] bf16, 512B stride, swizzled
  __shared__ __align__(16) char Yt[128*512];
  const int tid = threadIdx.x, wid = tid >> 6, lane = tid & 63;
  const int l15 = lane & 15, lg = lane >> 4;
  const int t = blockIdx.x;
  // ---- stage X + zero Y k-pad ----
  for (int v = tid; v < 15872; v += 512) {
    if (v < 14336) {
      int b = v / 112, c2 = v % 112; int col = c2*2;
      unsigned val;
      if (col < 100) val = ((const unsigned*)embhat)[(size_t)(t*128 + b)*50 + c2];
      else if (col < 200) {
        int rt = response[b*TT + t];
        val = pk2(emb_r[rt*100 + col - 100], emb_r[rt*100 + col - 99]);
      } else val = 0u;
      *(unsigned*)(Xt + ((b*512 + col*2) ^ ((b&7)<<4))) = val;
    } else {
      int e = v - 14336; int b = e / 12; int col = 200 + (e % 12)*2;
      *(unsigned*)(Yt + ((b*512 + col*2) ^ ((b&7)<<4))) = 0u;
    }
  }
  __syncthreads();
  // ---- GEMM1: Y = relu(X @ linB^T + lin_b)  (8 mt x 13 nt) ----
  for (int tp = wid; tp < 104; tp += 8) {
    int mt = tp / 13, nt = tp % 13;
    int arow = mt*16 + l15;
    f32x4 acc = {0.f,0.f,0.f,0.f};
#pragma unroll
    for (int kc = 0; kc < 7; kc++) {
      bf16x8 av = *(const bf16x8*)(Xt + ((arow*512 + kc*64 + lg*16) ^ ((arow&7)<<4)));
      bf16x8 bv = *(const bf16x8*)(linB + (nt*16 + l15)*224 + kc*32 + lg*8);
      acc = __builtin_amdgcn_mfma_f32_16x16x32_bf16(av, bv, acc, 0, 0, 0);
    }
    int col = nt*16 + l15, r0 = mt*16 + lg*4;
    if (col < 200) {
      float lbv = lin_b[col];
#pragma unroll
      for (int r = 0; r < 4; r++) {
        int row = r0 + r;
        *(__hip_bfloat16*)(Yt + ((row*512 + col*2) ^ ((row&7)<<4))) = tobf(fmaxf(acc[r] + lbv, 0.f));
      }
    }
  }
  __syncthreads();
  // ---- GEMM2: xg = Y @ wihB^T + bih + bhh  (8 mt x 25 nt) ----
  for (int tp = wid; tp < 200; tp += 8) {
    int mt = tp / 25, nt = tp % 25;
    int arow = mt*16 + l15;
    f32x4 acc = {0.f,0.f,0.f,0.f};
#pragma unroll
    for (int kc = 0; kc < 7; kc++) {
      bf16x8 av = *(const bf16x8*)(Yt + ((arow*512 + kc*64 + lg*16) ^ ((arow&7)<<4)));
      bf16x8 bv = *(const bf16x8*)(wihB + (nt*16 + l15)*224 + kc*32 + lg*8);
      acc = __builtin_amdgcn_mfma_f32_16x16x32_bf16(av, bv, acc, 0, 0, 0);
    }
    int col = nt*16 + l15, r0 = mt*16 + lg*4;
    float bs = bih[col] + bhh[col];
#pragma unroll
    for (int r = 0; r < 4; r++)
      xg[(size_t)(t*128 + r0 + r)*400 + col] = tobf(acc[r] + bs);
  }
}

// ---------------------------------------------------------------------------
// P3: per-(b,t) top-10 of dot(eq[question[b,t+1]], eq[question[b,j]]), j<t
// ---------------------------------------------------------------------------
__global__ __launch_bounds__(256, 2) void k_topk(
    const float* __restrict__ emb_q, const int* __restrict__ question,
    int* __restrict__ topidx)
{
  __shared__ float Qb[150*101];
  __shared__ int qid[150];
  __shared__ float tval[1490];
  __shared__ int tidxs[1490];
  const int b = blockIdx.x, tid = threadIdx.x;
  if (tid < 150) qid[tid] = question[b*TT + tid];
  __syncthreads();
  for (int i = tid; i < 15000; i += 256) { int r = i/100, c = i%100; Qb[r*101+c] = emb_q[qid[r]*100+c]; }
  __syncthreads();
  if (tid < TS) {
    const int t = tid;
    float* v = &tval[t*10]; int* ix = &tidxs[t*10];
    for (int p = 0; p < 10; p++) { v[p] = -3.0e38f; ix[p] = 0; }
    const float* qrow = &Qb[(t+1)*101];
    for (int j = 0; j < t; j++) {
      const float* r = &Qb[j*101];
      float s = 0.f;
      for (int k = 0; k < 100; k++) s += qrow[k] * r[k];
      if (s > v[9]) {
        int p = 9;
        while (p > 0 && s > v[p-1]) { v[p] = v[p-1]; ix[p] = ix[p-1]; p--; }
        v[p] = s; ix[p] = j;
      }
    }
    for (int p = 0; p < 10; p++) topidx[(t*BB + b)*10 + p] = ix[p];
  }
}

// ---------------------------------------------------------------------------
// P4: sequential scan — one block per batch element. 4 barriers/step.
//   Whh packed uint4 k-major (8 bf16/read); h consumed as bf16.
// ---------------------------------------------------------------------------
__global__ __launch_bounds__(512, 1) void k_scan(
    const float* __restrict__ emb_q, const float* __restrict__ emb_s,
    const float* __restrict__ Whh,
    const float* __restrict__ qW, const float* __restrict__ qb,
    const float* __restrict__ kW, const float* __restrict__ kb,
    const float* __restrict__ wW, const float* __restrict__ wb,
    const float* __restrict__ h0, const float* __restrict__ c0,
    const int* __restrict__ question, const int* __restrict__ qs_skill,
    const __hip_bfloat16* __restrict__ xg, const int* __restrict__ topidx,
    float* __restrict__ out)
{
  __shared__ __align__(16) uint4 Wh4[5200];      // [k8*400 + j], 8 bf16 each
  __shared__ __align__(16) float hist[15000];    // [150][100]; row 0 stays zero
  __shared__ __align__(16) unsigned hbfu[52];    // h as 104 bf16 (pad 0)
  __shared__ __align__(16) float h_l[100];
  __shared__ __align__(16) float qs_l[500];
  __shared__ __align__(16) float qv[100];
  __shared__ float c_l[100], gates[400], partial[100];
  __shared__ float kv[100], skv[150], wvec[200];
  __shared__ float gmat[55], sq_l[5];
  __shared__ int selidx[11];
  __shared__ float scal[4]; // 0:ck 1:cq 2:wb0 3:sk(current h)
  const int b = blockIdx.x, tid = threadIdx.x;
  // ---- init ----
  for (int i = tid; i < 5200; i += 512) {
    int k8 = i / 400, j = i % 400, kb_ = k8*8;
    float v[8];
#pragma unroll
    for (int r = 0; r < 8; r++) { int k = kb_ + r; v[r] = (k < 100) ? Whh[j*100 + k] : 0.f; }
    Wh4[i] = make_uint4(pk2(v[0],v[1]), pk2(v[2],v[3]), pk2(v[4],v[5]), pk2(v[6],v[7]));
  }
  for (int i = tid; i < 15000; i += 512) hist[i] = 0.f;
  if (tid < 200) wvec[tid] = wW[tid];
  if (tid < 150) skv[tid] = 0.f;
  if (tid >= 256 && tid < 356) { h_l[tid-256] = h0[b*100+tid-256]; c_l[tid-256] = c0[b*100+tid-256]; }
  if (tid == 480) { hbfu[50] = 0u; hbfu[51] = 0u; }
  __syncthreads();
  if (tid < 100) {
    float a1 = 0.f, a2 = 0.f;
    for (int c = 0; c < 100; c++) { a1 += kW[c*100+tid] * wvec[100+c]; a2 += qW[c*100+tid] * wvec[c]; }
    kv[tid] = a1; qv[tid] = a2;
  } else if (tid >= 128 && tid < 178) {
    int l = tid - 128; hbfu[l] = pk2(h_l[2*l], h_l[2*l+1]);
  } else if (tid == 256) {
    float ck = 0.f, cq = 0.f;
    for (int c = 0; c < 100; c++) { ck += kb[c] * wvec[100+c]; cq += qb[c] * wvec[c]; }
    scal[0] = ck; scal[1] = cq; scal[2] = wb[0]; scal[3] = 0.f;
    skv[0] = ck;
    out[b*TT] = 0.5f;
  }
  __syncthreads();
  for (int t = 0; t < TS; t++) {
    // ---- P1: gates (waves 0-6) || qs_l + selidx staging (wave 7) ----
    if (tid < 400) {
      float acc = bf(xg[((size_t)t*BB + b)*400 + tid]);
#pragma unroll
      for (int k8 = 0; k8 < 13; k8++) {
        uint4 w = Wh4[k8*400 + tid];
        uint4 h = *(const uint4*)&hbfu[k8*4];
        acc += blo(w.x)*blo(h.x) + bhi(w.x)*bhi(h.x)
             + blo(w.y)*blo(h.y) + bhi(w.y)*bhi(h.y)
             + blo(w.z)*blo(h.z) + bhi(w.z)*bhi(h.z)
             + blo(w.w)*blo(h.w) + bhi(w.w)*bhi(h.w);
      }
      gates[tid] = acc;
    } else if (tid >= 448) {
      int l = tid - 448;
      const int qn = question[b*TT + t + 1];
      for (int e = l; e < 500; e += 64) {
        int q = e / 100;
        qs_l[e] = (q == 0) ? emb_q[qn*100 + e] : emb_s[qs_skill[qn*4 + q - 1]*100 + e%100];
      }
      if (l < 11) {
        if (l == 0) selidx[0] = -2;
        else {
          int pp = l - 1, cnt = t < 10 ? t : 10;
          selidx[l] = (pp < cnt) ? topidx[((size_t)t*BB + b)*10 + pp] : -1;
        }
      }
    }
    __syncthreads();
    // ---- P2: LSTM pointwise ----
    if (tid < 100) {
      float cc = sigm(gates[100+tid])*c_l[tid] + sigm(gates[tid])*tanhf(gates[200+tid]);
      c_l[tid] = cc;
      float hn = sigm(gates[300+tid])*tanhf(cc);
      h_l[tid] = hn;
      if (t > 0) hist[t*100+tid] = hn;
      partial[tid] = hn * kv[tid];
    }
    __syncthreads();
    // ---- P3: sk reduce (w0) | hbf pack (lanes 64-113) | g/sq dots (128+) ----
    if (tid < 64) {
      float v = partial[tid] + ((tid < 36) ? partial[tid+64] : 0.f);
#pragma unroll
      for (int o = 32; o; o >>= 1) v += __shfl_xor(v, o);
      if (tid == 0) { float s = v + scal[0]; scal[3] = s; if (t > 0) skv[t] = s; }
    } else if (tid < 114) {
      int l = tid - 64; hbfu[l] = pk2(h_l[2*l], h_l[2*l+1]);
    } else if (tid >= 128 && tid < 368) {
      int u = (tid - 128) >> 2, l4 = tid & 3;
      const float* row;
      int q;
      const bool isG = (u < 55);
      if (isG) {
        q = u / 11;
        int s = u % 11;
        int j = (s == 0) ? 0 : selidx[s];
        if (j < 0) j = 0;
        row = (s == 0) ? h_l : &hist[j*100];
      } else { q = u - 55; row = qv; }
      const float4* qsq = (const float4*)&qs_l[q*100];
      const float4* rq = (const float4*)row;
      float part = 0.f;
      int k40 = l4*7, k41 = k40 + 7 > 25 ? 25 : k40 + 7;
      for (int k4 = k40; k4 < k41; k4++) {
        float4 a = qsq[k4], bb = rq[k4];
        part += a.x*bb.x + a.y*bb.y + a.z*bb.z + a.w*bb.w;
      }
      part += __shfl_xor(part, 1);
      part += __shfl_xor(part, 2);
      if (l4 == 0) { if (isG) gmat[u] = part; else sq_l[q] = part + scal[1]; }
    }
    __syncthreads();
    // ---- P4: masked softmax over 55 + y (wave 0) ----
    if (tid < 64) {
      const bool has = (tid < 55);
      int q = has ? tid/11 : 0, s = has ? tid%11 : 0;
      int j = (s == 0) ? 0 : selidx[s];
      bool valid = has && ((s == 0) || (j >= 0));
      if (j < 0) j = 0;
      float sk = (s == 0) ? scal[3] : skv[j];
      float sc = valid ? (sq_l[q] + sk + scal[2]) : -1e9f;
      float gv = has ? gmat[tid] : 0.f;
      float m = sc;
#pragma unroll
      for (int o = 32; o; o >>= 1) m = fmaxf(m, __shfl_xor(m, o));
      float ex = has ? expf(sc - m) : 0.f;
      float num = ex * gv, den = ex;
#pragma unroll
      for (int o = 32; o; o >>= 1) { num += __shfl_xor(num, o); den += __shfl_xor(den, o); }
      if (tid == 0) out[b*TT + t + 1] = sigm(num/den);
    }
    __syncthreads();
  }
}

extern "C" void kernel_launch(void* const* d_in, const int* in_sizes, int n_in,
                              void* d_out, int out_size, void* d_ws, size_t ws_size,
                              hipStream_t stream) {
  const float* emb_q  = (const float*)d_in[0];
  const float* emb_q2 = (const float*)d_in[1];
  const float* emb_s  = (const float*)d_in[2];
  const float* emb_u  = (const float*)d_in[3];
  const float* emb_r  = (const float*)d_in[4];
  const float* w1_q   = (const float*)d_in[5];
  const float* w2_q   = (const float*)d_in[6];
  const float* lin_W  = (const float*)d_in[7];
  const float* lin_b  = (const float*)d_in[8];
  const float* Wih    = (const float*)d_in[9];
  const float* Whh    = (const float*)d_in[10];
  const float* bih    = (const float*)d_in[11];
  const float* bhh    = (const float*)d_in[12];
  const float* agg_W  = (const float*)d_in[13];
  const float* agg_b  = (const float*)d_in[14];
  const float* last_W = (const float*)d_in[15];
  const float* last_b = (const float*)d_in[16];
  const float* qW     = (const float*)d_in[17];
  const float* qb     = (const float*)d_in[18];
  const float* kW     = (const float*)d_in[19];
  const float* kb     = (const float*)d_in[20];
  const float* wW     = (const float*)d_in[21];
  const float* wb     = (const float*)d_in[22];
  const float* h0     = (const float*)d_in[23];
  const float* c0     = (const float*)d_in[24];
  const int* user      = (const int*)d_in[25];
  const int* question  = (const int*)d_in[26];
  const int* response  = (const int*)d_in[27];
  const int* mask      = (const int*)d_in[28];
  const int* q_nb      = (const int*)d_in[29];
  const int* s_nb      = (const int*)d_in[30];
  const int* u_nb      = (const int*)d_in[31];
  const int* q_nb2     = (const int*)d_in[32];
  const int* qs_skill  = (const int*)d_in[33];

  char* ws = (char*)d_ws;
  __hip_bfloat16* embhat = (__hip_bfloat16*)(ws + 0);          //  3,814,400
  __hip_bfloat16* xg     = (__hip_bfloat16*)(ws + 3814400);    // 15,257,600
  int*            topidx = (int*)(ws + 19072000);              //    762,880
  __hip_bfloat16* Wb     = (__hip_bfloat16*)(ws + 19834880);   //    131,072
  uint2*          W0g    = (uint2*)(ws + 19965952);            //     20,000
  uint2*          WLg    = (uint2*)(ws + 19985952);            //     20,000
  uint2*          eq2b   = (uint2*)(ws + 20005952);            // 10,000,000
  uint2*          esb    = (uint2*)(ws + 30005952);            //    400,000
  __hip_bfloat16* linB   = (__hip_bfloat16*)(ws + 30405952);   //     93,184
  __hip_bfloat16* wihB   = (__hip_bfloat16*)(ws + 30499136);   //    179,200 -> 30,678,336 total

  k_prep<<<2048, 256, 0, stream>>>(agg_W, last_W, emb_q2, emb_s, lin_W, Wih,
                                   Wb, W0g, WLg, eq2b, esb, linB, wihB);
  k_embhat<<<NITEM, 512, 0, stream>>>(emb_q, emb_q2, emb_u, w1_q, w2_q,
                                      agg_b, last_b,
                                      user, question, mask, q_nb, s_nb, u_nb, q_nb2,
                                      Wb, W0g, WLg, eq2b, esb, embhat);
  k_lin<<<TS, 512, 0, stream>>>(emb_r, lin_b, bih, bhh, response, embhat,
                                linB, wihB, xg);
  k_topk<<<128, 256, 0, stream>>>(emb_q, question, topidx);
  k_scan<<<128, 512, 0, stream>>>(emb_q, emb_s, Whh, qW, qb, kW, kb, wW, wb,
                                  h0, c0, question, qs_skill, xg, topidx,
                                  (float*)d_out);
}

// Round 8
// 1353.754 us; speedup vs baseline: 2.8189x; 1.1597x over previous
//
#include <hip/hip_runtime.h>
#include <hip/hip_bf16.h>

#define BB 128
#define TT 150
#define TS 149
#define NITEM (TS*BB)

typedef __attribute__((ext_vector_type(8))) short bf16x8;
typedef __attribute__((ext_vector_type(4))) float f32x4;

__device__ __forceinline__ float bf(__hip_bfloat16 x) { return __bfloat162float(x); }
__device__ __forceinline__ __hip_bfloat16 tobf(float x) { return __float2bfloat16(x); }
__device__ __forceinline__ float sigm(float x) { return 1.f / (1.f + expf(-x)); }

__device__ __forceinline__ unsigned pk2(float a, float b) {
  unsigned ua = __float_as_uint(a), ub = __float_as_uint(b);
  ua += 0x7fffu + ((ua >> 16) & 1u);
  ub += 0x7fffu + ((ub >> 16) & 1u);
  return (ua >> 16) | (ub & 0xffff0000u);
}
__device__ __forceinline__ float blo(unsigned u) { return __uint_as_float(u << 16); }
__device__ __forceinline__ float bhi(unsigned u) { return __uint_as_float(u & 0xffff0000u); }

// 4-column dot; W layout [k4*100 + c] uint2 (4 bf16), W in global/L2
__device__ __forceinline__ void dot4c(const uint2* __restrict__ W, int q,
                                      const float* __restrict__ x, float acc[4]) {
  for (int k4 = 0; k4 < 25; k4++) {
    float4 xv = *(const float4*)&x[k4*4];
#pragma unroll
    for (int j = 0; j < 4; j++) {
      uint2 w = W[k4*100 + q + 25*j];
      acc[j] = fmaf(blo(w.x), xv.x, fmaf(bhi(w.x), xv.y,
               fmaf(blo(w.y), xv.z, fmaf(bhi(w.y), xv.w, acc[j]))));
    }
  }
}

// ---------------------------------------------------------------------------
// P0: one-time weight conversion + fused gather tables (gQ/gU/gT1Q/gT1U)
//   gQ[q]  = 0.25*sum_i emb_s[q_nb[q,i]]  + emb_q[q]     (bufQ rows, t0aQ)
//   gU[u]  = 0.1 *sum_k emb_q2[u_nb[u,k]] + emb_u[u]     (bufU rows, t0aU)
//   gT1Q[s]= 0.1 *sum_j emb_q[s_nb[s,j]]  + emb_s[s]     (t1aQ rows)
//   gT1U[q]= 0.2 *sum_p emb_u[q_nb2[q,p]] + emb_q2[q]    (t1aU rows)
// ---------------------------------------------------------------------------
#define PREP_N 3256728
__global__ __launch_bounds__(256, 4) void k_prep(
    const float* __restrict__ agg_W, const float* __restrict__ last_W,
    const float* __restrict__ lin_W, const float* __restrict__ Wih,
    const float* __restrict__ emb_q, const float* __restrict__ emb_q2,
    const float* __restrict__ emb_s, const float* __restrict__ emb_u,
    const int* __restrict__ q_nb, const int* __restrict__ s_nb,
    const int* __restrict__ u_nb, const int* __restrict__ q_nb2,
    __hip_bfloat16* __restrict__ Wb, uint2* __restrict__ W0g, uint2* __restrict__ WLg,
    __hip_bfloat16* __restrict__ linB, __hip_bfloat16* __restrict__ wihB,
    uint2* __restrict__ gQ, uint2* __restrict__ gU,
    uint2* __restrict__ gT1Q, uint2* __restrict__ gT1U)
{
  for (int v = blockIdx.x*256 + threadIdx.x; v < PREP_N; v += gridDim.x*256) {
    if (v < 65536) {
      int m = v >> 14, r = v & 16383, c = r >> 7, k = r & 127;
      const float* src = (m==0) ? agg_W+20000 : (m==1) ? agg_W+10000 : (m==2) ? agg_W : last_W;
      Wb[v] = tobf((c < 100 && k < 100) ? src[c*100+k] : 0.f);
    } else if (v < 70536) {
      int j = v - 65536; int mtx = j / 2500; j %= 2500;
      int k4 = j / 100, c = j % 100;
      const float* src = mtx ? last_W : agg_W;
      float4 a = *(const float4*)&src[c*100 + k4*4];
      (mtx ? WLg : W0g)[j] = make_uint2(pk2(a.x,a.y), pk2(a.z,a.w));
    } else if (v < 117128) {
      int j = v - 70536;                     // linB [208][224]
      int c = j / 224, k = j % 224;
      linB[j] = tobf((c < 200 && k < 200) ? lin_W[c*200+k] : 0.f);
    } else if (v < 206728) {
      int j = v - 117128;                    // wihB [400][224]
      int c = j / 224, k = j % 224;
      wihB[j] = tobf((k < 200) ? Wih[c*200+k] : 0.f);
    } else if (v < 1456728) {                // gQ
      int j = v - 206728, q = j / 25, k4 = j % 25;
      float sx=0.f,sy=0.f,sz=0.f,sw=0.f;
#pragma unroll
      for (int i = 0; i < 4; i++) {
        float4 e = *(const float4*)&emb_s[q_nb[q*4+i]*100 + k4*4];
        sx+=e.x; sy+=e.y; sz+=e.z; sw+=e.w;
      }
      float4 a = *(const float4*)&emb_q[q*100 + k4*4];
      gQ[j] = make_uint2(pk2(0.25f*sx+a.x, 0.25f*sy+a.y), pk2(0.25f*sz+a.z, 0.25f*sw+a.w));
    } else if (v < 1956728) {                // gU
      int j = v - 1456728, u = j / 25, k4 = j % 25;
      float sx=0.f,sy=0.f,sz=0.f,sw=0.f;
      for (int k = 0; k < 10; k++) {
        float4 e = *(const float4*)&emb_q2[u_nb[u*10+k]*100 + k4*4];
        sx+=e.x; sy+=e.y; sz+=e.z; sw+=e.w;
      }
      float4 a = *(const float4*)&emb_u[u*100 + k4*4];
      gU[j] = make_uint2(pk2(0.1f*sx+a.x, 0.1f*sy+a.y), pk2(0.1f*sz+a.z, 0.1f*sw+a.w));
    } else if (v < 2006728) {                // gT1Q (skills)
      int j = v - 1956728, s = j / 25, k4 = j % 25;
      float sx=0.f,sy=0.f,sz=0.f,sw=0.f;
      for (int jj = 0; jj < 10; jj++) {
        float4 e = *(const float4*)&emb_q[s_nb[s*10+jj]*100 + k4*4];
        sx+=e.x; sy+=e.y; sz+=e.z; sw+=e.w;
      }
      float4 a = *(const float4*)&emb_s[s*100 + k4*4];
      gT1Q[j] = make_uint2(pk2(0.1f*sx+a.x, 0.1f*sy+a.y), pk2(0.1f*sz+a.z, 0.1f*sw+a.w));
    } else {                                 // gT1U (questions)
      int j = v - 2006728, q = j / 25, k4 = j % 25;
      float sx=0.f,sy=0.f,sz=0.f,sw=0.f;
#pragma unroll
      for (int p = 0; p < 5; p++) {
        float4 e = *(const float4*)&emb_u[q_nb2[q*5+p]*100 + k4*4];
        sx+=e.x; sy+=e.y; sz+=e.z; sw+=e.w;
      }
      float4 a = *(const float4*)&emb_q2[q*100 + k4*4];
      gT1U[j] = make_uint2(pk2(0.2f*sx+a.x, 0.2f*sy+a.y), pk2(0.2f*sz+a.z, 0.2f*sw+a.w));
    }
  }
}

// ---------------------------------------------------------------------------
// P1: multi-hop aggregate, one item per block; table-based single-row gathers.
// A rows: 0-39 bufQ | 40-89 bufU | 96-99 t1aQ | 100-109 t1aU | 112 t0aQ | 113 t0aU
// ---------------------------------------------------------------------------
__global__ __launch_bounds__(512, 6) void k_embhat(
    const float* __restrict__ emb_q, const float* __restrict__ emb_q2,
    const float* __restrict__ w1_q, const float* __restrict__ w2_q,
    const float* __restrict__ agg_b, const float* __restrict__ last_b,
    const int* __restrict__ user, const int* __restrict__ question, const int* __restrict__ mask,
    const int* __restrict__ q_nb, const int* __restrict__ s_nb,
    const int* __restrict__ u_nb, const int* __restrict__ q_nb2,
    const __hip_bfloat16* __restrict__ Wb, const uint2* __restrict__ W0g,
    const uint2* __restrict__ WLg,
    const uint2* __restrict__ gQ, const uint2* __restrict__ gU,
    const uint2* __restrict__ gT1Q, const uint2* __restrict__ gT1U,
    __hip_bfloat16* __restrict__ embhat)
{
  __shared__ __align__(16) char Ab[114*256];        // [114 rows][128 k] bf16 swizzled
  __shared__ __hip_bfloat16 Cb[114*100];            // C rows bf16
  __shared__ int n2[40], m2[50], n1[4], m1[10];
  float* S = (float*)Ab;                            // overlays Ab after P3 (dead)
  const int tid = threadIdx.x, wid = tid >> 6, lane = tid & 63;
  const int l15 = lane & 15, lg = lane >> 4;
  const int item = blockIdx.x;
  const int t = item / BB, b = item % BB;
  const int qt = question[b*TT + t];
  const float w1 = w1_q[0], w2 = w2_q[0];

  if (mask[b*TT + t] != 1) {
    if (tid < 50) {
      const float2 q = *(const float2*)&emb_q[qt*100 + tid*2];
      const float2 p = *(const float2*)&emb_q2[qt*100 + tid*2];
      ((unsigned*)embhat)[item*50 + tid] = pk2(w1*q.x + w2*p.x, w1*q.y + w2*p.y);
    }
    return;
  }
  const int ut = user[b*TT + t];

  // ---- phase A: index staging + zero-pads ----
  for (int v = tid; v < 1102; v += 512) {
    if (v < 40) { int n1a = q_nb[qt*4 + v/10]; n2[v] = s_nb[n1a*10 + v%10]; }
    else if (v < 90) { int e = v-40; int m1a = u_nb[ut*10 + e/5]; m2[e] = q_nb2[m1a*5 + e%5]; }
    else if (v < 94) { n1[v-90] = q_nb[qt*4 + (v-90)]; }
    else if (v < 104) { m1[v-94] = u_nb[ut*10 + (v-94)]; }
    else {
      int z = v - 104, row, k4;
      if (z < 798) { row = z/7; k4 = 25 + z%7; }                       // k-pad
      else if (z < 948) { int e = z-798; row = 90 + e/25; k4 = e%25; } // rows 90-95
      else { int e = z-948; row = 110 + e/25; k4 = e%25; }             // rows 110-111
      int ofs = (row*256 + k4*8) ^ ((row&7)<<4);
      *(uint2*)(Ab + ofs) = make_uint2(0u, 0u);
    }
  }
  __syncthreads();
  // ---- phase B: single-row table gathers ----
  for (int v = tid; v < 2650; v += 512) {
    const uint2* src; int row, k4;
    if (v < 1000) { int r = v/25; k4 = v%25; src = &gQ[n2[r]*25]; row = r; }
    else if (v < 2250) { int e = v-1000; int r = e/25; k4 = e%25; src = &gU[m2[r]*25]; row = 40+r; }
    else if (v < 2350) { int e = v-2250; int a = e/25; k4 = e%25; src = &gT1Q[n1[a]*25]; row = 96+a; }
    else if (v < 2600) { int e = v-2350; int a = e/25; k4 = e%25; src = &gT1U[m1[a]*25]; row = 100+a; }
    else if (v < 2625) { k4 = v-2600; src = &gQ[qt*25]; row = 112; }
    else { k4 = v-2625; src = &gU[ut*25]; row = 113; }
    int ofs = (row*256 + k4*8) ^ ((row&7)<<4);
    *(uint2*)(Ab + ofs) = src[k4];
  }
  __syncthreads();
  // ---- P1: L1 MFMA — mt 0-5: W2, mt 6: W1, mt 7: W0 ----
  for (int tp = wid; tp < 56; tp += 8) {
    int mt = tp / 7, nt = tp % 7;
    const __hip_bfloat16* wm = Wb + ((mt < 6) ? 0 : (mt == 6) ? 16384 : 32768);
    int arow = mt*16 + l15; if (arow > 113) arow = 113;
    f32x4 acc = {0.f,0.f,0.f,0.f};
#pragma unroll
    for (int kc = 0; kc < 4; kc++) {
      bf16x8 av = *(const bf16x8*)(Ab + ((arow*256 + kc*64 + lg*16) ^ ((arow&7)<<4)));
      bf16x8 bv = *(const bf16x8*)(wm + (nt*16 + l15)*128 + kc*32 + lg*8);
      acc = __builtin_amdgcn_mfma_f32_16x16x32_bf16(av, bv, acc, 0, 0, 0);
    }
    int col = nt*16 + l15, r0 = mt*16 + lg*4;
    if (col < 100) {
#pragma unroll
      for (int r = 0; r < 4; r++)
        if (r0 + r < 114) Cb[(r0+r)*100 + col] = tobf(acc[r]);
    }
  }
  __syncthreads();
  // ---- P2: reduce + build L2 inputs (A rows 0-13 t1b-in, 16-17 t0b-in) ----
  for (int v = tid; v < 400; v += 512) {
    int k4 = (v < 350) ? v % 25 : (v - 350) % 25;
    float4 b2q = *(const float4*)&agg_b[200 + k4*4];
    float4 b1q = *(const float4*)&agg_b[100 + k4*4];
    float4 b0q = *(const float4*)&agg_b[k4*4];
    float x0, x1, x2, x3; int row;
#define RELU4(rr, bq, r0v,r1v,r2v,r3v) { \
    r0v = fmaxf(bf(Cb[(rr)*100 + k4*4+0]) + bq.x, 0.f); \
    r1v = fmaxf(bf(Cb[(rr)*100 + k4*4+1]) + bq.y, 0.f); \
    r2v = fmaxf(bf(Cb[(rr)*100 + k4*4+2]) + bq.z, 0.f); \
    r3v = fmaxf(bf(Cb[(rr)*100 + k4*4+3]) + bq.w, 0.f); }
    if (v < 350) {
      int a = v / 25;
      float s0=0.f,s1=0.f,s2=0.f,s3=0.f, r0,r1,r2,r3;
      float inv;
      if (a < 4) {
        for (int s = 0; s < 10; s++) { RELU4(a*10+s, b2q, r0,r1,r2,r3); s0+=r0;s1+=r1;s2+=r2;s3+=r3; }
        inv = 0.1f; RELU4(96+a, b1q, r0,r1,r2,r3);
      } else {
        int au = a - 4;
        for (int p = 0; p < 5; p++) { RELU4(40+au*5+p, b2q, r0,r1,r2,r3); s0+=r0;s1+=r1;s2+=r2;s3+=r3; }
        inv = 0.2f; RELU4(100+au, b1q, r0,r1,r2,r3);
      }
      x0 = inv*s0+r0; x1 = inv*s1+r1; x2 = inv*s2+r2; x3 = inv*s3+r3;
      row = a;
    } else {
      float s0=0.f,s1=0.f,s2=0.f,s3=0.f, r0,r1,r2,r3;
      if (v < 375) {
        for (int a = 0; a < 4; a++) { RELU4(96+a, b1q, r0,r1,r2,r3); s0+=r0;s1+=r1;s2+=r2;s3+=r3; }
        RELU4(112, b0q, r0,r1,r2,r3);
        x0 = 0.25f*s0+r0; x1 = 0.25f*s1+r1; x2 = 0.25f*s2+r2; x3 = 0.25f*s3+r3;
        row = 16;
      } else {
        for (int a = 0; a < 10; a++) { RELU4(100+a, b1q, r0,r1,r2,r3); s0+=r0;s1+=r1;s2+=r2;s3+=r3; }
        RELU4(113, b0q, r0,r1,r2,r3);
        x0 = 0.1f*s0+r0; x1 = 0.1f*s1+r1; x2 = 0.1f*s2+r2; x3 = 0.1f*s3+r3;
        row = 17;
      }
    }
    int ofs = (row*256 + k4*8) ^ ((row&7)<<4);
    *(uint2*)(Ab + ofs) = make_uint2(pk2(x0,x1), pk2(x2,x3));
  }
  __syncthreads();
  // ---- P3: L2 MFMA — mt0 (rows 0-15, W1), mt1 (rows 16-31, W0) ----
  for (int tp = wid; tp < 14; tp += 8) {
    int mt = tp / 7, nt = tp % 7;
    const __hip_bfloat16* wm = Wb + (mt ? 32768 : 16384);
    int arow = mt*16 + l15;
    f32x4 acc = {0.f,0.f,0.f,0.f};
#pragma unroll
    for (int kc = 0; kc < 4; kc++) {
      bf16x8 av = *(const bf16x8*)(Ab + ((arow*256 + kc*64 + lg*16) ^ ((arow&7)<<4)));
      bf16x8 bv = *(const bf16x8*)(wm + (nt*16 + l15)*128 + kc*32 + lg*8);
      acc = __builtin_amdgcn_mfma_f32_16x16x32_bf16(av, bv, acc, 0, 0, 0);
    }
    int col = nt*16 + l15, r0 = mt*16 + lg*4;
    if (col < 100) {
#pragma unroll
      for (int r = 0; r < 4; r++)
        if (r0 + r < 114) Cb[(r0+r)*100 + col] = tobf(acc[r]);
    }
  }
  __syncthreads();
  // ---- P4: build t0c inputs into S[0..199] (S overlays dead Ab) ----
  if (tid < 50) {
    int side = tid / 25, k4 = tid % 25;
    float4 b1q = *(const float4*)&agg_b[100 + k4*4];
    float4 b0q = *(const float4*)&agg_b[k4*4];
    float s0=0.f,s1=0.f,s2=0.f,s3=0.f, r0,r1,r2,r3;
    float inv;
    if (side == 0) {
      for (int a = 0; a < 4; a++) { RELU4(a, b1q, r0,r1,r2,r3); s0+=r0;s1+=r1;s2+=r2;s3+=r3; }
      inv = 0.25f; RELU4(16, b0q, r0,r1,r2,r3);
    } else {
      for (int a = 4; a < 14; a++) { RELU4(a, b1q, r0,r1,r2,r3); s0+=r0;s1+=r1;s2+=r2;s3+=r3; }
      inv = 0.1f; RELU4(17, b0q, r0,r1,r2,r3);
    }
    *(float4*)&S[side*100 + k4*4] = make_float4(inv*s0+r0, inv*s1+r1, inv*s2+r2, inv*s3+r3);
  }
  __syncthreads();
  // ---- P5: t0c = relu(W0 · in + b0) ----
  if (tid < 50) {
    int side = tid / 25, q = tid % 25;
    float acc[4] = {0.f,0.f,0.f,0.f};
    dot4c(W0g, q, &S[side*100], acc);
#pragma unroll
    for (int j = 0; j < 4; j++) {
      int c = q + 25*j;
      S[200 + side*100 + c] = fmaxf(agg_b[c] + acc[j], 0.f);
    }
  }
  __syncthreads();
  // ---- P6: last linear + combine ----
  if (tid < 25) {
    int q = tid;
    float aq[4] = {0.f,0.f,0.f,0.f}, au[4] = {0.f,0.f,0.f,0.f};
    dot4c(WLg, q, &S[200], aq);
    dot4c(WLg, q, &S[300], au);
#pragma unroll
    for (int j = 0; j < 4; j++) {
      int c = q + 25*j;
      float dq = fmaxf(last_b[c] + aq[j], 0.f);
      float du = fmaxf(last_b[c] + au[j], 0.f);
      embhat[item*100 + c] = tobf(w1*dq + w2*du);
    }
  }
#undef RELU4
}

// ---------------------------------------------------------------------------
// P2: fused xin+xg GEMM chain via MFMA. block = timestep t, row = batch b.
// ---------------------------------------------------------------------------
__global__ __launch_bounds__(512, 1) void k_lin(
    const float* __restrict__ emb_r, const float* __restrict__ lin_b,
    const float* __restrict__ bih, const float* __restrict__ bhh,
    const int* __restrict__ response,
    const __hip_bfloat16* __restrict__ embhat,
    const __hip_bfloat16* __restrict__ linB, const __hip_bfloat16* __restrict__ wihB,
    __hip_bfloat16* __restrict__ xg)
{
  __shared__ __align__(16) char Xt[128*512];   // [128][224] bf16, 512B stride, swizzled
  __shared__ __align__(16) char Yt[128*512];
  const int tid = threadIdx.x, wid = tid >> 6, lane = tid & 63;
  const int l15 = lane & 15, lg = lane >> 4;
  const int t = blockIdx.x;
  for (int v = tid; v < 15872; v += 512) {
    if (v < 14336) {
      int b = v / 112, c2 = v % 112; int col = c2*2;
      unsigned val;
      if (col < 100) val = ((const unsigned*)embhat)[(size_t)(t*128 + b)*50 + c2];
      else if (col < 200) {
        int rt = response[b*TT + t];
        val = pk2(emb_r[rt*100 + col - 100], emb_r[rt*100 + col - 99]);
      } else val = 0u;
      *(unsigned*)(Xt + ((b*512 + col*2) ^ ((b&7)<<4))) = val;
    } else {
      int e = v - 14336; int b = e / 12; int col = 200 + (e % 12)*2;
      *(unsigned*)(Yt + ((b*512 + col*2) ^ ((b&7)<<4))) = 0u;
    }
  }
  __syncthreads();
  for (int tp = wid; tp < 104; tp += 8) {
    int mt = tp / 13, nt = tp % 13;
    int arow = mt*16 + l15;
    f32x4 acc = {0.f,0.f,0.f,0.f};
#pragma unroll
    for (int kc = 0; kc < 7; kc++) {
      bf16x8 av = *(const bf16x8*)(Xt + ((arow*512 + kc*64 + lg*16) ^ ((arow&7)<<4)));
      bf16x8 bv = *(const bf16x8*)(linB + (nt*16 + l15)*224 + kc*32 + lg*8);
      acc = __builtin_amdgcn_mfma_f32_16x16x32_bf16(av, bv, acc, 0, 0, 0);
    }
    int col = nt*16 + l15, r0 = mt*16 + lg*4;
    if (col < 200) {
      float lbv = lin_b[col];
#pragma unroll
      for (int r = 0; r < 4; r++) {
        int row = r0 + r;
        *(__hip_bfloat16*)(Yt + ((row*512 + col*2) ^ ((row&7)<<4))) = tobf(fmaxf(acc[r] + lbv, 0.f));
      }
    }
  }
  __syncthreads();
  for (int tp = wid; tp < 200; tp += 8) {
    int mt = tp / 25, nt = tp % 25;
    int arow = mt*16 + l15;
    f32x4 acc = {0.f,0.f,0.f,0.f};
#pragma unroll
    for (int kc = 0; kc < 7; kc++) {
      bf16x8 av = *(const bf16x8*)(Yt + ((arow*512 + kc*64 + lg*16) ^ ((arow&7)<<4)));
      bf16x8 bv = *(const bf16x8*)(wihB + (nt*16 + l15)*224 + kc*32 + lg*8);
      acc = __builtin_amdgcn_mfma_f32_16x16x32_bf16(av, bv, acc, 0, 0, 0);
    }
    int col = nt*16 + l15, r0 = mt*16 + lg*4;
    float bs = bih[col] + bhh[col];
#pragma unroll
    for (int r = 0; r < 4; r++)
      xg[(size_t)(t*128 + r0 + r)*400 + col] = tobf(acc[r] + bs);
  }
}

// ---------------------------------------------------------------------------
// P3: per-(b,t) top-10, float4 inner dot (stride 104)
// ---------------------------------------------------------------------------
__global__ __launch_bounds__(256, 2) void k_topk(
    const float* __restrict__ emb_q, const int* __restrict__ question,
    int* __restrict__ topidx)
{
  __shared__ __align__(16) float Qb[150*104];
  __shared__ int qid[150];
  __shared__ float tval[1490];
  __shared__ int tidxs[1490];
  const int b = blockIdx.x, tid = threadIdx.x;
  if (tid < 150) qid[tid] = question[b*TT + tid];
  __syncthreads();
  for (int i = tid; i < 15000; i += 256) { int r = i/100, c = i%100; Qb[r*104+c] = emb_q[qid[r]*100+c]; }
  __syncthreads();
  if (tid < TS) {
    const int t = tid;
    float* v = &tval[t*10]; int* ix = &tidxs[t*10];
    for (int p = 0; p < 10; p++) { v[p] = -3.0e38f; ix[p] = 0; }
    const float4* qrow = (const float4*)&Qb[(t+1)*104];
    for (int j = 0; j < t; j++) {
      const float4* r = (const float4*)&Qb[j*104];
      float s = 0.f;
#pragma unroll
      for (int k4 = 0; k4 < 25; k4++) {
        float4 a = qrow[k4], c = r[k4];
        s += a.x*c.x + a.y*c.y + a.z*c.z + a.w*c.w;
      }
      if (s > v[9]) {
        int p = 9;
        while (p > 0 && s > v[p-1]) { v[p] = v[p-1]; ix[p] = ix[p-1]; p--; }
        v[p] = s; ix[p] = j;
      }
    }
    for (int p = 0; p < 10; p++) topidx[(t*BB + b)*10 + p] = ix[p];
  }
}

// ---------------------------------------------------------------------------
// P4: sequential scan — 3 barriers/step (parity-buffered qs_l/selidx)
// ---------------------------------------------------------------------------
__global__ __launch_bounds__(512, 1) void k_scan(
    const float* __restrict__ emb_q, const float* __restrict__ emb_s,
    const float* __restrict__ Whh,
    const float* __restrict__ qW, const float* __restrict__ qb,
    const float* __restrict__ kW, const float* __restrict__ kb,
    const float* __restrict__ wW, const float* __restrict__ wb,
    const float* __restrict__ h0, const float* __restrict__ c0,
    const int* __restrict__ question, const int* __restrict__ qs_skill,
    const __hip_bfloat16* __restrict__ xg, const int* __restrict__ topidx,
    float* __restrict__ out)
{
  __shared__ __align__(16) uint4 Wh4[5200];      // [k8*400 + j], 8 bf16 each
  __shared__ __align__(16) float hist[15000];    // [150][100]; row 0 stays zero
  __shared__ __align__(16) unsigned hbfu[52];    // h as 104 bf16 (pad 0)
  __shared__ __align__(16) float h_l[100];
  __shared__ __align__(16) float qs_l[1000];     // parity-buffered [2][500]
  __shared__ __align__(16) float qv[100];
  __shared__ float c_l[100], gates[400], partial[100];
  __shared__ float kv[100], skv[150], wvec[200];
  __shared__ float gmat[55], sq_l[5];
  __shared__ int selidx[22];                     // parity-buffered [2][11]
  __shared__ float scal[4];
  const int b = blockIdx.x, tid = threadIdx.x;
  for (int i = tid; i < 5200; i += 512) {
    int k8 = i / 400, j = i % 400, kb_ = k8*8;
    float v[8];
#pragma unroll
    for (int r = 0; r < 8; r++) { int k = kb_ + r; v[r] = (k < 100) ? Whh[j*100 + k] : 0.f; }
    Wh4[i] = make_uint4(pk2(v[0],v[1]), pk2(v[2],v[3]), pk2(v[4],v[5]), pk2(v[6],v[7]));
  }
  for (int i = tid; i < 15000; i += 512) hist[i] = 0.f;
  if (tid < 200) wvec[tid] = wW[tid];
  if (tid < 150) skv[tid] = 0.f;
  if (tid >= 256 && tid < 356) { h_l[tid-256] = h0[b*100+tid-256]; c_l[tid-256] = c0[b*100+tid-256]; }
  if (tid == 480) { hbfu[50] = 0u; hbfu[51] = 0u; }
  __syncthreads();
  if (tid < 100) {
    float a1 = 0.f, a2 = 0.f;
    for (int c = 0; c < 100; c++) { a1 += kW[c*100+tid] * wvec[100+c]; a2 += qW[c*100+tid] * wvec[c]; }
    kv[tid] = a1; qv[tid] = a2;
  } else if (tid >= 128 && tid < 178) {
    int l = tid - 128; hbfu[l] = pk2(h_l[2*l], h_l[2*l+1]);
  } else if (tid == 256) {
    float ck = 0.f, cq = 0.f;
    for (int c = 0; c < 100; c++) { ck += kb[c] * wvec[100+c]; cq += qb[c] * wvec[c]; }
    scal[0] = ck; scal[1] = cq; scal[2] = wb[0]; scal[3] = 0.f;
    skv[0] = ck;
    out[b*TT] = 0.5f;
  }
  __syncthreads();
  for (int t = 0; t < TS; t++) {
    const int p = t & 1;
    // ---- P1: gates (lanes 0-399) || qs_l/selidx staging (wave 7) ----
    if (tid < 400) {
      float acc = bf(xg[((size_t)t*BB + b)*400 + tid]);
#pragma unroll
      for (int k8 = 0; k8 < 13; k8++) {
        uint4 w = Wh4[k8*400 + tid];
        uint4 h = *(const uint4*)&hbfu[k8*4];
        acc += blo(w.x)*blo(h.x) + bhi(w.x)*bhi(h.x)
             + blo(w.y)*blo(h.y) + bhi(w.y)*bhi(h.y)
             + blo(w.z)*blo(h.z) + bhi(w.z)*bhi(h.z)
             + blo(w.w)*blo(h.w) + bhi(w.w)*bhi(h.w);
      }
      gates[tid] = acc;
    } else if (tid >= 448) {
      int l = tid - 448;
      const int qn = question[b*TT + t + 1];
      for (int e = l; e < 500; e += 64) {
        int q = e / 100;
        qs_l[p*500 + e] = (q == 0) ? emb_q[qn*100 + e] : emb_s[qs_skill[qn*4 + q - 1]*100 + e%100];
      }
      if (l < 11) {
        if (l == 0) selidx[p*11] = -2;
        else {
          int pp = l - 1, cnt = t < 10 ? t : 10;
          selidx[p*11 + l] = (pp < cnt) ? topidx[((size_t)t*BB + b)*10 + pp] : -1;
        }
      }
    }
    __syncthreads();
    // ---- P2: LSTM pointwise ----
    if (tid < 100) {
      float cc = sigm(gates[100+tid])*c_l[tid] + sigm(gates[tid])*tanhf(gates[200+tid]);
      c_l[tid] = cc;
      float hn = sigm(gates[300+tid])*tanhf(cc);
      h_l[tid] = hn;
      if (t > 0) hist[t*100+tid] = hn;
      partial[tid] = hn * kv[tid];
    }
    __syncthreads();
    // ---- P3: sk reduce (w0) | hbf pack (64-113) | g/sq dots (128-367) ----
    if (tid < 64) {
      float v = partial[tid] + ((tid < 36) ? partial[tid+64] : 0.f);
#pragma unroll
      for (int o = 32; o; o >>= 1) v += __shfl_xor(v, o);
      if (tid == 0) { float s = v + scal[0]; scal[3] = s; if (t > 0) skv[t] = s; }
    } else if (tid < 114) {
      int l = tid - 64; hbfu[l] = pk2(h_l[2*l], h_l[2*l+1]);
    } else if (tid >= 128 && tid < 368) {
      int u = (tid - 128) >> 2, l4 = tid & 3;
      const float* row;
      int q;
      const bool isG = (u < 55);
      if (isG) {
        q = u / 11;
        int s = u % 11;
        int j = (s == 0) ? 0 : selidx[p*11 + s];
        if (j < 0) j = 0;
        row = (s == 0) ? h_l : &hist[j*100];
      } else { q = u - 55; row = qv; }
      const float4* qsq = (const float4*)&qs_l[p*500 + q*100];
      const float4* rq = (const float4*)row;
      float part = 0.f;
      int k40 = l4*7, k41 = k40 + 7 > 25 ? 25 : k40 + 7;
      for (int k4 = k40; k4 < k41; k4++) {
        float4 a = qsq[k4], bb = rq[k4];
        part += a.x*bb.x + a.y*bb.y + a.z*bb.z + a.w*bb.w;
      }
      part += __shfl_xor(part, 1);
      part += __shfl_xor(part, 2);
      if (l4 == 0) { if (isG) gmat[u] = part; else sq_l[q] = part + scal[1]; }
    }
    __syncthreads();
    // ---- P4: masked softmax over 55 + y (wave 0) — no trailing barrier ----
    if (tid < 64) {
      const bool has = (tid < 55);
      int q = has ? tid/11 : 0, s = has ? tid%11 : 0;
      int j = (s == 0) ? 0 : selidx[p*11 + s];
      bool valid = has && ((s == 0) || (j >= 0));
      if (j < 0) j = 0;
      float sk = (s == 0) ? scal[3] : skv[j];
      float sc = valid ? (sq_l[q] + sk + scal[2]) : -1e9f;
      float gv = has ? gmat[tid] : 0.f;
      float m = sc;
#pragma unroll
      for (int o = 32; o; o >>= 1) m = fmaxf(m, __shfl_xor(m, o));
      float ex = has ? expf(sc - m) : 0.f;
      float num = ex * gv, den = ex;
#pragma unroll
      for (int o = 32; o; o >>= 1) { num += __shfl_xor(num, o); den += __shfl_xor(den, o); }
      if (tid == 0) out[b*TT + t + 1] = sigm(num/den);
    }
  }
}

extern "C" void kernel_launch(void* const* d_in, const int* in_sizes, int n_in,
                              void* d_out, int out_size, void* d_ws, size_t ws_size,
                              hipStream_t stream) {
  const float* emb_q  = (const float*)d_in[0];
  const float* emb_q2 = (const float*)d_in[1];
  const float* emb_s  = (const float*)d_in[2];
  const float* emb_u  = (const float*)d_in[3];
  const float* emb_r  = (const float*)d_in[4];
  const float* w1_q   = (const float*)d_in[5];
  const float* w2_q   = (const float*)d_in[6];
  const float* lin_W  = (const float*)d_in[7];
  const float* lin_b  = (const float*)d_in[8];
  const float* Wih    = (const float*)d_in[9];
  const float* Whh    = (const float*)d_in[10];
  const float* bih    = (const float*)d_in[11];
  const float* bhh    = (const float*)d_in[12];
  const float* agg_W  = (const float*)d_in[13];
  const float* agg_b  = (const float*)d_in[14];
  const float* last_W = (const float*)d_in[15];
  const float* last_b = (const float*)d_in[16];
  const float* qW     = (const float*)d_in[17];
  const float* qb     = (const float*)d_in[18];
  const float* kW     = (const float*)d_in[19];
  const float* kb     = (const float*)d_in[20];
  const float* wW     = (const float*)d_in[21];
  const float* wb     = (const float*)d_in[22];
  const float* h0     = (const float*)d_in[23];
  const float* c0     = (const float*)d_in[24];
  const int* user      = (const int*)d_in[25];
  const int* question  = (const int*)d_in[26];
  const int* response  = (const int*)d_in[27];
  const int* mask      = (const int*)d_in[28];
  const int* q_nb      = (const int*)d_in[29];
  const int* s_nb      = (const int*)d_in[30];
  const int* u_nb      = (const int*)d_in[31];
  const int* q_nb2     = (const int*)d_in[32];
  const int* qs_skill  = (const int*)d_in[33];

  char* ws = (char*)d_ws;
  __hip_bfloat16* embhat = (__hip_bfloat16*)(ws + 0);          //  3,814,400
  __hip_bfloat16* xg     = (__hip_bfloat16*)(ws + 3814400);    // 15,257,600
  int*            topidx = (int*)(ws + 19072000);              //    762,880
  __hip_bfloat16* Wb     = (__hip_bfloat16*)(ws + 19834880);   //    131,072
  uint2*          W0g    = (uint2*)(ws + 19965952);            //     20,000
  uint2*          WLg    = (uint2*)(ws + 19985952);            //     20,000
  __hip_bfloat16* linB   = (__hip_bfloat16*)(ws + 20005952);   //     93,184
  __hip_bfloat16* wihB   = (__hip_bfloat16*)(ws + 20099136);   //    179,200
  uint2*          gQ     = (uint2*)(ws + 20278336);            // 10,000,000
  uint2*          gU     = (uint2*)(ws + 30278336);            //  4,000,000
  uint2*          gT1Q   = (uint2*)(ws + 34278336);            //    400,000
  uint2*          gT1U   = (uint2*)(ws + 34678336);            // 10,000,000 -> 44,678,336

  k_prep<<<2048, 256, 0, stream>>>(agg_W, last_W, lin_W, Wih,
                                   emb_q, emb_q2, emb_s, emb_u,
                                   q_nb, s_nb, u_nb, q_nb2,
                                   Wb, W0g, WLg, linB, wihB, gQ, gU, gT1Q, gT1U);
  k_embhat<<<NITEM, 512, 0, stream>>>(emb_q, emb_q2, w1_q, w2_q,
                                      agg_b, last_b,
                                      user, question, mask, q_nb, s_nb, u_nb, q_nb2,
                                      Wb, W0g, WLg, gQ, gU, gT1Q, gT1U, embhat);
  k_lin<<<TS, 512, 0, stream>>>(emb_r, lin_b, bih, bhh, response, embhat,
                                linB, wihB, xg);
  k_topk<<<128, 256, 0, stream>>>(emb_q, question, topidx);
  k_scan<<<128, 512, 0, stream>>>(emb_q, emb_s, Whh, qW, qb, kW, kb, wW, wb,
                                  h0, c0, question, qs_skill, xg, topidx,
                                  (float*)d_out);
}

// Round 9
// 1087.181 us; speedup vs baseline: 3.5101x; 1.2452x over previous
//
#include <hip/hip_runtime.h>
#include <hip/hip_bf16.h>

#define BB 128
#define TT 150
#define TS 149
#define NITEM (TS*BB)

typedef __attribute__((ext_vector_type(8))) short bf16x8;
typedef __attribute__((ext_vector_type(4))) float f32x4;

__device__ __forceinline__ float bf(__hip_bfloat16 x) { return __bfloat162float(x); }
__device__ __forceinline__ __hip_bfloat16 tobf(float x) { return __float2bfloat16(x); }
__device__ __forceinline__ float sigm(float x) { return 1.f / (1.f + expf(-x)); }

__device__ __forceinline__ unsigned pk2(float a, float b) {
  unsigned ua = __float_as_uint(a), ub = __float_as_uint(b);
  ua += 0x7fffu + ((ua >> 16) & 1u);
  ub += 0x7fffu + ((ub >> 16) & 1u);
  return (ua >> 16) | (ub & 0xffff0000u);
}
__device__ __forceinline__ float blo(unsigned u) { return __uint_as_float(u << 16); }
__device__ __forceinline__ float bhi(unsigned u) { return __uint_as_float(u & 0xffff0000u); }

// 4-column dot; W layout [k4*100 + c] uint2 (4 bf16), W in global/L2
__device__ __forceinline__ void dot4c(const uint2* __restrict__ W, int q,
                                      const float* __restrict__ x, float acc[4]) {
  for (int k4 = 0; k4 < 25; k4++) {
    float4 xv = *(const float4*)&x[k4*4];
#pragma unroll
    for (int j = 0; j < 4; j++) {
      uint2 w = W[k4*100 + q + 25*j];
      acc[j] = fmaf(blo(w.x), xv.x, fmaf(bhi(w.x), xv.y,
               fmaf(blo(w.y), xv.z, fmaf(bhi(w.y), xv.w, acc[j]))));
    }
  }
}

// ---------------------------------------------------------------------------
// P0: one-time weight conversion + fused gather tables + WhP/kvqv
// ---------------------------------------------------------------------------
#define PREP_N 3262131
__global__ __launch_bounds__(256, 4) void k_prep(
    const float* __restrict__ agg_W, const float* __restrict__ last_W,
    const float* __restrict__ lin_W, const float* __restrict__ Wih,
    const float* __restrict__ emb_q, const float* __restrict__ emb_q2,
    const float* __restrict__ emb_s, const float* __restrict__ emb_u,
    const int* __restrict__ q_nb, const int* __restrict__ s_nb,
    const int* __restrict__ u_nb, const int* __restrict__ q_nb2,
    const float* __restrict__ Whh,
    const float* __restrict__ qW, const float* __restrict__ qb,
    const float* __restrict__ kW, const float* __restrict__ kb,
    const float* __restrict__ wW, const float* __restrict__ wb,
    __hip_bfloat16* __restrict__ Wb, uint2* __restrict__ W0g, uint2* __restrict__ WLg,
    __hip_bfloat16* __restrict__ linB, __hip_bfloat16* __restrict__ wihB,
    uint2* __restrict__ gQ, uint2* __restrict__ gU,
    uint2* __restrict__ gT1Q, uint2* __restrict__ gT1U,
    uint4* __restrict__ WhP, float* __restrict__ kvqv)
{
  for (int v = blockIdx.x*256 + threadIdx.x; v < PREP_N; v += gridDim.x*256) {
    if (v < 65536) {
      int m = v >> 14, r = v & 16383, c = r >> 7, k = r & 127;
      const float* src = (m==0) ? agg_W+20000 : (m==1) ? agg_W+10000 : (m==2) ? agg_W : last_W;
      Wb[v] = tobf((c < 100 && k < 100) ? src[c*100+k] : 0.f);
    } else if (v < 70536) {
      int j = v - 65536; int mtx = j / 2500; j %= 2500;
      int k4 = j / 100, c = j % 100;
      const float* src = mtx ? last_W : agg_W;
      float4 a = *(const float4*)&src[c*100 + k4*4];
      (mtx ? WLg : W0g)[j] = make_uint2(pk2(a.x,a.y), pk2(a.z,a.w));
    } else if (v < 117128) {
      int j = v - 70536;                     // linB [208][224]
      int c = j / 224, k = j % 224;
      linB[j] = tobf((c < 200 && k < 200) ? lin_W[c*200+k] : 0.f);
    } else if (v < 206728) {
      int j = v - 117128;                    // wihB [400][224]
      int c = j / 224, k = j % 224;
      wihB[j] = tobf((k < 200) ? Wih[c*200+k] : 0.f);
    } else if (v < 1456728) {                // gQ
      int j = v - 206728, q = j / 25, k4 = j % 25;
      float sx=0.f,sy=0.f,sz=0.f,sw=0.f;
#pragma unroll
      for (int i = 0; i < 4; i++) {
        float4 e = *(const float4*)&emb_s[q_nb[q*4+i]*100 + k4*4];
        sx+=e.x; sy+=e.y; sz+=e.z; sw+=e.w;
      }
      float4 a = *(const float4*)&emb_q[q*100 + k4*4];
      gQ[j] = make_uint2(pk2(0.25f*sx+a.x, 0.25f*sy+a.y), pk2(0.25f*sz+a.z, 0.25f*sw+a.w));
    } else if (v < 1956728) {                // gU
      int j = v - 1456728, u = j / 25, k4 = j % 25;
      float sx=0.f,sy=0.f,sz=0.f,sw=0.f;
      for (int k = 0; k < 10; k++) {
        float4 e = *(const float4*)&emb_q2[u_nb[u*10+k]*100 + k4*4];
        sx+=e.x; sy+=e.y; sz+=e.z; sw+=e.w;
      }
      float4 a = *(const float4*)&emb_u[u*100 + k4*4];
      gU[j] = make_uint2(pk2(0.1f*sx+a.x, 0.1f*sy+a.y), pk2(0.1f*sz+a.z, 0.1f*sw+a.w));
    } else if (v < 2006728) {                // gT1Q (skills)
      int j = v - 1956728, s = j / 25, k4 = j % 25;
      float sx=0.f,sy=0.f,sz=0.f,sw=0.f;
      for (int jj = 0; jj < 10; jj++) {
        float4 e = *(const float4*)&emb_q[s_nb[s*10+jj]*100 + k4*4];
        sx+=e.x; sy+=e.y; sz+=e.z; sw+=e.w;
      }
      float4 a = *(const float4*)&emb_s[s*100 + k4*4];
      gT1Q[j] = make_uint2(pk2(0.1f*sx+a.x, 0.1f*sy+a.y), pk2(0.1f*sz+a.z, 0.1f*sw+a.w));
    } else if (v < 3256728) {                // gT1U (questions)
      int j = v - 2006728, q = j / 25, k4 = j % 25;
      float sx=0.f,sy=0.f,sz=0.f,sw=0.f;
#pragma unroll
      for (int p = 0; p < 5; p++) {
        float4 e = *(const float4*)&emb_u[q_nb2[q*5+p]*100 + k4*4];
        sx+=e.x; sy+=e.y; sz+=e.z; sw+=e.w;
      }
      float4 a = *(const float4*)&emb_q2[q*100 + k4*4];
      gT1U[j] = make_uint2(pk2(0.2f*sx+a.x, 0.2f*sy+a.y), pk2(0.2f*sz+a.z, 0.2f*sw+a.w));
    } else if (v < 3261928) {                // WhP [400][13] uint4 (8 bf16)
      int j = v - 3256728; int row = j / 13, k8 = j % 13;
      float vv[8];
#pragma unroll
      for (int r = 0; r < 8; r++) { int k = k8*8 + r; vv[r] = (k < 100) ? Whh[row*100 + k] : 0.f; }
      WhP[j] = make_uint4(pk2(vv[0],vv[1]), pk2(vv[2],vv[3]), pk2(vv[4],vv[5]), pk2(vv[6],vv[7]));
    } else {                                 // kvqv: [0..99] kv, [100..199] qv, 200 ck, 201 cq, 202 wb0
      int idx = v - 3261928;
      float s = 0.f;
      if (idx < 100)      { for (int c = 0; c < 100; c++) s += kW[c*100+idx] * wW[100+c]; kvqv[idx] = s; }
      else if (idx < 200) { int t2 = idx-100; for (int c = 0; c < 100; c++) s += qW[c*100+t2] * wW[c]; kvqv[idx] = s; }
      else if (idx == 200){ for (int c = 0; c < 100; c++) s += kb[c] * wW[100+c]; kvqv[200] = s; }
      else if (idx == 201){ for (int c = 0; c < 100; c++) s += qb[c] * wW[c]; kvqv[201] = s; }
      else kvqv[202] = wb[0];
    }
  }
}

// ---------------------------------------------------------------------------
// P1: multi-hop aggregate, one item per block; table-based single-row gathers.
// ---------------------------------------------------------------------------
__global__ __launch_bounds__(512, 6) void k_embhat(
    const float* __restrict__ emb_q, const float* __restrict__ emb_q2,
    const float* __restrict__ w1_q, const float* __restrict__ w2_q,
    const float* __restrict__ agg_b, const float* __restrict__ last_b,
    const int* __restrict__ user, const int* __restrict__ question, const int* __restrict__ mask,
    const int* __restrict__ q_nb, const int* __restrict__ s_nb,
    const int* __restrict__ u_nb, const int* __restrict__ q_nb2,
    const __hip_bfloat16* __restrict__ Wb, const uint2* __restrict__ W0g,
    const uint2* __restrict__ WLg,
    const uint2* __restrict__ gQ, const uint2* __restrict__ gU,
    const uint2* __restrict__ gT1Q, const uint2* __restrict__ gT1U,
    __hip_bfloat16* __restrict__ embhat)
{
  __shared__ __align__(16) char Ab[114*256];        // [114 rows][128 k] bf16 swizzled
  __shared__ __hip_bfloat16 Cb[114*100];            // C rows bf16
  __shared__ int n2[40], m2[50], n1[4], m1[10];
  float* S = (float*)Ab;                            // overlays Ab after P3 (dead)
  const int tid = threadIdx.x, wid = tid >> 6, lane = tid & 63;
  const int l15 = lane & 15, lg = lane >> 4;
  const int item = blockIdx.x;
  const int t = item / BB, b = item % BB;
  const int qt = question[b*TT + t];
  const float w1 = w1_q[0], w2 = w2_q[0];

  if (mask[b*TT + t] != 1) {
    if (tid < 50) {
      const float2 q = *(const float2*)&emb_q[qt*100 + tid*2];
      const float2 p = *(const float2*)&emb_q2[qt*100 + tid*2];
      ((unsigned*)embhat)[item*50 + tid] = pk2(w1*q.x + w2*p.x, w1*q.y + w2*p.y);
    }
    return;
  }
  const int ut = user[b*TT + t];

  // ---- phase A: index staging + zero-pads ----
  for (int v = tid; v < 1102; v += 512) {
    if (v < 40) { int n1a = q_nb[qt*4 + v/10]; n2[v] = s_nb[n1a*10 + v%10]; }
    else if (v < 90) { int e = v-40; int m1a = u_nb[ut*10 + e/5]; m2[e] = q_nb2[m1a*5 + e%5]; }
    else if (v < 94) { n1[v-90] = q_nb[qt*4 + (v-90)]; }
    else if (v < 104) { m1[v-94] = u_nb[ut*10 + (v-94)]; }
    else {
      int z = v - 104, row, k4;
      if (z < 798) { row = z/7; k4 = 25 + z%7; }
      else if (z < 948) { int e = z-798; row = 90 + e/25; k4 = e%25; }
      else { int e = z-948; row = 110 + e/25; k4 = e%25; }
      int ofs = (row*256 + k4*8) ^ ((row&7)<<4);
      *(uint2*)(Ab + ofs) = make_uint2(0u, 0u);
    }
  }
  __syncthreads();
  // ---- phase B: single-row table gathers ----
  for (int v = tid; v < 2650; v += 512) {
    const uint2* src; int row, k4;
    if (v < 1000) { int r = v/25; k4 = v%25; src = &gQ[n2[r]*25]; row = r; }
    else if (v < 2250) { int e = v-1000; int r = e/25; k4 = e%25; src = &gU[m2[r]*25]; row = 40+r; }
    else if (v < 2350) { int e = v-2250; int a = e/25; k4 = e%25; src = &gT1Q[n1[a]*25]; row = 96+a; }
    else if (v < 2600) { int e = v-2350; int a = e/25; k4 = e%25; src = &gT1U[m1[a]*25]; row = 100+a; }
    else if (v < 2625) { k4 = v-2600; src = &gQ[qt*25]; row = 112; }
    else { k4 = v-2625; src = &gU[ut*25]; row = 113; }
    int ofs = (row*256 + k4*8) ^ ((row&7)<<4);
    *(uint2*)(Ab + ofs) = src[k4];
  }
  __syncthreads();
  // ---- P1: L1 MFMA — mt 0-5: W2, mt 6: W1, mt 7: W0 ----
  for (int tp = wid; tp < 56; tp += 8) {
    int mt = tp / 7, nt = tp % 7;
    const __hip_bfloat16* wm = Wb + ((mt < 6) ? 0 : (mt == 6) ? 16384 : 32768);
    int arow = mt*16 + l15; if (arow > 113) arow = 113;
    f32x4 acc = {0.f,0.f,0.f,0.f};
#pragma unroll
    for (int kc = 0; kc < 4; kc++) {
      bf16x8 av = *(const bf16x8*)(Ab + ((arow*256 + kc*64 + lg*16) ^ ((arow&7)<<4)));
      bf16x8 bv = *(const bf16x8*)(wm + (nt*16 + l15)*128 + kc*32 + lg*8);
      acc = __builtin_amdgcn_mfma_f32_16x16x32_bf16(av, bv, acc, 0, 0, 0);
    }
    int col = nt*16 + l15, r0 = mt*16 + lg*4;
    if (col < 100) {
#pragma unroll
      for (int r = 0; r < 4; r++)
        if (r0 + r < 114) Cb[(r0+r)*100 + col] = tobf(acc[r]);
    }
  }
  __syncthreads();
  // ---- P2: reduce + build L2 inputs ----
  for (int v = tid; v < 400; v += 512) {
    int k4 = (v < 350) ? v % 25 : (v - 350) % 25;
    float4 b2q = *(const float4*)&agg_b[200 + k4*4];
    float4 b1q = *(const float4*)&agg_b[100 + k4*4];
    float4 b0q = *(const float4*)&agg_b[k4*4];
    float x0, x1, x2, x3; int row;
#define RELU4(rr, bq, r0v,r1v,r2v,r3v) { \
    r0v = fmaxf(bf(Cb[(rr)*100 + k4*4+0]) + bq.x, 0.f); \
    r1v = fmaxf(bf(Cb[(rr)*100 + k4*4+1]) + bq.y, 0.f); \
    r2v = fmaxf(bf(Cb[(rr)*100 + k4*4+2]) + bq.z, 0.f); \
    r3v = fmaxf(bf(Cb[(rr)*100 + k4*4+3]) + bq.w, 0.f); }
    if (v < 350) {
      int a = v / 25;
      float s0=0.f,s1=0.f,s2=0.f,s3=0.f, r0,r1,r2,r3;
      float inv;
      if (a < 4) {
        for (int s = 0; s < 10; s++) { RELU4(a*10+s, b2q, r0,r1,r2,r3); s0+=r0;s1+=r1;s2+=r2;s3+=r3; }
        inv = 0.1f; RELU4(96+a, b1q, r0,r1,r2,r3);
      } else {
        int au = a - 4;
        for (int p = 0; p < 5; p++) { RELU4(40+au*5+p, b2q, r0,r1,r2,r3); s0+=r0;s1+=r1;s2+=r2;s3+=r3; }
        inv = 0.2f; RELU4(100+au, b1q, r0,r1,r2,r3);
      }
      x0 = inv*s0+r0; x1 = inv*s1+r1; x2 = inv*s2+r2; x3 = inv*s3+r3;
      row = a;
    } else {
      float s0=0.f,s1=0.f,s2=0.f,s3=0.f, r0,r1,r2,r3;
      if (v < 375) {
        for (int a = 0; a < 4; a++) { RELU4(96+a, b1q, r0,r1,r2,r3); s0+=r0;s1+=r1;s2+=r2;s3+=r3; }
        RELU4(112, b0q, r0,r1,r2,r3);
        x0 = 0.25f*s0+r0; x1 = 0.25f*s1+r1; x2 = 0.25f*s2+r2; x3 = 0.25f*s3+r3;
        row = 16;
      } else {
        for (int a = 0; a < 10; a++) { RELU4(100+a, b1q, r0,r1,r2,r3); s0+=r0;s1+=r1;s2+=r2;s3+=r3; }
        RELU4(113, b0q, r0,r1,r2,r3);
        x0 = 0.1f*s0+r0; x1 = 0.1f*s1+r1; x2 = 0.1f*s2+r2; x3 = 0.1f*s3+r3;
        row = 17;
      }
    }
    int ofs = (row*256 + k4*8) ^ ((row&7)<<4);
    *(uint2*)(Ab + ofs) = make_uint2(pk2(x0,x1), pk2(x2,x3));
  }
  __syncthreads();
  // ---- P3: L2 MFMA ----
  for (int tp = wid; tp < 14; tp += 8) {
    int mt = tp / 7, nt = tp % 7;
    const __hip_bfloat16* wm = Wb + (mt ? 32768 : 16384);
    int arow = mt*16 + l15;
    f32x4 acc = {0.f,0.f,0.f,0.f};
#pragma unroll
    for (int kc = 0; kc < 4; kc++) {
      bf16x8 av = *(const bf16x8*)(Ab + ((arow*256 + kc*64 + lg*16) ^ ((arow&7)<<4)));
      bf16x8 bv = *(const bf16x8*)(wm + (nt*16 + l15)*128 + kc*32 + lg*8);
      acc = __builtin_amdgcn_mfma_f32_16x16x32_bf16(av, bv, acc, 0, 0, 0);
    }
    int col = nt*16 + l15, r0 = mt*16 + lg*4;
    if (col < 100) {
#pragma unroll
      for (int r = 0; r < 4; r++)
        if (r0 + r < 114) Cb[(r0+r)*100 + col] = tobf(acc[r]);
    }
  }
  __syncthreads();
  // ---- P4: build t0c inputs into S[0..199] ----
  if (tid < 50) {
    int side = tid / 25, k4 = tid % 25;
    float4 b1q = *(const float4*)&agg_b[100 + k4*4];
    float4 b0q = *(const float4*)&agg_b[k4*4];
    float s0=0.f,s1=0.f,s2=0.f,s3=0.f, r0,r1,r2,r3;
    float inv;
    if (side == 0) {
      for (int a = 0; a < 4; a++) { RELU4(a, b1q, r0,r1,r2,r3); s0+=r0;s1+=r1;s2+=r2;s3+=r3; }
      inv = 0.25f; RELU4(16, b0q, r0,r1,r2,r3);
    } else {
      for (int a = 4; a < 14; a++) { RELU4(a, b1q, r0,r1,r2,r3); s0+=r0;s1+=r1;s2+=r2;s3+=r3; }
      inv = 0.1f; RELU4(17, b0q, r0,r1,r2,r3);
    }
    *(float4*)&S[side*100 + k4*4] = make_float4(inv*s0+r0, inv*s1+r1, inv*s2+r2, inv*s3+r3);
  }
  __syncthreads();
  // ---- P5: t0c ----
  if (tid < 50) {
    int side = tid / 25, q = tid % 25;
    float acc[4] = {0.f,0.f,0.f,0.f};
    dot4c(W0g, q, &S[side*100], acc);
#pragma unroll
    for (int j = 0; j < 4; j++) {
      int c = q + 25*j;
      S[200 + side*100 + c] = fmaxf(agg_b[c] + acc[j], 0.f);
    }
  }
  __syncthreads();
  // ---- P6: last linear + combine ----
  if (tid < 25) {
    int q = tid;
    float aq[4] = {0.f,0.f,0.f,0.f}, au[4] = {0.f,0.f,0.f,0.f};
    dot4c(WLg, q, &S[200], aq);
    dot4c(WLg, q, &S[300], au);
#pragma unroll
    for (int j = 0; j < 4; j++) {
      int c = q + 25*j;
      float dq = fmaxf(last_b[c] + aq[j], 0.f);
      float du = fmaxf(last_b[c] + au[j], 0.f);
      embhat[item*100 + c] = tobf(w1*dq + w2*du);
    }
  }
#undef RELU4
}

// ---------------------------------------------------------------------------
// P2: fused xin+xg GEMM chain via MFMA. block = timestep t, row = batch b.
// ---------------------------------------------------------------------------
__global__ __launch_bounds__(512, 1) void k_lin(
    const float* __restrict__ emb_r, const float* __restrict__ lin_b,
    const float* __restrict__ bih, const float* __restrict__ bhh,
    const int* __restrict__ response,
    const __hip_bfloat16* __restrict__ embhat,
    const __hip_bfloat16* __restrict__ linB, const __hip_bfloat16* __restrict__ wihB,
    __hip_bfloat16* __restrict__ xg)
{
  __shared__ __align__(16) char Xt[128*512];
  __shared__ __align__(16) char Yt[128*512];
  const int tid = threadIdx.x, wid = tid >> 6, lane = tid & 63;
  const int l15 = lane & 15, lg = lane >> 4;
  const int t = blockIdx.x;
  for (int v = tid; v < 15872; v += 512) {
    if (v < 14336) {
      int b = v / 112, c2 = v % 112; int col = c2*2;
      unsigned val;
      if (col < 100) val = ((const unsigned*)embhat)[(size_t)(t*128 + b)*50 + c2];
      else if (col < 200) {
        int rt = response[b*TT + t];
        val = pk2(emb_r[rt*100 + col - 100], emb_r[rt*100 + col - 99]);
      } else val = 0u;
      *(unsigned*)(Xt + ((b*512 + col*2) ^ ((b&7)<<4))) = val;
    } else {
      int e = v - 14336; int b = e / 12; int col = 200 + (e % 12)*2;
      *(unsigned*)(Yt + ((b*512 + col*2) ^ ((b&7)<<4))) = 0u;
    }
  }
  __syncthreads();
  for (int tp = wid; tp < 104; tp += 8) {
    int mt = tp / 13, nt = tp % 13;
    int arow = mt*16 + l15;
    f32x4 acc = {0.f,0.f,0.f,0.f};
#pragma unroll
    for (int kc = 0; kc < 7; kc++) {
      bf16x8 av = *(const bf16x8*)(Xt + ((arow*512 + kc*64 + lg*16) ^ ((arow&7)<<4)));
      bf16x8 bv = *(const bf16x8*)(linB + (nt*16 + l15)*224 + kc*32 + lg*8);
      acc = __builtin_amdgcn_mfma_f32_16x16x32_bf16(av, bv, acc, 0, 0, 0);
    }
    int col = nt*16 + l15, r0 = mt*16 + lg*4;
    if (col < 200) {
      float lbv = lin_b[col];
#pragma unroll
      for (int r = 0; r < 4; r++) {
        int row = r0 + r;
        *(__hip_bfloat16*)(Yt + ((row*512 + col*2) ^ ((row&7)<<4))) = tobf(fmaxf(acc[r] + lbv, 0.f));
      }
    }
  }
  __syncthreads();
  for (int tp = wid; tp < 200; tp += 8) {
    int mt = tp / 25, nt = tp % 25;
    int arow = mt*16 + l15;
    f32x4 acc = {0.f,0.f,0.f,0.f};
#pragma unroll
    for (int kc = 0; kc < 7; kc++) {
      bf16x8 av = *(const bf16x8*)(Yt + ((arow*512 + kc*64 + lg*16) ^ ((arow&7)<<4)));
      bf16x8 bv = *(const bf16x8*)(wihB + (nt*16 + l15)*224 + kc*32 + lg*8);
      acc = __builtin_amdgcn_mfma_f32_16x16x32_bf16(av, bv, acc, 0, 0, 0);
    }
    int col = nt*16 + l15, r0 = mt*16 + lg*4;
    float bs = bih[col] + bhh[col];
#pragma unroll
    for (int r = 0; r < 4; r++)
      xg[(size_t)(t*128 + r0 + r)*400 + col] = tobf(acc[r] + bs);
  }
}

// ---------------------------------------------------------------------------
// P3: per-(b,t) top-10, float4 inner dot
// ---------------------------------------------------------------------------
__global__ __launch_bounds__(256, 2) void k_topk(
    const float* __restrict__ emb_q, const int* __restrict__ question,
    int* __restrict__ topidx)
{
  __shared__ __align__(16) float Qb[150*104];
  __shared__ int qid[150];
  __shared__ float tval[1490];
  __shared__ int tidxs[1490];
  const int b = blockIdx.x, tid = threadIdx.x;
  if (tid < 150) qid[tid] = question[b*TT + tid];
  __syncthreads();
  for (int i = tid; i < 15000; i += 256) { int r = i/100, c = i%100; Qb[r*104+c] = emb_q[qid[r]*100+c]; }
  __syncthreads();
  if (tid < TS) {
    const int t = tid;
    float* v = &tval[t*10]; int* ix = &tidxs[t*10];
    for (int p = 0; p < 10; p++) { v[p] = -3.0e38f; ix[p] = 0; }
    const float4* qrow = (const float4*)&Qb[(t+1)*104];
    for (int j = 0; j < t; j++) {
      const float4* r = (const float4*)&Qb[j*104];
      float s = 0.f;
#pragma unroll
      for (int k4 = 0; k4 < 25; k4++) {
        float4 a = qrow[k4], c = r[k4];
        s += a.x*c.x + a.y*c.y + a.z*c.z + a.w*c.w;
      }
      if (s > v[9]) {
        int p = 9;
        while (p > 0 && s > v[p-1]) { v[p] = v[p-1]; ix[p] = ix[p-1]; p--; }
        v[p] = s; ix[p] = j;
      }
    }
    for (int p = 0; p < 10; p++) topidx[(t*BB + b)*10 + p] = ix[p];
  }
}

// ---------------------------------------------------------------------------
// P4a: LSTM-only sequential scan. Whh in REGISTERS (13 uint4/thread).
//   2 barriers/step; h crosses steps via hbfu; c in register; xg prefetched.
//   Writes h (bf16 pairs) per (b,t) to hstG.
// ---------------------------------------------------------------------------
__global__ __launch_bounds__(448, 1) void k_lstm(
    const uint4* __restrict__ WhP,
    const __hip_bfloat16* __restrict__ xg,
    const float* __restrict__ h0, const float* __restrict__ c0,
    unsigned* __restrict__ hstG, float* __restrict__ out)
{
  __shared__ unsigned hbfu[52];
  __shared__ float gates[400];
  const int b = blockIdx.x, tid = threadIdx.x;
  uint4 w[13];
  if (tid < 400) {
#pragma unroll
    for (int k8 = 0; k8 < 13; k8++) w[k8] = WhP[tid*13 + k8];
  }
  float c = 0.f;
  if (tid < 100) c = c0[b*100 + tid];
  if (tid < 50) hbfu[tid] = pk2(h0[b*100 + 2*tid], h0[b*100 + 2*tid + 1]);
  else if (tid < 52) hbfu[tid] = 0u;
  if (tid == 128) out[b*TT] = 0.5f;
  float xpre = 0.f;
  if (tid < 400) xpre = bf(xg[(size_t)b*400 + tid]);
  __syncthreads();
  for (int t = 0; t < TS; t++) {
    if (tid < 400) {
      float acc = xpre;
      if (t + 1 < TS) xpre = bf(xg[((size_t)(t+1)*BB + b)*400 + tid]);
#pragma unroll
      for (int k8 = 0; k8 < 13; k8++) {
        uint4 h = *(const uint4*)&hbfu[k8*4];
        acc += blo(w[k8].x)*blo(h.x) + bhi(w[k8].x)*bhi(h.x)
             + blo(w[k8].y)*blo(h.y) + bhi(w[k8].y)*bhi(h.y)
             + blo(w[k8].z)*blo(h.z) + bhi(w[k8].z)*bhi(h.z)
             + blo(w[k8].w)*blo(h.w) + bhi(w[k8].w)*bhi(h.w);
      }
      gates[tid] = acc;
    }
    __syncthreads();
    if (tid < 100) {
      float cc = sigm(gates[100+tid])*c + sigm(gates[tid])*tanhf(gates[200+tid]);
      c = cc;
      float hn = sigm(gates[300+tid])*tanhf(cc);
      float hp = __shfl_xor(hn, 1);
      if (!(tid & 1)) {
        unsigned pkv = pk2(hn, hp);
        hbfu[tid >> 1] = pkv;
        hstG[((size_t)b*TS + t)*50 + (tid >> 1)] = pkv;
      }
    }
    __syncthreads();
  }
}

// ---------------------------------------------------------------------------
// P4b: attention/prediction — fully parallel over (b,t). One wave per t,
//   barrier-free main loop. Rows/skv from hstG; j==0 keeps zero-row semantics.
// ---------------------------------------------------------------------------
__global__ __launch_bounds__(512, 1) void k_attn(
    const float* __restrict__ emb_q, const float* __restrict__ emb_s,
    const int* __restrict__ question, const int* __restrict__ qs_skill,
    const int* __restrict__ topidx, const unsigned* __restrict__ hstG,
    const float* __restrict__ kvqv, float* __restrict__ out)
{
  __shared__ __align__(16) uint2 Hl[149*26];    // row stride 26 uint2 (208B)
  __shared__ __align__(16) float qsb[8][500];
  __shared__ float sqb[8][5];
  __shared__ float skt[152];
  __shared__ float qvl[100];
  const int b = blockIdx.x, tid = threadIdx.x;
  const int wv = tid >> 6, lane = tid & 63;
  for (int i = tid; i < 149*25; i += 512) {
    int r = i / 25, cc = i % 25;
    Hl[r*26 + cc] = *(const uint2*)&hstG[((size_t)b*TS + r)*50 + cc*2];
  }
  if (tid < 100) qvl[tid] = kvqv[100 + tid];
  __syncthreads();
  const float ck = kvqv[200], cq = kvqv[201], wb0 = kvqv[202];
  // skt[r] = Hl[r]·kv + ck  (2 lanes per row)
  if (tid < 298) {
    int r = tid >> 1, half = tid & 1;
    float s = 0.f;
    for (int cc = half*13; cc < (half ? 25 : 13); cc++) {
      uint2 u = Hl[r*26 + cc];
      float4 kvv = *(const float4*)&kvqv[cc*4];
      s += blo(u.x)*kvv.x + bhi(u.x)*kvv.y + blo(u.y)*kvv.z + bhi(u.y)*kvv.w;
    }
    s += __shfl_xor(s, 1);
    if (!half) skt[r] = s + ck;
  }
  __syncthreads();
  for (int t0 = 0; t0 < TS; t0 += 8) {
    int t = t0 + wv;
    if (t >= TS) continue;
    const int qn = question[b*TT + t + 1];
    for (int e = lane; e < 500; e += 64) {
      int q = e / 100;
      qsb[wv][e] = (q == 0) ? emb_q[qn*100 + e]
                            : emb_s[qs_skill[qn*4 + q - 1]*100 + e%100];
    }
    // lanes 55-59: sq[q] = qs[q]·qv + cq
    if (lane >= 55 && lane < 60) {
      int q = lane - 55;
      float s2 = 0.f;
      for (int cc = 0; cc < 100; cc++) s2 += qsb[wv][q*100 + cc] * qvl[cc];
      sqb[wv][q] = s2 + cq;
    }
    // lanes 0-54: g dot + score
    float scv = -3.0e38f, gval = 0.f;
    if (lane < 55) {
      int q = lane / 11, s = lane % 11;
      int j; bool valid = true;
      float sk = 0.f;
      if (s == 0) { j = t; sk = skt[t]; }
      else {
        int cnt = t < 10 ? t : 10;
        if (s - 1 < cnt) {
          j = topidx[((size_t)t*BB + b)*10 + s - 1];
          sk = (j == 0) ? ck : skt[j];
        } else { j = -1; valid = false; }
      }
      if (valid && j > 0) {
        const uint2* hr = &Hl[j*26];
        const float4* qq = (const float4*)&qsb[wv][q*100];
        for (int cc = 0; cc < 25; cc++) {
          uint2 u = hr[cc]; float4 a = qq[cc];
          gval += blo(u.x)*a.x + bhi(u.x)*a.y + blo(u.y)*a.z + bhi(u.y)*a.w;
        }
      } else if (s == 0 && j == 0) {
        // t==0, s==0: row = Hl[0]
        const uint2* hr = &Hl[0];
        const float4* qq = (const float4*)&qsb[wv][q*100];
        for (int cc = 0; cc < 25; cc++) {
          uint2 u = hr[cc]; float4 a = qq[cc];
          gval += blo(u.x)*a.x + bhi(u.x)*a.y + blo(u.y)*a.z + bhi(u.y)*a.w;
        }
      }
      scv = valid ? (sqb[wv][q] + sk + wb0) : -1e9f;
    }
    float m = scv;
#pragma unroll
    for (int o = 32; o; o >>= 1) m = fmaxf(m, __shfl_xor(m, o));
    float ex = (lane < 55) ? expf(scv - m) : 0.f;
    float num = ex * gval, den = ex;
#pragma unroll
    for (int o = 32; o; o >>= 1) { num += __shfl_xor(num, o); den += __shfl_xor(den, o); }
    if (lane == 0) out[b*TT + t + 1] = sigm(num/den);
  }
}

extern "C" void kernel_launch(void* const* d_in, const int* in_sizes, int n_in,
                              void* d_out, int out_size, void* d_ws, size_t ws_size,
                              hipStream_t stream) {
  const float* emb_q  = (const float*)d_in[0];
  const float* emb_q2 = (const float*)d_in[1];
  const float* emb_s  = (const float*)d_in[2];
  const float* emb_u  = (const float*)d_in[3];
  const float* emb_r  = (const float*)d_in[4];
  const float* w1_q   = (const float*)d_in[5];
  const float* w2_q   = (const float*)d_in[6];
  const float* lin_W  = (const float*)d_in[7];
  const float* lin_b  = (const float*)d_in[8];
  const float* Wih    = (const float*)d_in[9];
  const float* Whh    = (const float*)d_in[10];
  const float* bih    = (const float*)d_in[11];
  const float* bhh    = (const float*)d_in[12];
  const float* agg_W  = (const float*)d_in[13];
  const float* agg_b  = (const float*)d_in[14];
  const float* last_W = (const float*)d_in[15];
  const float* last_b = (const float*)d_in[16];
  const float* qW     = (const float*)d_in[17];
  const float* qb     = (const float*)d_in[18];
  const float* kW     = (const float*)d_in[19];
  const float* kb     = (const float*)d_in[20];
  const float* wW     = (const float*)d_in[21];
  const float* wb     = (const float*)d_in[22];
  const float* h0     = (const float*)d_in[23];
  const float* c0     = (const float*)d_in[24];
  const int* user      = (const int*)d_in[25];
  const int* question  = (const int*)d_in[26];
  const int* response  = (const int*)d_in[27];
  const int* mask      = (const int*)d_in[28];
  const int* q_nb      = (const int*)d_in[29];
  const int* s_nb      = (const int*)d_in[30];
  const int* u_nb      = (const int*)d_in[31];
  const int* q_nb2     = (const int*)d_in[32];
  const int* qs_skill  = (const int*)d_in[33];

  char* ws = (char*)d_ws;
  __hip_bfloat16* embhat = (__hip_bfloat16*)(ws + 0);          //  3,814,400
  __hip_bfloat16* xg     = (__hip_bfloat16*)(ws + 3814400);    // 15,257,600
  int*            topidx = (int*)(ws + 19072000);              //    762,880
  __hip_bfloat16* Wb     = (__hip_bfloat16*)(ws + 19834880);   //    131,072
  uint2*          W0g    = (uint2*)(ws + 19965952);            //     20,000
  uint2*          WLg    = (uint2*)(ws + 19985952);            //     20,000
  __hip_bfloat16* linB   = (__hip_bfloat16*)(ws + 20005952);   //     93,184
  __hip_bfloat16* wihB   = (__hip_bfloat16*)(ws + 20099136);   //    179,200
  uint2*          gQ     = (uint2*)(ws + 20278336);            // 10,000,000
  uint2*          gU     = (uint2*)(ws + 30278336);            //  4,000,000
  uint2*          gT1Q   = (uint2*)(ws + 34278336);            //    400,000
  uint2*          gT1U   = (uint2*)(ws + 34678336);            // 10,000,000
  uint4*          WhP    = (uint4*)(ws + 44678336);            //     83,200
  float*          kvqv   = (float*)(ws + 44761536);            //      1,024
  unsigned*       hstG   = (unsigned*)(ws + 44762560);         //  3,814,400 -> 48,576,960

  k_prep<<<2048, 256, 0, stream>>>(agg_W, last_W, lin_W, Wih,
                                   emb_q, emb_q2, emb_s, emb_u,
                                   q_nb, s_nb, u_nb, q_nb2,
                                   Whh, qW, qb, kW, kb, wW, wb,
                                   Wb, W0g, WLg, linB, wihB, gQ, gU, gT1Q, gT1U,
                                   WhP, kvqv);
  k_embhat<<<NITEM, 512, 0, stream>>>(emb_q, emb_q2, w1_q, w2_q,
                                      agg_b, last_b,
                                      user, question, mask, q_nb, s_nb, u_nb, q_nb2,
                                      Wb, W0g, WLg, gQ, gU, gT1Q, gT1U, embhat);
  k_lin<<<TS, 512, 0, stream>>>(emb_r, lin_b, bih, bhh, response, embhat,
                                linB, wihB, xg);
  k_topk<<<128, 256, 0, stream>>>(emb_q, question, topidx);
  k_lstm<<<128, 448, 0, stream>>>(WhP, xg, h0, c0, hstG, (float*)d_out);
  k_attn<<<128, 512, 0, stream>>>(emb_q, emb_s, question, qs_skill,
                                  topidx, hstG, kvqv, (float*)d_out);
}

// Round 10
// 902.874 us; speedup vs baseline: 4.2267x; 1.2041x over previous
//
#include <hip/hip_runtime.h>
#include <hip/hip_bf16.h>

#define BB 128
#define TT 150
#define TS 149
#define NITEM (TS*BB)

typedef __attribute__((ext_vector_type(8))) short bf16x8;
typedef __attribute__((ext_vector_type(4))) float f32x4;

__device__ __forceinline__ float bf(__hip_bfloat16 x) { return __bfloat162float(x); }
__device__ __forceinline__ __hip_bfloat16 tobf(float x) { return __float2bfloat16(x); }
__device__ __forceinline__ float sigm(float x) { return 1.f / (1.f + expf(-x)); }

__device__ __forceinline__ unsigned pk2(float a, float b) {
  unsigned ua = __float_as_uint(a), ub = __float_as_uint(b);
  ua += 0x7fffu + ((ua >> 16) & 1u);
  ub += 0x7fffu + ((ub >> 16) & 1u);
  return (ua >> 16) | (ub & 0xffff0000u);
}
__device__ __forceinline__ float blo(unsigned u) { return __uint_as_float(u << 16); }
__device__ __forceinline__ float bhi(unsigned u) { return __uint_as_float(u & 0xffff0000u); }

// ---------------------------------------------------------------------------
// P0: one-time weight conversion + fused gather tables + WhP/kvqv + col-major
// ---------------------------------------------------------------------------
#define PREP_N 3267131
__global__ __launch_bounds__(256, 4) void k_prep(
    const float* __restrict__ agg_W, const float* __restrict__ last_W,
    const float* __restrict__ lin_W, const float* __restrict__ Wih,
    const float* __restrict__ emb_q, const float* __restrict__ emb_q2,
    const float* __restrict__ emb_s, const float* __restrict__ emb_u,
    const int* __restrict__ q_nb, const int* __restrict__ s_nb,
    const int* __restrict__ u_nb, const int* __restrict__ q_nb2,
    const float* __restrict__ Whh,
    const float* __restrict__ qW, const float* __restrict__ qb,
    const float* __restrict__ kW, const float* __restrict__ kb,
    const float* __restrict__ wW, const float* __restrict__ wb,
    __hip_bfloat16* __restrict__ Wb, uint2* __restrict__ W0g, uint2* __restrict__ WLg,
    __hip_bfloat16* __restrict__ linB, __hip_bfloat16* __restrict__ wihB,
    uint2* __restrict__ gQ, uint2* __restrict__ gU,
    uint2* __restrict__ gT1Q, uint2* __restrict__ gT1U,
    uint4* __restrict__ WhP, float* __restrict__ kvqv,
    uint2* __restrict__ W0c, uint2* __restrict__ WLc)
{
  for (int v = blockIdx.x*256 + threadIdx.x; v < PREP_N; v += gridDim.x*256) {
    if (v < 65536) {
      int m = v >> 14, r = v & 16383, c = r >> 7, k = r & 127;
      const float* src = (m==0) ? agg_W+20000 : (m==1) ? agg_W+10000 : (m==2) ? agg_W : last_W;
      Wb[v] = tobf((c < 100 && k < 100) ? src[c*100+k] : 0.f);
    } else if (v < 70536) {
      int j = v - 65536; int mtx = j / 2500; j %= 2500;
      int k4 = j / 100, c = j % 100;
      const float* src = mtx ? last_W : agg_W;
      float4 a = *(const float4*)&src[c*100 + k4*4];
      (mtx ? WLg : W0g)[j] = make_uint2(pk2(a.x,a.y), pk2(a.z,a.w));
    } else if (v < 117128) {
      int j = v - 70536;                     // linB [208][224]
      int c = j / 224, k = j % 224;
      linB[j] = tobf((c < 200 && k < 200) ? lin_W[c*200+k] : 0.f);
    } else if (v < 206728) {
      int j = v - 117128;                    // wihB [400][224]
      int c = j / 224, k = j % 224;
      wihB[j] = tobf((k < 200) ? Wih[c*200+k] : 0.f);
    } else if (v < 1456728) {                // gQ
      int j = v - 206728, q = j / 25, k4 = j % 25;
      float sx=0.f,sy=0.f,sz=0.f,sw=0.f;
#pragma unroll
      for (int i = 0; i < 4; i++) {
        float4 e = *(const float4*)&emb_s[q_nb[q*4+i]*100 + k4*4];
        sx+=e.x; sy+=e.y; sz+=e.z; sw+=e.w;
      }
      float4 a = *(const float4*)&emb_q[q*100 + k4*4];
      gQ[j] = make_uint2(pk2(0.25f*sx+a.x, 0.25f*sy+a.y), pk2(0.25f*sz+a.z, 0.25f*sw+a.w));
    } else if (v < 1956728) {                // gU
      int j = v - 1456728, u = j / 25, k4 = j % 25;
      float sx=0.f,sy=0.f,sz=0.f,sw=0.f;
      for (int k = 0; k < 10; k++) {
        float4 e = *(const float4*)&emb_q2[u_nb[u*10+k]*100 + k4*4];
        sx+=e.x; sy+=e.y; sz+=e.z; sw+=e.w;
      }
      float4 a = *(const float4*)&emb_u[u*100 + k4*4];
      gU[j] = make_uint2(pk2(0.1f*sx+a.x, 0.1f*sy+a.y), pk2(0.1f*sz+a.z, 0.1f*sw+a.w));
    } else if (v < 2006728) {                // gT1Q (skills)
      int j = v - 1956728, s = j / 25, k4 = j % 25;
      float sx=0.f,sy=0.f,sz=0.f,sw=0.f;
      for (int jj = 0; jj < 10; jj++) {
        float4 e = *(const float4*)&emb_q[s_nb[s*10+jj]*100 + k4*4];
        sx+=e.x; sy+=e.y; sz+=e.z; sw+=e.w;
      }
      float4 a = *(const float4*)&emb_s[s*100 + k4*4];
      gT1Q[j] = make_uint2(pk2(0.1f*sx+a.x, 0.1f*sy+a.y), pk2(0.1f*sz+a.z, 0.1f*sw+a.w));
    } else if (v < 3256728) {                // gT1U (questions)
      int j = v - 2006728, q = j / 25, k4 = j % 25;
      float sx=0.f,sy=0.f,sz=0.f,sw=0.f;
#pragma unroll
      for (int p = 0; p < 5; p++) {
        float4 e = *(const float4*)&emb_u[q_nb2[q*5+p]*100 + k4*4];
        sx+=e.x; sy+=e.y; sz+=e.z; sw+=e.w;
      }
      float4 a = *(const float4*)&emb_q2[q*100 + k4*4];
      gT1U[j] = make_uint2(pk2(0.2f*sx+a.x, 0.2f*sy+a.y), pk2(0.2f*sz+a.z, 0.2f*sw+a.w));
    } else if (v < 3261928) {                // WhP [400][13] uint4 (8 bf16)
      int j = v - 3256728; int row = j / 13, k8 = j % 13;
      float vv[8];
#pragma unroll
      for (int r = 0; r < 8; r++) { int k = k8*8 + r; vv[r] = (k < 100) ? Whh[row*100 + k] : 0.f; }
      WhP[j] = make_uint4(pk2(vv[0],vv[1]), pk2(vv[2],vv[3]), pk2(vv[4],vv[5]), pk2(vv[6],vv[7]));
    } else if (v < 3262131) {                // kvqv
      int idx = v - 3261928;
      float s = 0.f;
      if (idx < 100)      { for (int c = 0; c < 100; c++) s += kW[c*100+idx] * wW[100+c]; kvqv[idx] = s; }
      else if (idx < 200) { int t2 = idx-100; for (int c = 0; c < 100; c++) s += qW[c*100+t2] * wW[c]; kvqv[idx] = s; }
      else if (idx == 200){ for (int c = 0; c < 100; c++) s += kb[c] * wW[100+c]; kvqv[200] = s; }
      else if (idx == 201){ for (int c = 0; c < 100; c++) s += qb[c] * wW[c]; kvqv[201] = s; }
      else kvqv[202] = wb[0];
    } else {                                 // col-major W0c/WLc [c*25+k4]
      int j = v - 3262131; int mtx = j / 2500; j %= 2500;
      int c = j / 25, k4 = j % 25;
      const float* src = mtx ? last_W : agg_W;
      float4 a = *(const float4*)&src[c*100 + k4*4];
      (mtx ? WLc : W0c)[j] = make_uint2(pk2(a.x,a.y), pk2(a.z,a.w));
    }
  }
}

// ---------------------------------------------------------------------------
// P1: multi-hop aggregate, one item per block; W2 B-frags in registers;
//     nt-major wave mapping; col-major parallel tail.
// ---------------------------------------------------------------------------
__global__ __launch_bounds__(512, 6) void k_embhat(
    const float* __restrict__ emb_q, const float* __restrict__ emb_q2,
    const float* __restrict__ w1_q, const float* __restrict__ w2_q,
    const float* __restrict__ agg_b, const float* __restrict__ last_b,
    const int* __restrict__ user, const int* __restrict__ question, const int* __restrict__ mask,
    const int* __restrict__ q_nb, const int* __restrict__ s_nb,
    const int* __restrict__ u_nb, const int* __restrict__ q_nb2,
    const __hip_bfloat16* __restrict__ Wb,
    const uint2* __restrict__ W0c, const uint2* __restrict__ WLc,
    const uint2* __restrict__ gQ, const uint2* __restrict__ gU,
    const uint2* __restrict__ gT1Q, const uint2* __restrict__ gT1U,
    __hip_bfloat16* __restrict__ embhat)
{
  __shared__ __align__(16) char Ab[114*256];        // [114 rows][128 k] bf16 swizzled
  __shared__ __hip_bfloat16 Cb[114*100];            // C rows bf16
  __shared__ int n2[40], m2[50], n1[4], m1[10];
  float* S = (float*)Ab;                            // overlays Ab after P3 (dead)
  const int tid = threadIdx.x, wid = tid >> 6, lane = tid & 63;
  const int l15 = lane & 15, lg = lane >> 4;
  const int item = blockIdx.x;
  const int t = item / BB, b = item % BB;
  const int qt = question[b*TT + t];
  const float w1 = w1_q[0], w2 = w2_q[0];

  if (mask[b*TT + t] != 1) {
    if (tid < 50) {
      const float2 q = *(const float2*)&emb_q[qt*100 + tid*2];
      const float2 p = *(const float2*)&emb_q2[qt*100 + tid*2];
      ((unsigned*)embhat)[item*50 + tid] = pk2(w1*q.x + w2*p.x, w1*q.y + w2*p.y);
    }
    return;
  }
  const int ut = user[b*TT + t];

  // preload W2 B-fragments (wave = nt) — overlaps with gather phases
  bf16x8 w2f[4];
  if (wid < 7) {
#pragma unroll
    for (int kc = 0; kc < 4; kc++)
      w2f[kc] = *(const bf16x8*)(Wb + (wid*16 + l15)*128 + kc*32 + lg*8);
  }

  // ---- phase A: index staging + zero-pads ----
  for (int v = tid; v < 1102; v += 512) {
    if (v < 40) { int n1a = q_nb[qt*4 + v/10]; n2[v] = s_nb[n1a*10 + v%10]; }
    else if (v < 90) { int e = v-40; int m1a = u_nb[ut*10 + e/5]; m2[e] = q_nb2[m1a*5 + e%5]; }
    else if (v < 94) { n1[v-90] = q_nb[qt*4 + (v-90)]; }
    else if (v < 104) { m1[v-94] = u_nb[ut*10 + (v-94)]; }
    else {
      int z = v - 104, row, k4;
      if (z < 798) { row = z/7; k4 = 25 + z%7; }
      else if (z < 948) { int e = z-798; row = 90 + e/25; k4 = e%25; }
      else { int e = z-948; row = 110 + e/25; k4 = e%25; }
      int ofs = (row*256 + k4*8) ^ ((row&7)<<4);
      *(uint2*)(Ab + ofs) = make_uint2(0u, 0u);
    }
  }
  __syncthreads();
  // ---- phase B: single-row table gathers ----
  for (int v = tid; v < 2650; v += 512) {
    const uint2* src; int row, k4;
    if (v < 1000) { int r = v/25; k4 = v%25; src = &gQ[n2[r]*25]; row = r; }
    else if (v < 2250) { int e = v-1000; int r = e/25; k4 = e%25; src = &gU[m2[r]*25]; row = 40+r; }
    else if (v < 2350) { int e = v-2250; int a = e/25; k4 = e%25; src = &gT1Q[n1[a]*25]; row = 96+a; }
    else if (v < 2600) { int e = v-2350; int a = e/25; k4 = e%25; src = &gT1U[m1[a]*25]; row = 100+a; }
    else if (v < 2625) { k4 = v-2600; src = &gQ[qt*25]; row = 112; }
    else { k4 = v-2625; src = &gU[ut*25]; row = 113; }
    int ofs = (row*256 + k4*8) ^ ((row&7)<<4);
    *(uint2*)(Ab + ofs) = src[k4];
  }
  __syncthreads();
  // ---- P1: L1 MFMA — wave nt=wid handles mt 0..7. mt0-5: W2 (registers) ----
  if (wid < 7) {
    const int nt = wid, brow = nt*16 + l15;
#pragma unroll
    for (int mt = 0; mt < 6; mt++) {
      int arow = mt*16 + l15;
      f32x4 acc = {0.f,0.f,0.f,0.f};
#pragma unroll
      for (int kc = 0; kc < 4; kc++) {
        bf16x8 av = *(const bf16x8*)(Ab + ((arow*256 + kc*64 + lg*16) ^ ((arow&7)<<4)));
        acc = __builtin_amdgcn_mfma_f32_16x16x32_bf16(av, w2f[kc], acc, 0, 0, 0);
      }
      int col = nt*16 + l15, r0 = mt*16 + lg*4;
      if (col < 100) {
#pragma unroll
        for (int r = 0; r < 4; r++)
          if (r0 + r < 114) Cb[(r0+r)*100 + col] = tobf(acc[r]);
      }
    }
#pragma unroll
    for (int mt = 6; mt < 8; mt++) {
      const __hip_bfloat16* wm = Wb + ((mt == 6) ? 16384 : 32768);
      int arow = mt*16 + l15; if (arow > 113) arow = 113;
      f32x4 acc = {0.f,0.f,0.f,0.f};
#pragma unroll
      for (int kc = 0; kc < 4; kc++) {
        bf16x8 av = *(const bf16x8*)(Ab + ((arow*256 + kc*64 + lg*16) ^ ((arow&7)<<4)));
        bf16x8 bv = *(const bf16x8*)(wm + brow*128 + kc*32 + lg*8);
        acc = __builtin_amdgcn_mfma_f32_16x16x32_bf16(av, bv, acc, 0, 0, 0);
      }
      int col = nt*16 + l15, r0 = mt*16 + lg*4;
      if (col < 100) {
#pragma unroll
        for (int r = 0; r < 4; r++)
          if (r0 + r < 114) Cb[(r0+r)*100 + col] = tobf(acc[r]);
      }
    }
  }
  __syncthreads();
  // ---- P2: reduce + build L2 inputs ----
  for (int v = tid; v < 400; v += 512) {
    int k4 = (v < 350) ? v % 25 : (v - 350) % 25;
    float4 b2q = *(const float4*)&agg_b[200 + k4*4];
    float4 b1q = *(const float4*)&agg_b[100 + k4*4];
    float4 b0q = *(const float4*)&agg_b[k4*4];
    float x0, x1, x2, x3; int row;
#define RELU4(rr, bq, r0v,r1v,r2v,r3v) { \
    r0v = fmaxf(bf(Cb[(rr)*100 + k4*4+0]) + bq.x, 0.f); \
    r1v = fmaxf(bf(Cb[(rr)*100 + k4*4+1]) + bq.y, 0.f); \
    r2v = fmaxf(bf(Cb[(rr)*100 + k4*4+2]) + bq.z, 0.f); \
    r3v = fmaxf(bf(Cb[(rr)*100 + k4*4+3]) + bq.w, 0.f); }
    if (v < 350) {
      int a = v / 25;
      float s0=0.f,s1=0.f,s2=0.f,s3=0.f, r0,r1,r2,r3;
      float inv;
      if (a < 4) {
        for (int s = 0; s < 10; s++) { RELU4(a*10+s, b2q, r0,r1,r2,r3); s0+=r0;s1+=r1;s2+=r2;s3+=r3; }
        inv = 0.1f; RELU4(96+a, b1q, r0,r1,r2,r3);
      } else {
        int au = a - 4;
        for (int p = 0; p < 5; p++) { RELU4(40+au*5+p, b2q, r0,r1,r2,r3); s0+=r0;s1+=r1;s2+=r2;s3+=r3; }
        inv = 0.2f; RELU4(100+au, b1q, r0,r1,r2,r3);
      }
      x0 = inv*s0+r0; x1 = inv*s1+r1; x2 = inv*s2+r2; x3 = inv*s3+r3;
      row = a;
    } else {
      float s0=0.f,s1=0.f,s2=0.f,s3=0.f, r0,r1,r2,r3;
      if (v < 375) {
        for (int a = 0; a < 4; a++) { RELU4(96+a, b1q, r0,r1,r2,r3); s0+=r0;s1+=r1;s2+=r2;s3+=r3; }
        RELU4(112, b0q, r0,r1,r2,r3);
        x0 = 0.25f*s0+r0; x1 = 0.25f*s1+r1; x2 = 0.25f*s2+r2; x3 = 0.25f*s3+r3;
        row = 16;
      } else {
        for (int a = 0; a < 10; a++) { RELU4(100+a, b1q, r0,r1,r2,r3); s0+=r0;s1+=r1;s2+=r2;s3+=r3; }
        RELU4(113, b0q, r0,r1,r2,r3);
        x0 = 0.1f*s0+r0; x1 = 0.1f*s1+r1; x2 = 0.1f*s2+r2; x3 = 0.1f*s3+r3;
        row = 17;
      }
    }
    int ofs = (row*256 + k4*8) ^ ((row&7)<<4);
    *(uint2*)(Ab + ofs) = make_uint2(pk2(x0,x1), pk2(x2,x3));
  }
  __syncthreads();
  // ---- P3: L2 MFMA — wave nt=wid, mt0 (W1, in-line), mt1 (W0) ----
  if (wid < 7) {
    const int nt = wid, brow = nt*16 + l15;
#pragma unroll
    for (int mt = 0; mt < 2; mt++) {
      const __hip_bfloat16* wm = Wb + (mt ? 32768 : 16384);
      int arow = mt*16 + l15;
      f32x4 acc = {0.f,0.f,0.f,0.f};
#pragma unroll
      for (int kc = 0; kc < 4; kc++) {
        bf16x8 av = *(const bf16x8*)(Ab + ((arow*256 + kc*64 + lg*16) ^ ((arow&7)<<4)));
        bf16x8 bv = *(const bf16x8*)(wm + brow*128 + kc*32 + lg*8);
        acc = __builtin_amdgcn_mfma_f32_16x16x32_bf16(av, bv, acc, 0, 0, 0);
      }
      int col = nt*16 + l15, r0 = mt*16 + lg*4;
      if (col < 100) {
#pragma unroll
        for (int r = 0; r < 4; r++)
          if (r0 + r < 114) Cb[(r0+r)*100 + col] = tobf(acc[r]);
      }
    }
  }
  __syncthreads();
  // ---- P4: build t0c inputs into S[0..199] ----
  if (tid < 50) {
    int side = tid / 25, k4 = tid % 25;
    float4 b1q = *(const float4*)&agg_b[100 + k4*4];
    float4 b0q = *(const float4*)&agg_b[k4*4];
    float s0=0.f,s1=0.f,s2=0.f,s3=0.f, r0,r1,r2,r3;
    float inv;
    if (side == 0) {
      for (int a = 0; a < 4; a++) { RELU4(a, b1q, r0,r1,r2,r3); s0+=r0;s1+=r1;s2+=r2;s3+=r3; }
      inv = 0.25f; RELU4(16, b0q, r0,r1,r2,r3);
    } else {
      for (int a = 4; a < 14; a++) { RELU4(a, b1q, r0,r1,r2,r3); s0+=r0;s1+=r1;s2+=r2;s3+=r3; }
      inv = 0.1f; RELU4(17, b0q, r0,r1,r2,r3);
    }
    *(float4*)&S[side*100 + k4*4] = make_float4(inv*s0+r0, inv*s1+r1, inv*s2+r2, inv*s3+r3);
  }
  __syncthreads();
  // ---- P5: t0c = relu(W0 · in + b0), 200 threads col-major ----
  if (tid < 200) {
    int side = tid / 100, c = tid % 100;
    const float4* xq = (const float4*)&S[side*100];
    float a0=0.f, a1=0.f, a2=0.f, a3=0.f;
    for (int k4 = 0; k4 < 25; k4++) {
      uint2 w = W0c[c*25 + k4];
      float4 xv = xq[k4];
      a0 = fmaf(blo(w.x), xv.x, a0);
      a1 = fmaf(bhi(w.x), xv.y, a1);
      a2 = fmaf(blo(w.y), xv.z, a2);
      a3 = fmaf(bhi(w.y), xv.w, a3);
    }
    S[200 + side*100 + c] = fmaxf(agg_b[c] + (a0+a1)+(a2+a3), 0.f);
  }
  __syncthreads();
  // ---- P6: last linear + combine, 100 threads col-major ----
  if (tid < 100) {
    int c = tid;
    const float4* xq0 = (const float4*)&S[200];
    const float4* xq1 = (const float4*)&S[300];
    float a0=0.f,a1=0.f,a2=0.f,a3=0.f, b0v=0.f,b1v=0.f,b2v=0.f,b3v=0.f;
    for (int k4 = 0; k4 < 25; k4++) {
      uint2 w = WLc[c*25 + k4];
      float4 x0v = xq0[k4], x1v = xq1[k4];
      a0 = fmaf(blo(w.x), x0v.x, a0); a1 = fmaf(bhi(w.x), x0v.y, a1);
      a2 = fmaf(blo(w.y), x0v.z, a2); a3 = fmaf(bhi(w.y), x0v.w, a3);
      b0v = fmaf(blo(w.x), x1v.x, b0v); b1v = fmaf(bhi(w.x), x1v.y, b1v);
      b2v = fmaf(blo(w.y), x1v.z, b2v); b3v = fmaf(bhi(w.y), x1v.w, b3v);
    }
    float dq = fmaxf(last_b[c] + (a0+a1)+(a2+a3), 0.f);
    float du = fmaxf(last_b[c] + (b0v+b1v)+(b2v+b3v), 0.f);
    embhat[item*100 + c] = tobf(w1*dq + w2*du);
  }
#undef RELU4
}

// ---------------------------------------------------------------------------
// P2: fused xin+xg GEMM chain. 64 batch rows/block -> 2 blocks/CU, 298 blocks.
// ---------------------------------------------------------------------------
__global__ __launch_bounds__(512, 2) void k_lin(
    const float* __restrict__ emb_r, const float* __restrict__ lin_b,
    const float* __restrict__ bih, const float* __restrict__ bhh,
    const int* __restrict__ response,
    const __hip_bfloat16* __restrict__ embhat,
    const __hip_bfloat16* __restrict__ linB, const __hip_bfloat16* __restrict__ wihB,
    __hip_bfloat16* __restrict__ xg)
{
  __shared__ __align__(16) char Xt[64*512];
  __shared__ __align__(16) char Yt[64*512];
  const int tid = threadIdx.x, wid = tid >> 6, lane = tid & 63;
  const int l15 = lane & 15, lg = lane >> 4;
  const int t = blockIdx.x >> 1, rb = (blockIdx.x & 1) << 6;
  for (int v = tid; v < 7936; v += 512) {
    if (v < 7168) {
      int b = v / 112, c2 = v % 112; int col = c2*2;
      unsigned val;
      if (col < 100) val = ((const unsigned*)embhat)[(size_t)(t*128 + rb + b)*50 + c2];
      else if (col < 200) {
        int rt = response[(rb + b)*TT + t];
        val = pk2(emb_r[rt*100 + col - 100], emb_r[rt*100 + col - 99]);
      } else val = 0u;
      *(unsigned*)(Xt + ((b*512 + col*2) ^ ((b&7)<<4))) = val;
    } else {
      int e = v - 7168; int b = e / 12; int col = 200 + (e % 12)*2;
      *(unsigned*)(Yt + ((b*512 + col*2) ^ ((b&7)<<4))) = 0u;
    }
  }
  __syncthreads();
  for (int tp = wid; tp < 52; tp += 8) {
    int mt = tp / 13, nt = tp % 13;
    int arow = mt*16 + l15;
    f32x4 acc = {0.f,0.f,0.f,0.f};
#pragma unroll
    for (int kc = 0; kc < 7; kc++) {
      bf16x8 av = *(const bf16x8*)(Xt + ((arow*512 + kc*64 + lg*16) ^ ((arow&7)<<4)));
      bf16x8 bv = *(const bf16x8*)(linB + (nt*16 + l15)*224 + kc*32 + lg*8);
      acc = __builtin_amdgcn_mfma_f32_16x16x32_bf16(av, bv, acc, 0, 0, 0);
    }
    int col = nt*16 + l15, r0 = mt*16 + lg*4;
    if (col < 200) {
      float lbv = lin_b[col];
#pragma unroll
      for (int r = 0; r < 4; r++) {
        int row = r0 + r;
        *(__hip_bfloat16*)(Yt + ((row*512 + col*2) ^ ((row&7)<<4))) = tobf(fmaxf(acc[r] + lbv, 0.f));
      }
    }
  }
  __syncthreads();
  for (int tp = wid; tp < 100; tp += 8) {
    int mt = tp / 25, nt = tp % 25;
    int arow = mt*16 + l15;
    f32x4 acc = {0.f,0.f,0.f,0.f};
#pragma unroll
    for (int kc = 0; kc < 7; kc++) {
      bf16x8 av = *(const bf16x8*)(Yt + ((arow*512 + kc*64 + lg*16) ^ ((arow&7)<<4)));
      bf16x8 bv = *(const bf16x8*)(wihB + (nt*16 + l15)*224 + kc*32 + lg*8);
      acc = __builtin_amdgcn_mfma_f32_16x16x32_bf16(av, bv, acc, 0, 0, 0);
    }
    int col = nt*16 + l15, r0 = mt*16 + lg*4;
    float bs = bih[col] + bhh[col];
#pragma unroll
    for (int r = 0; r < 4; r++)
      xg[(size_t)(t*128 + rb + r0 + r)*400 + col] = tobf(acc[r] + bs);
  }
}

// ---------------------------------------------------------------------------
// P3: per-(b,t) top-10, float4 inner dot
// ---------------------------------------------------------------------------
__global__ __launch_bounds__(256, 2) void k_topk(
    const float* __restrict__ emb_q, const int* __restrict__ question,
    int* __restrict__ topidx)
{
  __shared__ __align__(16) float Qb[150*104];
  __shared__ int qid[150];
  __shared__ float tval[1490];
  __shared__ int tidxs[1490];
  const int b = blockIdx.x, tid = threadIdx.x;
  if (tid < 150) qid[tid] = question[b*TT + tid];
  __syncthreads();
  for (int i = tid; i < 15000; i += 256) { int r = i/100, c = i%100; Qb[r*104+c] = emb_q[qid[r]*100+c]; }
  __syncthreads();
  if (tid < TS) {
    const int t = tid;
    float* v = &tval[t*10]; int* ix = &tidxs[t*10];
    for (int p = 0; p < 10; p++) { v[p] = -3.0e38f; ix[p] = 0; }
    const float4* qrow = (const float4*)&Qb[(t+1)*104];
    for (int j = 0; j < t; j++) {
      const float4* r = (const float4*)&Qb[j*104];
      float s = 0.f;
#pragma unroll
      for (int k4 = 0; k4 < 25; k4++) {
        float4 a = qrow[k4], c = r[k4];
        s += a.x*c.x + a.y*c.y + a.z*c.z + a.w*c.w;
      }
      if (s > v[9]) {
        int p = 9;
        while (p > 0 && s > v[p-1]) { v[p] = v[p-1]; ix[p] = ix[p-1]; p--; }
        v[p] = s; ix[p] = j;
      }
    }
    for (int p = 0; p < 10; p++) topidx[(t*BB + b)*10 + p] = ix[p];
  }
}

// ---------------------------------------------------------------------------
// P4a: LSTM-only scan; Whh in registers; 4-way split accumulators.
// ---------------------------------------------------------------------------
__global__ __launch_bounds__(448, 1) void k_lstm(
    const uint4* __restrict__ WhP,
    const __hip_bfloat16* __restrict__ xg,
    const float* __restrict__ h0, const float* __restrict__ c0,
    unsigned* __restrict__ hstG, float* __restrict__ out)
{
  __shared__ unsigned hbfu[52];
  __shared__ float gates[400];
  const int b = blockIdx.x, tid = threadIdx.x;
  uint4 w[13];
  if (tid < 400) {
#pragma unroll
    for (int k8 = 0; k8 < 13; k8++) w[k8] = WhP[tid*13 + k8];
  }
  float c = 0.f;
  if (tid < 100) c = c0[b*100 + tid];
  if (tid < 50) hbfu[tid] = pk2(h0[b*100 + 2*tid], h0[b*100 + 2*tid + 1]);
  else if (tid < 52) hbfu[tid] = 0u;
  if (tid == 128) out[b*TT] = 0.5f;
  float xpre = 0.f;
  if (tid < 400) xpre = bf(xg[(size_t)b*400 + tid]);
  __syncthreads();
  for (int t = 0; t < TS; t++) {
    if (tid < 400) {
      float a0 = xpre, a1 = 0.f, a2 = 0.f, a3 = 0.f;
      if (t + 1 < TS) xpre = bf(xg[((size_t)(t+1)*BB + b)*400 + tid]);
#pragma unroll
      for (int k8 = 0; k8 < 13; k8++) {
        uint4 h = *(const uint4*)&hbfu[k8*4];
        a0 = fmaf(blo(w[k8].x), blo(h.x), a0);
        a1 = fmaf(bhi(w[k8].x), bhi(h.x), a1);
        a2 = fmaf(blo(w[k8].y), blo(h.y), a2);
        a3 = fmaf(bhi(w[k8].y), bhi(h.y), a3);
        a0 = fmaf(blo(w[k8].z), blo(h.z), a0);
        a1 = fmaf(bhi(w[k8].z), bhi(h.z), a1);
        a2 = fmaf(blo(w[k8].w), blo(h.w), a2);
        a3 = fmaf(bhi(w[k8].w), bhi(h.w), a3);
      }
      gates[tid] = (a0 + a1) + (a2 + a3);
    }
    __syncthreads();
    if (tid < 100) {
      float cc = sigm(gates[100+tid])*c + sigm(gates[tid])*tanhf(gates[200+tid]);
      c = cc;
      float hn = sigm(gates[300+tid])*tanhf(cc);
      float hp = __shfl_xor(hn, 1);
      if (!(tid & 1)) {
        unsigned pkv = pk2(hn, hp);
        hbfu[tid >> 1] = pkv;
        hstG[((size_t)b*TS + t)*50 + (tid >> 1)] = pkv;
      }
    }
    __syncthreads();
  }
}

// ---------------------------------------------------------------------------
// P4b: attention/prediction — parallel over (b,t); 4-way split dot chains.
// ---------------------------------------------------------------------------
__global__ __launch_bounds__(512, 1) void k_attn(
    const float* __restrict__ emb_q, const float* __restrict__ emb_s,
    const int* __restrict__ question, const int* __restrict__ qs_skill,
    const int* __restrict__ topidx, const unsigned* __restrict__ hstG,
    const float* __restrict__ kvqv, float* __restrict__ out)
{
  __shared__ __align__(16) uint2 Hl[149*26];
  __shared__ __align__(16) float qsb[8][500];
  __shared__ float sqb[8][5];
  __shared__ float skt[152];
  __shared__ __align__(16) float qvl[100];
  const int b = blockIdx.x, tid = threadIdx.x;
  const int wv = tid >> 6, lane = tid & 63;
  for (int i = tid; i < 149*25; i += 512) {
    int r = i / 25, cc = i % 25;
    Hl[r*26 + cc] = *(const uint2*)&hstG[((size_t)b*TS + r)*50 + cc*2];
  }
  if (tid < 100) qvl[tid] = kvqv[100 + tid];
  __syncthreads();
  const float ck = kvqv[200], cq = kvqv[201], wb0 = kvqv[202];
  if (tid < 298) {
    int r = tid >> 1, half = tid & 1;
    float s0=0.f,s1=0.f,s2=0.f,s3=0.f;
    for (int cc = half*13; cc < (half ? 25 : 13); cc++) {
      uint2 u = Hl[r*26 + cc];
      float4 kvv = *(const float4*)&kvqv[cc*4];
      s0 = fmaf(blo(u.x), kvv.x, s0); s1 = fmaf(bhi(u.x), kvv.y, s1);
      s2 = fmaf(blo(u.y), kvv.z, s2); s3 = fmaf(bhi(u.y), kvv.w, s3);
    }
    float s = (s0+s1)+(s2+s3);
    s += __shfl_xor(s, 1);
    if (!half) skt[r] = s + ck;
  }
  __syncthreads();
  for (int t0 = 0; t0 < TS; t0 += 8) {
    int t = t0 + wv;
    if (t >= TS) continue;
    const int qn = question[b*TT + t + 1];
    for (int e = lane; e < 500; e += 64) {
      int q = e / 100;
      qsb[wv][e] = (q == 0) ? emb_q[qn*100 + e]
                            : emb_s[qs_skill[qn*4 + q - 1]*100 + e%100];
    }
    if (lane >= 55 && lane < 60) {
      int q = lane - 55;
      const float4* qq = (const float4*)&qsb[wv][q*100];
      float s0=0.f,s1=0.f,s2=0.f,s3=0.f;
      for (int cc = 0; cc < 25; cc++) {
        float4 a = qq[cc]; float4 qv4 = *(const float4*)&qvl[cc*4];
        s0 = fmaf(a.x, qv4.x, s0); s1 = fmaf(a.y, qv4.y, s1);
        s2 = fmaf(a.z, qv4.z, s2); s3 = fmaf(a.w, qv4.w, s3);
      }
      sqb[wv][q] = (s0+s1)+(s2+s3) + cq;
    }
    float scv = -3.0e38f, gval = 0.f;
    if (lane < 55) {
      int q = lane / 11, s = lane % 11;
      int j; bool valid = true;
      float sk = 0.f;
      if (s == 0) { j = t; sk = skt[t]; }
      else {
        int cnt = t < 10 ? t : 10;
        if (s - 1 < cnt) {
          j = topidx[((size_t)t*BB + b)*10 + s - 1];
          sk = (j == 0) ? ck : skt[j];
        } else { j = -1; valid = false; }
      }
      if ((valid && j > 0) || (s == 0 && j == 0)) {
        const uint2* hr = &Hl[(j > 0 ? j : 0)*26];
        const float4* qq = (const float4*)&qsb[wv][q*100];
        float g0=0.f,g1=0.f,g2=0.f,g3=0.f;
        for (int cc = 0; cc < 25; cc++) {
          uint2 u = hr[cc]; float4 a = qq[cc];
          g0 = fmaf(blo(u.x), a.x, g0); g1 = fmaf(bhi(u.x), a.y, g1);
          g2 = fmaf(blo(u.y), a.z, g2); g3 = fmaf(bhi(u.y), a.w, g3);
        }
        gval = (g0+g1)+(g2+g3);
      }
      scv = valid ? (sqb[wv][q] + sk + wb0) : -1e9f;
    }
    float m = scv;
#pragma unroll
    for (int o = 32; o; o >>= 1) m = fmaxf(m, __shfl_xor(m, o));
    float ex = (lane < 55) ? expf(scv - m) : 0.f;
    float num = ex * gval, den = ex;
#pragma unroll
    for (int o = 32; o; o >>= 1) { num += __shfl_xor(num, o); den += __shfl_xor(den, o); }
    if (lane == 0) out[b*TT + t + 1] = sigm(num/den);
  }
}

extern "C" void kernel_launch(void* const* d_in, const int* in_sizes, int n_in,
                              void* d_out, int out_size, void* d_ws, size_t ws_size,
                              hipStream_t stream) {
  const float* emb_q  = (const float*)d_in[0];
  const float* emb_q2 = (const float*)d_in[1];
  const float* emb_s  = (const float*)d_in[2];
  const float* emb_u  = (const float*)d_in[3];
  const float* emb_r  = (const float*)d_in[4];
  const float* w1_q   = (const float*)d_in[5];
  const float* w2_q   = (const float*)d_in[6];
  const float* lin_W  = (const float*)d_in[7];
  const float* lin_b  = (const float*)d_in[8];
  const float* Wih    = (const float*)d_in[9];
  const float* Whh    = (const float*)d_in[10];
  const float* bih    = (const float*)d_in[11];
  const float* bhh    = (const float*)d_in[12];
  const float* agg_W  = (const float*)d_in[13];
  const float* agg_b  = (const float*)d_in[14];
  const float* last_W = (const float*)d_in[15];
  const float* last_b = (const float*)d_in[16];
  const float* qW     = (const float*)d_in[17];
  const float* qb     = (const float*)d_in[18];
  const float* kW     = (const float*)d_in[19];
  const float* kb     = (const float*)d_in[20];
  const float* wW     = (const float*)d_in[21];
  const float* wb     = (const float*)d_in[22];
  const float* h0     = (const float*)d_in[23];
  const float* c0     = (const float*)d_in[24];
  const int* user      = (const int*)d_in[25];
  const int* question  = (const int*)d_in[26];
  const int* response  = (const int*)d_in[27];
  const int* mask      = (const int*)d_in[28];
  const int* q_nb      = (const int*)d_in[29];
  const int* s_nb      = (const int*)d_in[30];
  const int* u_nb      = (const int*)d_in[31];
  const int* q_nb2     = (const int*)d_in[32];
  const int* qs_skill  = (const int*)d_in[33];

  char* ws = (char*)d_ws;
  __hip_bfloat16* embhat = (__hip_bfloat16*)(ws + 0);          //  3,814,400
  __hip_bfloat16* xg     = (__hip_bfloat16*)(ws + 3814400);    // 15,257,600
  int*            topidx = (int*)(ws + 19072000);              //    762,880
  __hip_bfloat16* Wb     = (__hip_bfloat16*)(ws + 19834880);   //    131,072
  uint2*          W0g    = (uint2*)(ws + 19965952);            //     20,000
  uint2*          WLg    = (uint2*)(ws + 19985952);            //     20,000
  __hip_bfloat16* linB   = (__hip_bfloat16*)(ws + 20005952);   //     93,184
  __hip_bfloat16* wihB   = (__hip_bfloat16*)(ws + 20099136);   //    179,200
  uint2*          gQ     = (uint2*)(ws + 20278336);            // 10,000,000
  uint2*          gU     = (uint2*)(ws + 30278336);            //  4,000,000
  uint2*          gT1Q   = (uint2*)(ws + 34278336);            //    400,000
  uint2*          gT1U   = (uint2*)(ws + 34678336);            // 10,000,000
  uint4*          WhP    = (uint4*)(ws + 44678336);            //     83,200
  float*          kvqv   = (float*)(ws + 44761536);            //      1,024
  unsigned*       hstG   = (unsigned*)(ws + 44762560);         //  3,814,400
  uint2*          W0c    = (uint2*)(ws + 48576960);            //     20,000
  uint2*          WLc    = (uint2*)(ws + 48596960);            //     20,000 -> 48,616,960

  k_prep<<<2048, 256, 0, stream>>>(agg_W, last_W, lin_W, Wih,
                                   emb_q, emb_q2, emb_s, emb_u,
                                   q_nb, s_nb, u_nb, q_nb2,
                                   Whh, qW, qb, kW, kb, wW, wb,
                                   Wb, W0g, WLg, linB, wihB, gQ, gU, gT1Q, gT1U,
                                   WhP, kvqv, W0c, WLc);
  k_embhat<<<NITEM, 512, 0, stream>>>(emb_q, emb_q2, w1_q, w2_q,
                                      agg_b, last_b,
                                      user, question, mask, q_nb, s_nb, u_nb, q_nb2,
                                      Wb, W0c, WLc, gQ, gU, gT1Q, gT1U, embhat);
  k_lin<<<TS*2, 512, 0, stream>>>(emb_r, lin_b, bih, bhh, response, embhat,
                                  linB, wihB, xg);
  k_topk<<<128, 256, 0, stream>>>(emb_q, question, topidx);
  k_lstm<<<128, 448, 0, stream>>>(WhP, xg, h0, c0, hstG, (float*)d_out);
  k_attn<<<128, 512, 0, stream>>>(emb_q, emb_s, question, qs_skill,
                                  topidx, hstG, kvqv, (float*)d_out);
}

// Round 11
// 834.318 us; speedup vs baseline: 4.5740x; 1.0822x over previous
//
#include <hip/hip_runtime.h>
#include <hip/hip_bf16.h>

#define BB 128
#define TT 150
#define TS 149
#define NITEM (TS*BB)

typedef __attribute__((ext_vector_type(8))) short bf16x8;
typedef __attribute__((ext_vector_type(4))) float f32x4;

__device__ __forceinline__ float bf(__hip_bfloat16 x) { return __bfloat162float(x); }
__device__ __forceinline__ __hip_bfloat16 tobf(float x) { return __float2bfloat16(x); }
__device__ __forceinline__ float sigm(float x) { return 1.f / (1.f + expf(-x)); }

__device__ __forceinline__ unsigned pk2(float a, float b) {
  unsigned ua = __float_as_uint(a), ub = __float_as_uint(b);
  ua += 0x7fffu + ((ua >> 16) & 1u);
  ub += 0x7fffu + ((ub >> 16) & 1u);
  return (ua >> 16) | (ub & 0xffff0000u);
}
__device__ __forceinline__ float blo(unsigned u) { return __uint_as_float(u << 16); }
__device__ __forceinline__ float bhi(unsigned u) { return __uint_as_float(u & 0xffff0000u); }

// ---------------------------------------------------------------------------
// P0: one-time weight conversion + fused gather tables + kvqv
// ---------------------------------------------------------------------------
#define PREP_N 3251931
__global__ __launch_bounds__(256, 4) void k_prep(
    const float* __restrict__ agg_W, const float* __restrict__ last_W,
    const float* __restrict__ lin_W, const float* __restrict__ Wih,
    const float* __restrict__ emb_q, const float* __restrict__ emb_q2,
    const float* __restrict__ emb_s, const float* __restrict__ emb_u,
    const int* __restrict__ q_nb, const int* __restrict__ s_nb,
    const int* __restrict__ u_nb, const int* __restrict__ q_nb2,
    const float* __restrict__ qW, const float* __restrict__ qb,
    const float* __restrict__ kW, const float* __restrict__ kb,
    const float* __restrict__ wW, const float* __restrict__ wb,
    __hip_bfloat16* __restrict__ Wb,
    __hip_bfloat16* __restrict__ linB, __hip_bfloat16* __restrict__ wihB,
    uint2* __restrict__ gQ, uint2* __restrict__ gU,
    uint2* __restrict__ gT1Q, uint2* __restrict__ gT1U,
    float* __restrict__ kvqv)
{
  for (int v = blockIdx.x*256 + threadIdx.x; v < PREP_N; v += gridDim.x*256) {
    if (v < 65536) {
      int m = v >> 14, r = v & 16383, c = r >> 7, k = r & 127;
      const float* src = (m==0) ? agg_W+20000 : (m==1) ? agg_W+10000 : (m==2) ? agg_W : last_W;
      Wb[v] = tobf((c < 100 && k < 100) ? src[c*100+k] : 0.f);
    } else if (v < 112128) {
      int j = v - 65536;                     // linB [208][224]
      int c = j / 224, k = j % 224;
      linB[j] = tobf((c < 200 && k < 200) ? lin_W[c*200+k] : 0.f);
    } else if (v < 201728) {
      int j = v - 112128;                    // wihB [400][224]
      int c = j / 224, k = j % 224;
      wihB[j] = tobf((k < 200) ? Wih[c*200+k] : 0.f);
    } else if (v < 1451728) {                // gQ
      int j = v - 201728, q = j / 25, k4 = j % 25;
      float sx=0.f,sy=0.f,sz=0.f,sw=0.f;
#pragma unroll
      for (int i = 0; i < 4; i++) {
        float4 e = *(const float4*)&emb_s[q_nb[q*4+i]*100 + k4*4];
        sx+=e.x; sy+=e.y; sz+=e.z; sw+=e.w;
      }
      float4 a = *(const float4*)&emb_q[q*100 + k4*4];
      gQ[j] = make_uint2(pk2(0.25f*sx+a.x, 0.25f*sy+a.y), pk2(0.25f*sz+a.z, 0.25f*sw+a.w));
    } else if (v < 1951728) {                // gU
      int j = v - 1451728, u = j / 25, k4 = j % 25;
      float sx=0.f,sy=0.f,sz=0.f,sw=0.f;
      for (int k = 0; k < 10; k++) {
        float4 e = *(const float4*)&emb_q2[u_nb[u*10+k]*100 + k4*4];
        sx+=e.x; sy+=e.y; sz+=e.z; sw+=e.w;
      }
      float4 a = *(const float4*)&emb_u[u*100 + k4*4];
      gU[j] = make_uint2(pk2(0.1f*sx+a.x, 0.1f*sy+a.y), pk2(0.1f*sz+a.z, 0.1f*sw+a.w));
    } else if (v < 2001728) {                // gT1Q (skills)
      int j = v - 1951728, s = j / 25, k4 = j % 25;
      float sx=0.f,sy=0.f,sz=0.f,sw=0.f;
      for (int jj = 0; jj < 10; jj++) {
        float4 e = *(const float4*)&emb_q[s_nb[s*10+jj]*100 + k4*4];
        sx+=e.x; sy+=e.y; sz+=e.z; sw+=e.w;
      }
      float4 a = *(const float4*)&emb_s[s*100 + k4*4];
      gT1Q[j] = make_uint2(pk2(0.1f*sx+a.x, 0.1f*sy+a.y), pk2(0.1f*sz+a.z, 0.1f*sw+a.w));
    } else if (v < 3251728) {                // gT1U (questions)
      int j = v - 2001728, q = j / 25, k4 = j % 25;
      float sx=0.f,sy=0.f,sz=0.f,sw=0.f;
#pragma unroll
      for (int p = 0; p < 5; p++) {
        float4 e = *(const float4*)&emb_u[q_nb2[q*5+p]*100 + k4*4];
        sx+=e.x; sy+=e.y; sz+=e.z; sw+=e.w;
      }
      float4 a = *(const float4*)&emb_q2[q*100 + k4*4];
      gT1U[j] = make_uint2(pk2(0.2f*sx+a.x, 0.2f*sy+a.y), pk2(0.2f*sz+a.z, 0.2f*sw+a.w));
    } else {                                 // kvqv: kv[100], qv[100], ck, cq, wb0
      int idx = v - 3251728;
      float s = 0.f;
      if (idx < 100)      { for (int c = 0; c < 100; c++) s += kW[c*100+idx] * wW[100+c]; kvqv[idx] = s; }
      else if (idx < 200) { int t2 = idx-100; for (int c = 0; c < 100; c++) s += qW[c*100+t2] * wW[c]; kvqv[idx] = s; }
      else if (idx == 200){ for (int c = 0; c < 100; c++) s += kb[c] * wW[100+c]; kvqv[200] = s; }
      else if (idx == 201){ for (int c = 0; c < 100; c++) s += qb[c] * wW[c]; kvqv[201] = s; }
      else kvqv[202] = wb[0];
    }
  }
}

// ---------------------------------------------------------------------------
// P1: multi-hop aggregate to t0c-inputs. Heavy: u0[item*200+side*100+..] bf16.
//     Light: u0[item*200+..] = final emb_hat (first 100 elems).
// ---------------------------------------------------------------------------
__global__ __launch_bounds__(512, 6) void k_embhat(
    const float* __restrict__ emb_q, const float* __restrict__ emb_q2,
    const float* __restrict__ w1_q, const float* __restrict__ w2_q,
    const float* __restrict__ agg_b,
    const int* __restrict__ user, const int* __restrict__ question, const int* __restrict__ mask,
    const int* __restrict__ q_nb, const int* __restrict__ s_nb,
    const int* __restrict__ u_nb, const int* __restrict__ q_nb2,
    const __hip_bfloat16* __restrict__ Wb,
    const uint2* __restrict__ gQ, const uint2* __restrict__ gU,
    const uint2* __restrict__ gT1Q, const uint2* __restrict__ gT1U,
    unsigned* __restrict__ u0)
{
  __shared__ __align__(16) char Ab[114*256];        // [114 rows][128 k] bf16 swizzled
  __shared__ __hip_bfloat16 Cb[114*100];            // C rows bf16
  __shared__ int n2[40], m2[50], n1[4], m1[10];
  const int tid = threadIdx.x, wid = tid >> 6, lane = tid & 63;
  const int l15 = lane & 15, lg = lane >> 4;
  const int item = blockIdx.x;
  const int t = item / BB, b = item % BB;
  const int qt = question[b*TT + t];
  const float w1 = w1_q[0], w2 = w2_q[0];

  if (mask[b*TT + t] != 1) {
    if (tid < 50) {
      const float2 q = *(const float2*)&emb_q[qt*100 + tid*2];
      const float2 p = *(const float2*)&emb_q2[qt*100 + tid*2];
      u0[(size_t)item*100 + tid] = pk2(w1*q.x + w2*p.x, w1*q.y + w2*p.y);
    }
    return;
  }
  const int ut = user[b*TT + t];

  // preload W2 B-fragments (wave = nt)
  bf16x8 w2f[4];
  if (wid < 7) {
#pragma unroll
    for (int kc = 0; kc < 4; kc++)
      w2f[kc] = *(const bf16x8*)(Wb + (wid*16 + l15)*128 + kc*32 + lg*8);
  }

  // ---- phase A: index staging + zero-pads ----
  for (int v = tid; v < 1102; v += 512) {
    if (v < 40) { int n1a = q_nb[qt*4 + v/10]; n2[v] = s_nb[n1a*10 + v%10]; }
    else if (v < 90) { int e = v-40; int m1a = u_nb[ut*10 + e/5]; m2[e] = q_nb2[m1a*5 + e%5]; }
    else if (v < 94) { n1[v-90] = q_nb[qt*4 + (v-90)]; }
    else if (v < 104) { m1[v-94] = u_nb[ut*10 + (v-94)]; }
    else {
      int z = v - 104, row, k4;
      if (z < 798) { row = z/7; k4 = 25 + z%7; }
      else if (z < 948) { int e = z-798; row = 90 + e/25; k4 = e%25; }
      else { int e = z-948; row = 110 + e/25; k4 = e%25; }
      int ofs = (row*256 + k4*8) ^ ((row&7)<<4);
      *(uint2*)(Ab + ofs) = make_uint2(0u, 0u);
    }
  }
  __syncthreads();
  // ---- phase B: single-row table gathers ----
  for (int v = tid; v < 2650; v += 512) {
    const uint2* src; int row, k4;
    if (v < 1000) { int r = v/25; k4 = v%25; src = &gQ[n2[r]*25]; row = r; }
    else if (v < 2250) { int e = v-1000; int r = e/25; k4 = e%25; src = &gU[m2[r]*25]; row = 40+r; }
    else if (v < 2350) { int e = v-2250; int a = e/25; k4 = e%25; src = &gT1Q[n1[a]*25]; row = 96+a; }
    else if (v < 2600) { int e = v-2350; int a = e/25; k4 = e%25; src = &gT1U[m1[a]*25]; row = 100+a; }
    else if (v < 2625) { k4 = v-2600; src = &gQ[qt*25]; row = 112; }
    else { k4 = v-2625; src = &gU[ut*25]; row = 113; }
    int ofs = (row*256 + k4*8) ^ ((row&7)<<4);
    *(uint2*)(Ab + ofs) = src[k4];
  }
  __syncthreads();
  // ---- P1: L1 MFMA — wave nt=wid, mt 0-5: W2 (regs), mt6: W1, mt7: W0 ----
  if (wid < 7) {
    const int nt = wid, brow = nt*16 + l15;
#pragma unroll
    for (int mt = 0; mt < 6; mt++) {
      int arow = mt*16 + l15;
      f32x4 acc = {0.f,0.f,0.f,0.f};
#pragma unroll
      for (int kc = 0; kc < 4; kc++) {
        bf16x8 av = *(const bf16x8*)(Ab + ((arow*256 + kc*64 + lg*16) ^ ((arow&7)<<4)));
        acc = __builtin_amdgcn_mfma_f32_16x16x32_bf16(av, w2f[kc], acc, 0, 0, 0);
      }
      int col = nt*16 + l15, r0 = mt*16 + lg*4;
      if (col < 100) {
#pragma unroll
        for (int r = 0; r < 4; r++)
          if (r0 + r < 114) Cb[(r0+r)*100 + col] = tobf(acc[r]);
      }
    }
#pragma unroll
    for (int mt = 6; mt < 8; mt++) {
      const __hip_bfloat16* wm = Wb + ((mt == 6) ? 16384 : 32768);
      int arow = mt*16 + l15; if (arow > 113) arow = 113;
      f32x4 acc = {0.f,0.f,0.f,0.f};
#pragma unroll
      for (int kc = 0; kc < 4; kc++) {
        bf16x8 av = *(const bf16x8*)(Ab + ((arow*256 + kc*64 + lg*16) ^ ((arow&7)<<4)));
        bf16x8 bv = *(const bf16x8*)(wm + brow*128 + kc*32 + lg*8);
        acc = __builtin_amdgcn_mfma_f32_16x16x32_bf16(av, bv, acc, 0, 0, 0);
      }
      int col = nt*16 + l15, r0 = mt*16 + lg*4;
      if (col < 100) {
#pragma unroll
        for (int r = 0; r < 4; r++)
          if (r0 + r < 114) Cb[(r0+r)*100 + col] = tobf(acc[r]);
      }
    }
  }
  __syncthreads();
  // ---- P2: reduce + build L2 inputs ----
  for (int v = tid; v < 400; v += 512) {
    int k4 = (v < 350) ? v % 25 : (v - 350) % 25;
    float4 b2q = *(const float4*)&agg_b[200 + k4*4];
    float4 b1q = *(const float4*)&agg_b[100 + k4*4];
    float4 b0q = *(const float4*)&agg_b[k4*4];
    float x0, x1, x2, x3; int row;
#define RELU4(rr, bq, r0v,r1v,r2v,r3v) { \
    r0v = fmaxf(bf(Cb[(rr)*100 + k4*4+0]) + bq.x, 0.f); \
    r1v = fmaxf(bf(Cb[(rr)*100 + k4*4+1]) + bq.y, 0.f); \
    r2v = fmaxf(bf(Cb[(rr)*100 + k4*4+2]) + bq.z, 0.f); \
    r3v = fmaxf(bf(Cb[(rr)*100 + k4*4+3]) + bq.w, 0.f); }
    if (v < 350) {
      int a = v / 25;
      float s0=0.f,s1=0.f,s2=0.f,s3=0.f, r0,r1,r2,r3;
      float inv;
      if (a < 4) {
        for (int s = 0; s < 10; s++) { RELU4(a*10+s, b2q, r0,r1,r2,r3); s0+=r0;s1+=r1;s2+=r2;s3+=r3; }
        inv = 0.1f; RELU4(96+a, b1q, r0,r1,r2,r3);
      } else {
        int au = a - 4;
        for (int p = 0; p < 5; p++) { RELU4(40+au*5+p, b2q, r0,r1,r2,r3); s0+=r0;s1+=r1;s2+=r2;s3+=r3; }
        inv = 0.2f; RELU4(100+au, b1q, r0,r1,r2,r3);
      }
      x0 = inv*s0+r0; x1 = inv*s1+r1; x2 = inv*s2+r2; x3 = inv*s3+r3;
      row = a;
    } else {
      float s0=0.f,s1=0.f,s2=0.f,s3=0.f, r0,r1,r2,r3;
      if (v < 375) {
        for (int a = 0; a < 4; a++) { RELU4(96+a, b1q, r0,r1,r2,r3); s0+=r0;s1+=r1;s2+=r2;s3+=r3; }
        RELU4(112, b0q, r0,r1,r2,r3);
        x0 = 0.25f*s0+r0; x1 = 0.25f*s1+r1; x2 = 0.25f*s2+r2; x3 = 0.25f*s3+r3;
        row = 16;
      } else {
        for (int a = 0; a < 10; a++) { RELU4(100+a, b1q, r0,r1,r2,r3); s0+=r0;s1+=r1;s2+=r2;s3+=r3; }
        RELU4(113, b0q, r0,r1,r2,r3);
        x0 = 0.1f*s0+r0; x1 = 0.1f*s1+r1; x2 = 0.1f*s2+r2; x3 = 0.1f*s3+r3;
        row = 17;
      }
    }
    int ofs = (row*256 + k4*8) ^ ((row&7)<<4);
    *(uint2*)(Ab + ofs) = make_uint2(pk2(x0,x1), pk2(x2,x3));
  }
  __syncthreads();
  // ---- P3: L2 MFMA — mt0 (rows 0-15, W1), mt1 (rows 16-31, W0) ----
  if (wid < 7) {
    const int nt = wid, brow = nt*16 + l15;
#pragma unroll
    for (int mt = 0; mt < 2; mt++) {
      const __hip_bfloat16* wm = Wb + (mt ? 32768 : 16384);
      int arow = mt*16 + l15;
      f32x4 acc = {0.f,0.f,0.f,0.f};
#pragma unroll
      for (int kc = 0; kc < 4; kc++) {
        bf16x8 av = *(const bf16x8*)(Ab + ((arow*256 + kc*64 + lg*16) ^ ((arow&7)<<4)));
        bf16x8 bv = *(const bf16x8*)(wm + brow*128 + kc*32 + lg*8);
        acc = __builtin_amdgcn_mfma_f32_16x16x32_bf16(av, bv, acc, 0, 0, 0);
      }
      int col = nt*16 + l15, r0 = mt*16 + lg*4;
      if (col < 100) {
#pragma unroll
        for (int r = 0; r < 4; r++)
          if (r0 + r < 114) Cb[(r0+r)*100 + col] = tobf(acc[r]);
      }
    }
  }
  __syncthreads();
  // ---- P4: build t0c inputs and write bf16 to u0 (ends kernel) ----
  if (tid < 50) {
    int side = tid / 25, k4 = tid % 25;
    float4 b1q = *(const float4*)&agg_b[100 + k4*4];
    float4 b0q = *(const float4*)&agg_b[k4*4];
    float s0=0.f,s1=0.f,s2=0.f,s3=0.f, r0,r1,r2,r3;
    float inv;
    if (side == 0) {
      for (int a = 0; a < 4; a++) { RELU4(a, b1q, r0,r1,r2,r3); s0+=r0;s1+=r1;s2+=r2;s3+=r3; }
      inv = 0.25f; RELU4(16, b0q, r0,r1,r2,r3);
    } else {
      for (int a = 4; a < 14; a++) { RELU4(a, b1q, r0,r1,r2,r3); s0+=r0;s1+=r1;s2+=r2;s3+=r3; }
      inv = 0.1f; RELU4(17, b0q, r0,r1,r2,r3);
    }
    float x0 = inv*s0+r0, x1 = inv*s1+r1, x2 = inv*s2+r2, x3 = inv*s3+r3;
    *(uint2*)&u0[(size_t)item*100 + side*50 + k4*2] = make_uint2(pk2(x0,x1), pk2(x2,x3));
  }
#undef RELU4
}

// ---------------------------------------------------------------------------
// P2: GEMM chain: t0cin -> W0(relu) -> WL(relu) -> combine(mask) -> X ->
//     lin(relu) -> Wih -> xg.  32 items per block, 4 barriers, 32KB LDS.
// ---------------------------------------------------------------------------
__global__ __launch_bounds__(512, 4) void k_chain(
    const float* __restrict__ emb_r,
    const float* __restrict__ agg_b, const float* __restrict__ last_b,
    const float* __restrict__ lin_b, const float* __restrict__ bih,
    const float* __restrict__ bhh,
    const float* __restrict__ w1_q, const float* __restrict__ w2_q,
    const int* __restrict__ response, const int* __restrict__ mask,
    const unsigned* __restrict__ u0,
    const __hip_bfloat16* __restrict__ Wb,
    const __hip_bfloat16* __restrict__ linB, const __hip_bfloat16* __restrict__ wihB,
    __hip_bfloat16* __restrict__ xg)
{
  __shared__ __align__(16) char B1[64*256];  // A1 [64][128] bf16; later Xt [32][224]@512B
  __shared__ __align__(16) char B2[64*256];  // Xb [64][128] bf16; later Yt [32][224]@512B
  __shared__ int msk[32];
  const int tid = threadIdx.x, wid = tid >> 6, lane = tid & 63;
  const int l15 = lane & 15, lg = lane >> 4;
  const int t = blockIdx.x >> 2, rb = (blockIdx.x & 3) << 5;
  const float w1 = w1_q[0], w2 = w2_q[0];
  // ---- P1: stage A1 + zero pads + mask ----
  for (int v = tid; v < 2528; v += 512) {
    if (v < 1600) {
      int row = v / 25, k4 = v % 25;
      int item = t*128 + rb + (row >> 1), side = row & 1;
      uint2 val = *(const uint2*)&u0[(size_t)item*100 + side*50 + k4*2];
      *(uint2*)(B1 + ((row*256 + k4*8) ^ ((row&7)<<4))) = val;
    } else if (v < 2048) {
      int e = v-1600; int row = e/7, k4 = 25 + e%7;
      *(uint2*)(B1 + ((row*256 + k4*8) ^ ((row&7)<<4))) = make_uint2(0u,0u);
    } else if (v < 2496) {
      int e = v-2048; int row = e/7, k4 = 25 + e%7;
      *(uint2*)(B2 + ((row*256 + k4*8) ^ ((row&7)<<4))) = make_uint2(0u,0u);
    } else {
      int i = v - 2496;
      msk[i] = mask[(rb+i)*TT + t];
    }
  }
  __syncthreads();
  // ---- P2: GEMM W0 -> relu -> Xb (B2) ----
  for (int tp = wid; tp < 28; tp += 8) {
    int mt = tp / 7, nt = tp % 7;
    int arow = mt*16 + l15;
    f32x4 acc = {0.f,0.f,0.f,0.f};
#pragma unroll
    for (int kc = 0; kc < 4; kc++) {
      bf16x8 av = *(const bf16x8*)(B1 + ((arow*256 + kc*64 + lg*16) ^ ((arow&7)<<4)));
      bf16x8 bv = *(const bf16x8*)(Wb + 32768 + (nt*16 + l15)*128 + kc*32 + lg*8);
      acc = __builtin_amdgcn_mfma_f32_16x16x32_bf16(av, bv, acc, 0, 0, 0);
    }
    int col = nt*16 + l15, r0 = mt*16 + lg*4;
    if (col < 100) {
      float b0v = agg_b[col];
#pragma unroll
      for (int r = 0; r < 4; r++) {
        int row = r0 + r;
        *(__hip_bfloat16*)(B2 + ((row*256 + col*2) ^ ((row&7)<<4))) = tobf(fmaxf(acc[r] + b0v, 0.f));
      }
    }
  }
  __syncthreads();
  // ---- P3: GEMM WL -> relu -> combine(mask) -> Xt (B1) + emb_r + pad ----
  for (int tp = wid; tp < 28; tp += 8) {
    int mt = tp / 7, nt = tp % 7;
    int arow = mt*16 + l15;
    f32x4 acc = {0.f,0.f,0.f,0.f};
#pragma unroll
    for (int kc = 0; kc < 4; kc++) {
      bf16x8 av = *(const bf16x8*)(B2 + ((arow*256 + kc*64 + lg*16) ^ ((arow&7)<<4)));
      bf16x8 bv = *(const bf16x8*)(Wb + 49152 + (nt*16 + l15)*128 + kc*32 + lg*8);
      acc = __builtin_amdgcn_mfma_f32_16x16x32_bf16(av, bv, acc, 0, 0, 0);
    }
    int col = nt*16 + l15, r0 = mt*16 + lg*4;
    if (col < 100) {
      float blv = last_b[col];
#pragma unroll
      for (int pp = 0; pp < 2; pp++) {
        int il = (r0 >> 1) + pp;
        int item = t*128 + rb + il;
        float e;
        if (msk[il] == 1)
          e = w1*fmaxf(acc[2*pp] + blv, 0.f) + w2*fmaxf(acc[2*pp+1] + blv, 0.f);
        else
          e = bf(((const __hip_bfloat16*)u0)[(size_t)item*200 + col]);
        *(__hip_bfloat16*)(B1 + ((il*512 + col*2) ^ ((il&7)<<4))) = tobf(e);
      }
    }
  }
  for (int v = tid; v < 1984; v += 512) {
    if (v < 1600) {
      int row = v / 50, c2 = v % 50; int col = 100 + c2*2;
      int rt = response[(rb+row)*TT + t];
      unsigned val = pk2(emb_r[rt*100 + c2*2], emb_r[rt*100 + c2*2 + 1]);
      *(unsigned*)(B1 + ((row*512 + col*2) ^ ((row&7)<<4))) = val;
    } else {
      int e = v - 1600; int row = e/12, col = 200 + (e%12)*2;
      *(unsigned*)(B1 + ((row*512 + col*2) ^ ((row&7)<<4))) = 0u;
    }
  }
  __syncthreads();
  // ---- P4: zero Yt pad + GEMM lin -> relu -> Yt (B2 as [32][512B]) ----
  for (int v = tid; v < 384; v += 512) {
    int row = v/12, col = 200 + (v%12)*2;
    *(unsigned*)(B2 + ((row*512 + col*2) ^ ((row&7)<<4))) = 0u;
  }
  for (int tp = wid; tp < 26; tp += 8) {
    int mt = tp / 13, nt = tp % 13;
    int arow = mt*16 + l15;
    f32x4 acc = {0.f,0.f,0.f,0.f};
#pragma unroll
    for (int kc = 0; kc < 7; kc++) {
      bf16x8 av = *(const bf16x8*)(B1 + ((arow*512 + kc*64 + lg*16) ^ ((arow&7)<<4)));
      bf16x8 bv = *(const bf16x8*)(linB + (nt*16 + l15)*224 + kc*32 + lg*8);
      acc = __builtin_amdgcn_mfma_f32_16x16x32_bf16(av, bv, acc, 0, 0, 0);
    }
    int col = nt*16 + l15, r0 = mt*16 + lg*4;
    if (col < 200) {
      float lbv = lin_b[col];
#pragma unroll
      for (int r = 0; r < 4; r++) {
        int row = r0 + r;
        *(__hip_bfloat16*)(B2 + ((row*512 + col*2) ^ ((row&7)<<4))) = tobf(fmaxf(acc[r] + lbv, 0.f));
      }
    }
  }
  __syncthreads();
  // ---- P5: GEMM wih -> xg ----
  for (int tp = wid; tp < 50; tp += 8) {
    int mt = tp / 25, nt = tp % 25;
    int arow = mt*16 + l15;
    f32x4 acc = {0.f,0.f,0.f,0.f};
#pragma unroll
    for (int kc = 0; kc < 7; kc++) {
      bf16x8 av = *(const bf16x8*)(B2 + ((arow*512 + kc*64 + lg*16) ^ ((arow&7)<<4)));
      bf16x8 bv = *(const bf16x8*)(wihB + (nt*16 + l15)*224 + kc*32 + lg*8);
      acc = __builtin_amdgcn_mfma_f32_16x16x32_bf16(av, bv, acc, 0, 0, 0);
    }
    int col = nt*16 + l15, r0 = mt*16 + lg*4;
    float bs = bih[col] + bhh[col];
#pragma unroll
    for (int r = 0; r < 4; r++)
      xg[(size_t)(t*128 + rb + r0 + r)*400 + col] = tobf(acc[r] + bs);
  }
}

// ---------------------------------------------------------------------------
// P3: per-(b,t) top-10, float4 inner dot
// ---------------------------------------------------------------------------
__global__ __launch_bounds__(256, 2) void k_topk(
    const float* __restrict__ emb_q, const int* __restrict__ question,
    int* __restrict__ topidx)
{
  __shared__ __align__(16) float Qb[150*104];
  __shared__ int qid[150];
  __shared__ float tval[1490];
  __shared__ int tidxs[1490];
  const int b = blockIdx.x, tid = threadIdx.x;
  if (tid < 150) qid[tid] = question[b*TT + tid];
  __syncthreads();
  for (int i = tid; i < 15000; i += 256) { int r = i/100, c = i%100; Qb[r*104+c] = emb_q[qid[r]*100+c]; }
  __syncthreads();
  if (tid < TS) {
    const int t = tid;
    float* v = &tval[t*10]; int* ix = &tidxs[t*10];
    for (int p = 0; p < 10; p++) { v[p] = -3.0e38f; ix[p] = 0; }
    const float4* qrow = (const float4*)&Qb[(t+1)*104];
    for (int j = 0; j < t; j++) {
      const float4* r = (const float4*)&Qb[j*104];
      float s = 0.f;
#pragma unroll
      for (int k4 = 0; k4 < 25; k4++) {
        float4 a = qrow[k4], c = r[k4];
        s += a.x*c.x + a.y*c.y + a.z*c.z + a.w*c.w;
      }
      if (s > v[9]) {
        int p = 9;
        while (p > 0 && s > v[p-1]) { v[p] = v[p-1]; ix[p] = ix[p-1]; p--; }
        v[p] = s; ix[p] = j;
      }
    }
    for (int p = 0; p < 10; p++) topidx[(t*BB + b)*10 + p] = ix[p];
  }
}

// ---------------------------------------------------------------------------
// P4: fused LSTM + attention. Whh f32 rows in registers; hist f32 in LDS.
// ---------------------------------------------------------------------------
__global__ __launch_bounds__(512, 1) void k_seq(
    const float* __restrict__ Whh, const __hip_bfloat16* __restrict__ xg,
    const float* __restrict__ h0, const float* __restrict__ c0,
    const float* __restrict__ emb_q, const float* __restrict__ emb_s,
    const int* __restrict__ question, const int* __restrict__ qs_skill,
    const int* __restrict__ topidx, const float* __restrict__ kvqv,
    float* __restrict__ out)
{
  __shared__ __align__(16) float hist[TS*100];   // 59.6 KB; row t = h after step t
  __shared__ __align__(16) float h_l[100];
  __shared__ float gates[400];
  __shared__ __align__(16) float qsb[8][500];
  __shared__ float sqb[8][5];
  __shared__ float skt[152];
  __shared__ __align__(16) float qvl[100];
  const int b = blockIdx.x, tid = threadIdx.x;
  const int wv = tid >> 6, lane = tid & 63;
  float4 w[25];
  if (tid < 400) {
#pragma unroll
    for (int k4 = 0; k4 < 25; k4++) w[k4] = *(const float4*)&Whh[tid*100 + k4*4];
  }
  float c = 0.f;
  if (tid < 100) { c = c0[b*100 + tid]; h_l[tid] = h0[b*100 + tid]; }
  if (tid >= 128 && tid < 228) qvl[tid-128] = kvqv[100 + (tid-128)];
  if (tid == 480) out[b*TT] = 0.5f;
  float xpre = 0.f;
  if (tid < 400) xpre = bf(xg[(size_t)b*400 + tid]);
  __syncthreads();
  // ---- LSTM scan ----
  for (int t = 0; t < TS; t++) {
    if (tid < 400) {
      float a0 = xpre, a1 = 0.f, a2 = 0.f, a3 = 0.f;
      if (t + 1 < TS) xpre = bf(xg[((size_t)(t+1)*BB + b)*400 + tid]);
#pragma unroll
      for (int k4 = 0; k4 < 25; k4++) {
        float4 h4 = *(const float4*)&h_l[k4*4];
        a0 = fmaf(w[k4].x, h4.x, a0);
        a1 = fmaf(w[k4].y, h4.y, a1);
        a2 = fmaf(w[k4].z, h4.z, a2);
        a3 = fmaf(w[k4].w, h4.w, a3);
      }
      gates[tid] = (a0 + a1) + (a2 + a3);
    }
    __syncthreads();
    if (tid < 100) {
      float cc = sigm(gates[100+tid])*c + sigm(gates[tid])*tanhf(gates[200+tid]);
      c = cc;
      float hn = sigm(gates[300+tid])*tanhf(cc);
      h_l[tid] = hn;
      hist[t*100 + tid] = hn;
    }
    __syncthreads();
  }
  // ---- skt[r] = hist[r]·kv + ck ----
  const float ck = kvqv[200], cq = kvqv[201], wb0 = kvqv[202];
  if (tid < 298) {
    int r = tid >> 1, half = tid & 1;
    float s0=0.f,s1=0.f,s2=0.f,s3=0.f;
    for (int k4 = half*13; k4 < (half ? 25 : 13); k4++) {
      float4 h4 = *(const float4*)&hist[r*100 + k4*4];
      float4 kv4 = *(const float4*)&kvqv[k4*4];
      s0 = fmaf(h4.x, kv4.x, s0); s1 = fmaf(h4.y, kv4.y, s1);
      s2 = fmaf(h4.z, kv4.z, s2); s3 = fmaf(h4.w, kv4.w, s3);
    }
    float s = (s0+s1)+(s2+s3);
    s += __shfl_xor(s, 1);
    if (!half) skt[r] = s + ck;
  }
  __syncthreads();
  // ---- attention: one wave per t ----
  for (int t0 = 0; t0 < TS; t0 += 8) {
    int t = t0 + wv;
    if (t >= TS) continue;
    const int qn = question[b*TT + t + 1];
    for (int e = lane; e < 500; e += 64) {
      int q = e / 100;
      qsb[wv][e] = (q == 0) ? emb_q[qn*100 + e]
                            : emb_s[qs_skill[qn*4 + q - 1]*100 + e%100];
    }
    if (lane >= 55 && lane < 60) {
      int q = lane - 55;
      const float4* qq = (const float4*)&qsb[wv][q*100];
      float s0=0.f,s1=0.f,s2=0.f,s3=0.f;
      for (int k4 = 0; k4 < 25; k4++) {
        float4 a = qq[k4]; float4 qv4 = *(const float4*)&qvl[k4*4];
        s0 = fmaf(a.x, qv4.x, s0); s1 = fmaf(a.y, qv4.y, s1);
        s2 = fmaf(a.z, qv4.z, s2); s3 = fmaf(a.w, qv4.w, s3);
      }
      sqb[wv][q] = (s0+s1)+(s2+s3) + cq;
    }
    float scv = -3.0e38f, gval = 0.f;
    if (lane < 55) {
      int q = lane / 11, s = lane % 11;
      int j; bool valid = true;
      float sk = 0.f;
      if (s == 0) { j = t; sk = skt[t]; }
      else {
        int cnt = t < 10 ? t : 10;
        if (s - 1 < cnt) {
          j = topidx[((size_t)t*BB + b)*10 + s - 1];
          sk = (j == 0) ? ck : skt[j];
        } else { j = -1; valid = false; }
      }
      if ((s == 0) || (valid && j > 0)) {
        int row = (s == 0) ? t : j;
        const float4* hr = (const float4*)&hist[row*100];
        const float4* qq = (const float4*)&qsb[wv][q*100];
        float g0=0.f,g1=0.f,g2=0.f,g3=0.f;
        for (int k4 = 0; k4 < 25; k4++) {
          float4 h4 = hr[k4]; float4 a = qq[k4];
          g0 = fmaf(h4.x, a.x, g0); g1 = fmaf(h4.y, a.y, g1);
          g2 = fmaf(h4.z, a.z, g2); g3 = fmaf(h4.w, a.w, g3);
        }
        gval = (g0+g1)+(g2+g3);
      }
      scv = valid ? (sqb[wv][q] + sk + wb0) : -1e9f;
    }
    float m = scv;
#pragma unroll
    for (int o = 32; o; o >>= 1) m = fmaxf(m, __shfl_xor(m, o));
    float ex = (lane < 55) ? expf(scv - m) : 0.f;
    float num = ex * gval, den = ex;
#pragma unroll
    for (int o = 32; o; o >>= 1) { num += __shfl_xor(num, o); den += __shfl_xor(den, o); }
    if (lane == 0) out[b*TT + t + 1] = sigm(num/den);
  }
}

extern "C" void kernel_launch(void* const* d_in, const int* in_sizes, int n_in,
                              void* d_out, int out_size, void* d_ws, size_t ws_size,
                              hipStream_t stream) {
  const float* emb_q  = (const float*)d_in[0];
  const float* emb_q2 = (const float*)d_in[1];
  const float* emb_s  = (const float*)d_in[2];
  const float* emb_u  = (const float*)d_in[3];
  const float* emb_r  = (const float*)d_in[4];
  const float* w1_q   = (const float*)d_in[5];
  const float* w2_q   = (const float*)d_in[6];
  const float* lin_W  = (const float*)d_in[7];
  const float* lin_b  = (const float*)d_in[8];
  const float* Wih    = (const float*)d_in[9];
  const float* Whh    = (const float*)d_in[10];
  const float* bih    = (const float*)d_in[11];
  const float* bhh    = (const float*)d_in[12];
  const float* agg_W  = (const float*)d_in[13];
  const float* agg_b  = (const float*)d_in[14];
  const float* last_W = (const float*)d_in[15];
  const float* last_b = (const float*)d_in[16];
  const float* qW     = (const float*)d_in[17];
  const float* qb     = (const float*)d_in[18];
  const float* kW     = (const float*)d_in[19];
  const float* kb     = (const float*)d_in[20];
  const float* wW     = (const float*)d_in[21];
  const float* wb     = (const float*)d_in[22];
  const float* h0     = (const float*)d_in[23];
  const float* c0     = (const float*)d_in[24];
  const int* user      = (const int*)d_in[25];
  const int* question  = (const int*)d_in[26];
  const int* response  = (const int*)d_in[27];
  const int* mask      = (const int*)d_in[28];
  const int* q_nb      = (const int*)d_in[29];
  const int* s_nb      = (const int*)d_in[30];
  const int* u_nb      = (const int*)d_in[31];
  const int* q_nb2     = (const int*)d_in[32];
  const int* qs_skill  = (const int*)d_in[33];

  char* ws = (char*)d_ws;
  unsigned*       u0     = (unsigned*)(ws + 0);                //  7,628,800 (emb_or_t0cin)
  __hip_bfloat16* xg     = (__hip_bfloat16*)(ws + 7628800);    // 15,257,600
  int*            topidx = (int*)(ws + 22886400);              //    762,880
  __hip_bfloat16* Wb     = (__hip_bfloat16*)(ws + 23649280);   //    131,072
  __hip_bfloat16* linB   = (__hip_bfloat16*)(ws + 23780352);   //     93,184
  __hip_bfloat16* wihB   = (__hip_bfloat16*)(ws + 23873536);   //    179,200
  uint2*          gQ     = (uint2*)(ws + 24052736);            // 10,000,000
  uint2*          gU     = (uint2*)(ws + 34052736);            //  4,000,000
  uint2*          gT1Q   = (uint2*)(ws + 38052736);            //    400,000
  uint2*          gT1U   = (uint2*)(ws + 38452736);            // 10,000,000
  float*          kvqv   = (float*)(ws + 48452736);            //      1,024 -> 48,453,760

  k_prep<<<2048, 256, 0, stream>>>(agg_W, last_W, lin_W, Wih,
                                   emb_q, emb_q2, emb_s, emb_u,
                                   q_nb, s_nb, u_nb, q_nb2,
                                   qW, qb, kW, kb, wW, wb,
                                   Wb, linB, wihB, gQ, gU, gT1Q, gT1U, kvqv);
  k_embhat<<<NITEM, 512, 0, stream>>>(emb_q, emb_q2, w1_q, w2_q, agg_b,
                                      user, question, mask, q_nb, s_nb, u_nb, q_nb2,
                                      Wb, gQ, gU, gT1Q, gT1U, u0);
  k_chain<<<TS*4, 512, 0, stream>>>(emb_r, agg_b, last_b, lin_b, bih, bhh,
                                    w1_q, w2_q, response, mask, u0,
                                    Wb, linB, wihB, xg);
  k_topk<<<128, 256, 0, stream>>>(emb_q, question, topidx);
  k_seq<<<128, 512, 0, stream>>>(Whh, xg, h0, c0, emb_q, emb_s,
                                 question, qs_skill, topidx, kvqv, (float*)d_out);
}